// Round 1
// baseline (1335.499 us; speedup 1.0000x reference)
//
#include <hip/hip_runtime.h>
#include <cstdint>
#include <cstddef>

#define B_  16
#define N_  576
#define D_  768
#define H_  12
#define HD_ 64
#define M_  128
#define J_  704   // N_ + M_

// ---------------- helpers ----------------

__device__ __forceinline__ float softplus_f(float x) {
    return (x > 20.f) ? x : log1pf(expf(x));
}

__device__ __forceinline__ float wred_sum64(float v) {
#pragma unroll
    for (int m = 1; m < 64; m <<= 1) v += __shfl_xor(v, m, 64);
    return v;
}

// expmap0 total multiplier for a row with raw sumsq n2; also returns final ||out||^2
__device__ __forceinline__ float expmap0_factor(float n2, float sc, float* n2out) {
    const float ATANH_1M1E5 = 6.1030335f;     // artanh(1 - 1e-5)
    float n0 = sqrtf(fmaxf(n2, 1e-15f));
    float maxtan = ATANH_1M1E5 / sc;
    float f1 = fminf(1.f, maxtan / n0);       // pre-clip
    float n1 = n0 * f1;
    float a  = sc * n1;
    float th = tanhf(a);
    float yfac  = th / a;                     // y = u * f1 * yfac
    float ynorm = th / sc;
    float lim   = (1.f - 1e-5f) / sc;
    float f2 = fminf(1.f, lim / ynorm);       // post-clip
    float fn = ynorm * f2;
    *n2out = fn * fn;
    return f1 * yfac * f2;
}

__device__ __forceinline__ float artanh_fast(float z) {  // z in [0, 1-1e-7]
    return 0.5f * __logf((1.f + z) / (1.f - z));
}

// ---------------- kernel 1: QKV projection GEMM ----------------
// q/k/v[i][o] = sum_k x[i][k] * W[o][k] + b[o]; scatter into head-major buffers.
__global__ __launch_bounds__(256) void gemm_qkv_kernel(
    const float* __restrict__ x,
    const float* __restrict__ Wq, const float* __restrict__ Wk, const float* __restrict__ Wv,
    const float* __restrict__ bq, const float* __restrict__ bk, const float* __restrict__ bv,
    float* __restrict__ qh, float* __restrict__ Kh, float* __restrict__ Vh)
{
    __shared__ float aT[64][68];
    __shared__ float wT[64][68];
    const int mt = blockIdx.x;            // 0..143 row tile
    const int ot = blockIdx.y;            // 0..35 col tile
    const int which = ot / 12;            // 0=q 1=k 2=v
    const int h = ot % 12;
    const float* W    = which == 0 ? Wq : (which == 1 ? Wk : Wv);
    const float* bias = which == 0 ? bq : (which == 1 ? bk : bv);
    const int tid = threadIdx.x, ty = tid >> 4, tx = tid & 15;
    const int sr = tid >> 4, sc4 = tid & 15;
    const int row0 = mt * 64, wrow0 = h * 64;

    float acc[4][4] = {};
    for (int k0 = 0; k0 < 768; k0 += 64) {
#pragma unroll
        for (int s = 0; s < 4; ++s) {
            int r = sr + s * 16;
            float4 a4 = *(const float4*)&x[(size_t)(row0 + r) * 768 + k0 + sc4 * 4];
            aT[sc4*4+0][r] = a4.x; aT[sc4*4+1][r] = a4.y; aT[sc4*4+2][r] = a4.z; aT[sc4*4+3][r] = a4.w;
            float4 w4 = *(const float4*)&W[(size_t)(wrow0 + r) * 768 + k0 + sc4 * 4];
            wT[sc4*4+0][r] = w4.x; wT[sc4*4+1][r] = w4.y; wT[sc4*4+2][r] = w4.z; wT[sc4*4+3][r] = w4.w;
        }
        __syncthreads();
#pragma unroll 16
        for (int kk = 0; kk < 64; ++kk) {
            float4 a4 = *(const float4*)&aT[kk][ty * 4];
            float4 w4 = *(const float4*)&wT[kk][tx * 4];
            float av[4] = {a4.x, a4.y, a4.z, a4.w};
            float wv[4] = {w4.x, w4.y, w4.z, w4.w};
#pragma unroll
            for (int u = 0; u < 4; ++u)
#pragma unroll
                for (int v = 0; v < 4; ++v)
                    acc[u][v] = fmaf(av[u], wv[v], acc[u][v]);
        }
        __syncthreads();
    }
    float4 b4 = *(const float4*)&bias[wrow0 + tx * 4];
#pragma unroll
    for (int u = 0; u < 4; ++u) {
        int i = row0 + ty * 4 + u;
        int b = i / 576, n = i - b * 576;
        float4 o;
        o.x = acc[u][0] + b4.x; o.y = acc[u][1] + b4.y;
        o.z = acc[u][2] + b4.z; o.w = acc[u][3] + b4.w;
        if (which == 0) {
            size_t dst = (((size_t)(b * 12 + h)) * 576 + n) * 64 + tx * 4;
            *(float4*)&qh[dst] = o;
        } else {
            size_t dst = (((size_t)(b * 12 + h)) * 704 + n) * 64 + tx * 4;
            if (which == 1) *(float4*)&Kh[dst] = o;
            else            *(float4*)&Vh[dst] = o;
        }
    }
}

// ---------------- kernel 2: expmap0 on q (in place) + x2 ----------------
__global__ __launch_bounds__(256) void expmap_q_kernel(
    float* __restrict__ qh, float* __restrict__ x2q, const float* __restrict__ curv_raw)
{
    const float c  = softplus_f(curv_raw[0]);
    const float sc = sqrtf(c);
    const int wid = threadIdx.x >> 6, lane = threadIdx.x & 63;
    const int row = blockIdx.x * 4 + wid;          // < B*H*N
    const size_t off = (size_t)row * 64 + lane;
    float u = qh[off];
    float n2 = wred_sum64(u * u);
    float n2o;
    float f = expmap0_factor(n2, sc, &n2o);
    qh[off] = u * f;
    if (lane == 0) x2q[row] = n2o;
}

// ---------------- kernel 3: build K_h/V_h (expmap + centroid rows) + y2,gamma ----------------
__global__ __launch_bounds__(256) void build_kv_kernel(
    float* __restrict__ Kh, float* __restrict__ Vh, const float* __restrict__ cent,
    float* __restrict__ y2g, float* __restrict__ gam, float* __restrict__ gm1,
    const float* __restrict__ curv_raw)
{
    const float c  = softplus_f(curv_raw[0]);
    const float sc = sqrtf(c);
    const int wid = threadIdx.x >> 6, lane = threadIdx.x & 63;
    const int g = blockIdx.x * 4 + wid;            // < B*H*J
    const int hj = g % (H_ * J_);
    const int h = hj / J_, j = hj % J_;
    const size_t off = (size_t)g * 64 + lane;
    float kx, vx;
    if (j < N_) { kx = Kh[off]; vx = Vh[off]; }
    else        { float cv = cent[(((size_t)h) * M_ + (j - N_)) * 64 + lane]; kx = cv; vx = cv; }
    float n2k = wred_sum64(kx * kx);
    float n2v = wred_sum64(vx * vx);
    float y2o, v2o;
    float fk = expmap0_factor(n2k, sc, &y2o);
    float fv = expmap0_factor(n2v, sc, &v2o);
    Kh[off] = kx * fk;
    Vh[off] = vx * fv;
    if (lane == 0) {
        y2g[g] = y2o;
        float gmm = 2.f / fmaxf(1.f - c * v2o, 1e-15f);
        gam[g] = gmm;
        gm1[g] = gmm - 1.f;
    }
}

// ---------------- kernel 4: fused hyperbolic attention ----------------
// Per block: one (b,h) pair, 64 q rows. Online-softmax over 11 j-tiles of 64.
// Softmax normalizer cancels in nom/den; epilogue folds mobius_half+logmap0.
__global__ __launch_bounds__(256) void attn_kernel(
    const float* __restrict__ qh, const float* __restrict__ Kh, const float* __restrict__ Vh,
    const float* __restrict__ x2q, const float* __restrict__ y2g,
    const float* __restrict__ gam, const float* __restrict__ gm1,
    const float* __restrict__ sigma_raw, const float* __restrict__ curv_raw,
    float* __restrict__ Obuf)
{
    __shared__ float qT[64][68];   // qT[kk][r]
    __shared__ float KV[64][68];   // phase S: KT[kk][j] ; phase PV: gV[j][hd]
    __shared__ float wTs[64][68];  // wTs[j][r]
    __shared__ float x2s[64], y2s[64], gm1s[64];

    const int blk = blockIdx.x;
    const int qt = blk % 9;
    const int bh = blk / 9;
    const int b = bh / 12, h = bh % 12;
    const float c  = softplus_f(curv_raw[0]);
    const float sc = sqrtf(c);
    const float sig = softplus_f(sigma_raw[h]) + 1e-6f;
    const float coef = -2.f / (c * sig * sig);   // logit = coef * artanh(arg)^2

    const int tid = threadIdx.x, ty = tid >> 4, tx = tid & 15;
    const int sr = tid >> 4, sc4 = tid & 15;

    const size_t qbase = (size_t)bh * 576 + qt * 64;
#pragma unroll
    for (int s = 0; s < 4; ++s) {
        int r = sr + s * 16;
        float4 a4 = *(const float4*)&qh[(qbase + r) * 64 + sc4 * 4];
        qT[sc4*4+0][r] = a4.x; qT[sc4*4+1][r] = a4.y; qT[sc4*4+2][r] = a4.z; qT[sc4*4+3][r] = a4.w;
    }
    if (tid < 64) x2s[tid] = x2q[qbase + tid];

    float nom[4][4] = {};
    float den[4] = {};
    float mrow[4] = {-1e30f, -1e30f, -1e30f, -1e30f};
    const size_t kvbase = (size_t)bh * 704;

    for (int jt = 0; jt < 11; ++jt) {
        const size_t jb = kvbase + jt * 64;
        // ---- stage K tile (transposed) + per-j scalars
#pragma unroll
        for (int s = 0; s < 4; ++s) {
            int r = sr + s * 16;
            float4 a4 = *(const float4*)&Kh[(jb + r) * 64 + sc4 * 4];
            KV[sc4*4+0][r] = a4.x; KV[sc4*4+1][r] = a4.y; KV[sc4*4+2][r] = a4.z; KV[sc4*4+3][r] = a4.w;
        }
        if (tid < 64) { y2s[tid] = y2g[jb + tid]; gm1s[tid] = gm1[jb + tid]; }
        __syncthreads();

        // ---- S = q . K^T  (xy inner products)
        float s4[4][4] = {};
#pragma unroll 16
        for (int kk = 0; kk < 64; ++kk) {
            float4 a4 = *(const float4*)&qT[kk][ty * 4];
            float4 k4 = *(const float4*)&KV[kk][tx * 4];
            float av[4] = {a4.x, a4.y, a4.z, a4.w};
            float kv[4] = {k4.x, k4.y, k4.z, k4.w};
#pragma unroll
            for (int u = 0; u < 4; ++u)
#pragma unroll
                for (int v = 0; v < 4; ++v)
                    s4[u][v] = fmaf(av[u], kv[v], s4[u][v]);
        }

        // ---- xy -> logit
#pragma unroll
        for (int u = 0; u < 4; ++u) {
            float x2 = x2s[ty * 4 + u];
            float Bc = fmaf(-c, x2, 1.f);
#pragma unroll
            for (int v = 0; v < 4; ++v) {
                float xy = s4[u][v];
                float y2 = y2s[tx * 4 + v];
                float A = 1.f - 2.f * c * xy + c * y2;
                float num2 = A * A * x2 - 2.f * A * Bc * xy + Bc * Bc * y2;
                float dn = 1.f - 2.f * c * xy + c * c * x2 * y2;
                float arg = sc * sqrtf(fmaxf(num2, 0.f)) / fmaxf(dn, 1e-15f);
                arg = fminf(arg, 1.f - 1e-7f);
                float t = artanh_fast(arg);
                s4[u][v] = coef * t * t;
            }
        }

        // ---- online softmax (unnormalized) + den accumulation + write wT
        float sclr[4];
#pragma unroll
        for (int u = 0; u < 4; ++u) {
            float tm = fmaxf(fmaxf(s4[u][0], s4[u][1]), fmaxf(s4[u][2], s4[u][3]));
#pragma unroll
            for (int msk = 1; msk < 16; msk <<= 1) tm = fmaxf(tm, __shfl_xor(tm, msk, 64));
            float mnew = fmaxf(mrow[u], tm);
            float scl = __expf(mrow[u] - mnew);
            mrow[u] = mnew; sclr[u] = scl;
            float dl = 0.f;
#pragma unroll
            for (int v = 0; v < 4; ++v) {
                float w = __expf(s4[u][v] - mnew);
                s4[u][v] = w;
                dl = fmaf(w, gm1s[tx * 4 + v], dl);
            }
#pragma unroll
            for (int msk = 1; msk < 16; msk <<= 1) dl += __shfl_xor(dl, msk, 64);
            den[u] = fmaf(den[u], scl, dl);
#pragma unroll
            for (int v = 0; v < 4; ++v) wTs[tx * 4 + v][ty * 4 + u] = s4[u][v];
        }
        __syncthreads();

        // ---- stage gamma*V into KV (row-major [j][hd])
#pragma unroll
        for (int s = 0; s < 4; ++s) {
            int r = sr + s * 16;
            float gg = gam[jb + r];
            float4 a4 = *(const float4*)&Vh[(jb + r) * 64 + sc4 * 4];
            a4.x *= gg; a4.y *= gg; a4.z *= gg; a4.w *= gg;
            *(float4*)&KV[r][sc4 * 4] = a4;
        }
        __syncthreads();

        // ---- PV: nom[r][hd] += sum_j w[r][j] * gV[j][hd]
#pragma unroll
        for (int u = 0; u < 4; ++u) {
            float s_ = sclr[u];
#pragma unroll
            for (int v = 0; v < 4; ++v) nom[u][v] *= s_;
        }
#pragma unroll 16
        for (int jl = 0; jl < 64; ++jl) {
            float4 w4 = *(const float4*)&wTs[jl][ty * 4];
            float4 v4 = *(const float4*)&KV[jl][tx * 4];
            float wv[4] = {w4.x, w4.y, w4.z, w4.w};
            float vv[4] = {v4.x, v4.y, v4.z, v4.w};
#pragma unroll
            for (int u = 0; u < 4; ++u)
#pragma unroll
                for (int v = 0; v < 4; ++v)
                    nom[u][v] = fmaf(wv[u], vv[v], nom[u][v]);
        }
        __syncthreads();
    }

    // ---- epilogue: two_mean = nom/den ; O = 0.5*artanh(sc*n)/(sc*n) * two_mean
#pragma unroll
    for (int u = 0; u < 4; ++u) {
        float d = den[u];
        d = (d >= 0.f) ? fmaxf(d, 1e-10f) : fminf(d, -1e-10f);
        float rd = 1.f / d;
        float o[4];
        float n2 = 0.f;
#pragma unroll
        for (int v = 0; v < 4; ++v) { o[v] = nom[u][v] * rd; n2 = fmaf(o[v], o[v], n2); }
#pragma unroll
        for (int msk = 1; msk < 16; msk <<= 1) n2 += __shfl_xor(n2, msk, 64);
        float nrm = sqrtf(fmaxf(n2, 1e-15f));
        float arg = fminf(sc * nrm, 1.f - 1e-7f);
        float t = artanh_fast(arg);
        float f = 0.5f * t / (sc * nrm);
        int nrow = qt * 64 + ty * 4 + u;
        size_t dst = (((size_t)b * 576 + nrow) * 768) + h * 64 + tx * 4;
        float4 o4 = { o[0] * f, o[1] * f, o[2] * f, o[3] * f };
        *(float4*)&Obuf[dst] = o4;
    }
}

// ---------------- kernel 5: output projection GEMM ----------------
__global__ __launch_bounds__(256) void gemm_o_kernel(
    const float* __restrict__ A, const float* __restrict__ W, const float* __restrict__ bias,
    float* __restrict__ C)
{
    __shared__ float aT[64][68];
    __shared__ float wT[64][68];
    const int mt = blockIdx.x;            // 0..143
    const int ot = blockIdx.y;            // 0..11
    const int tid = threadIdx.x, ty = tid >> 4, tx = tid & 15;
    const int sr = tid >> 4, sc4 = tid & 15;
    const int row0 = mt * 64, col0 = ot * 64;

    float acc[4][4] = {};
    for (int k0 = 0; k0 < 768; k0 += 64) {
#pragma unroll
        for (int s = 0; s < 4; ++s) {
            int r = sr + s * 16;
            float4 a4 = *(const float4*)&A[(size_t)(row0 + r) * 768 + k0 + sc4 * 4];
            aT[sc4*4+0][r] = a4.x; aT[sc4*4+1][r] = a4.y; aT[sc4*4+2][r] = a4.z; aT[sc4*4+3][r] = a4.w;
            float4 w4 = *(const float4*)&W[(size_t)(col0 + r) * 768 + k0 + sc4 * 4];
            wT[sc4*4+0][r] = w4.x; wT[sc4*4+1][r] = w4.y; wT[sc4*4+2][r] = w4.z; wT[sc4*4+3][r] = w4.w;
        }
        __syncthreads();
#pragma unroll 16
        for (int kk = 0; kk < 64; ++kk) {
            float4 a4 = *(const float4*)&aT[kk][ty * 4];
            float4 w4 = *(const float4*)&wT[kk][tx * 4];
            float av[4] = {a4.x, a4.y, a4.z, a4.w};
            float wv[4] = {w4.x, w4.y, w4.z, w4.w};
#pragma unroll
            for (int u = 0; u < 4; ++u)
#pragma unroll
                for (int v = 0; v < 4; ++v)
                    acc[u][v] = fmaf(av[u], wv[v], acc[u][v]);
        }
        __syncthreads();
    }
    float4 b4 = *(const float4*)&bias[col0 + tx * 4];
#pragma unroll
    for (int u = 0; u < 4; ++u) {
        int i = row0 + ty * 4 + u;
        float4 o;
        o.x = acc[u][0] + b4.x; o.y = acc[u][1] + b4.y;
        o.z = acc[u][2] + b4.z; o.w = acc[u][3] + b4.w;
        *(float4*)&C[(size_t)i * 768 + col0 + tx * 4] = o;
    }
}

// ---------------- launcher ----------------
extern "C" void kernel_launch(void* const* d_in, const int* in_sizes, int n_in,
                              void* d_out, int out_size, void* d_ws, size_t ws_size,
                              hipStream_t stream) {
    (void)in_sizes; (void)n_in; (void)out_size; (void)ws_size;
    const float* x    = (const float*)d_in[0];
    const float* Wq   = (const float*)d_in[1];
    const float* bq   = (const float*)d_in[2];
    const float* Wk   = (const float*)d_in[3];
    const float* bk   = (const float*)d_in[4];
    const float* Wv   = (const float*)d_in[5];
    const float* bv   = (const float*)d_in[6];
    const float* Wo   = (const float*)d_in[7];
    const float* bo   = (const float*)d_in[8];
    const float* cent = (const float*)d_in[9];
    const float* curv = (const float*)d_in[10];
    const float* sigr = (const float*)d_in[11];
    float* out = (float*)d_out;

    float* ws = (float*)d_ws;
    const size_t QH  = (size_t)B_ * H_ * N_ * 64;   // 7,077,888
    const size_t KVH = (size_t)B_ * H_ * J_ * 64;   // 8,650,752
    float* qh   = ws;
    float* Kh   = qh + QH;
    float* Vh   = Kh + KVH;
    float* Obuf = Vh + KVH;
    float* x2q  = Obuf + QH;
    float* y2g  = x2q + (size_t)B_ * H_ * N_;
    float* gam  = y2g + (size_t)B_ * H_ * J_;
    float* gm1  = gam + (size_t)B_ * H_ * J_;

    gemm_qkv_kernel<<<dim3(144, 36), 256, 0, stream>>>(x, Wq, Wk, Wv, bq, bk, bv, qh, Kh, Vh);
    expmap_q_kernel<<<27648, 256, 0, stream>>>(qh, x2q, curv);
    build_kv_kernel<<<33792, 256, 0, stream>>>(Kh, Vh, cent, y2g, gam, gm1, curv);
    attn_kernel<<<1728, 256, 0, stream>>>(qh, Kh, Vh, x2q, y2g, gam, gm1, sigr, curv, Obuf);
    gemm_o_kernel<<<dim3(144, 12), 256, 0, stream>>>(Obuf, Wo, bo, out);
}

// Round 2
// 795.896 us; speedup vs baseline: 1.6780x; 1.6780x over previous
//
#include <hip/hip_runtime.h>
#include <cstdint>
#include <cstddef>

#define B_  16
#define N_  576
#define D_  768
#define H_  12
#define HD_ 64
#define M_  128
#define J_  704   // N_ + M_

typedef unsigned short u16;
typedef __attribute__((ext_vector_type(8))) short bf16x8;
typedef __attribute__((ext_vector_type(4))) float f32x4;
typedef __attribute__((ext_vector_type(4))) unsigned short u16x4;

// ---------------- helpers ----------------

__device__ __forceinline__ float softplus_f(float x) {
    return (x > 20.f) ? x : log1pf(expf(x));
}

__device__ __forceinline__ float wred_sum64(float v) {
#pragma unroll
    for (int m = 1; m < 64; m <<= 1) v += __shfl_xor(v, m, 64);
    return v;
}

__device__ __forceinline__ u16 bf16_rne(float f) {
    unsigned int u = __float_as_uint(f);
    unsigned int r = u + 0x7FFFu + ((u >> 16) & 1u);
    return (u16)(r >> 16);
}
__device__ __forceinline__ float bf16_tof(u16 h) {
    return __uint_as_float(((unsigned int)h) << 16);
}

// expmap0 total multiplier for a row with raw sumsq n2; also returns final ||out||^2
__device__ __forceinline__ float expmap0_factor(float n2, float sc, float* n2out) {
    const float ATANH_1M1E5 = 6.1030335f;     // artanh(1 - 1e-5)
    float n0 = sqrtf(fmaxf(n2, 1e-15f));
    float maxtan = ATANH_1M1E5 / sc;
    float f1 = fminf(1.f, maxtan / n0);       // pre-clip
    float n1 = n0 * f1;
    float a  = sc * n1;
    float th = tanhf(a);
    float yfac  = th / a;                     // y = u * f1 * yfac
    float ynorm = th / sc;
    float lim   = (1.f - 1e-5f) / sc;
    float f2 = fminf(1.f, lim / ynorm);       // post-clip
    float fn = ynorm * f2;
    *n2out = fn * fn;
    return f1 * yfac * f2;
}

__device__ __forceinline__ float artanh_fast(float z) {  // z in [0, 1-1e-7]
    return 0.5f * __logf((1.f + z) / (1.f - z));
}

// global -> LDS direct copy, 16B per lane (wave-uniform LDS base + lane*16)
typedef const __attribute__((address_space(1))) unsigned int* gas_u32;
typedef __attribute__((address_space(3))) unsigned int* las_u32;
__device__ __forceinline__ void gload_lds16(const u16* g, u16* l) {
    __builtin_amdgcn_global_load_lds((gas_u32)(const void*)g, (las_u32)(void*)l, 16, 0, 0);
}

// ---------------- kernel 0: f32 -> bf16 hi/lo split ----------------
__global__ __launch_bounds__(256) void split_bf16_kernel(
    const float* __restrict__ src, u16* __restrict__ hi, u16* __restrict__ lo, int n4)
{
    int i = blockIdx.x * 256 + threadIdx.x;
    if (i >= n4) return;
    float4 v = ((const float4*)src)[i];
    u16x4 h, l;
    h[0] = bf16_rne(v.x); l[0] = bf16_rne(v.x - bf16_tof(h[0]));
    h[1] = bf16_rne(v.y); l[1] = bf16_rne(v.y - bf16_tof(h[1]));
    h[2] = bf16_rne(v.z); l[2] = bf16_rne(v.z - bf16_tof(h[2]));
    h[3] = bf16_rne(v.w); l[3] = bf16_rne(v.w - bf16_tof(h[3]));
    ((u16x4*)hi)[i] = h;
    ((u16x4*)lo)[i] = l;
}

// ---------------- kernel 1: QKV projection (split-bf16 MFMA) ----------------
// C[i][o] = sum_k x[i][k]*W[o][k] + b[o], scattered into head-major q/K/V buffers.
// 128x128 tile, BK=32, 4 waves (2x2 of 64x64), 16x16x32 bf16 MFMA, 3 passes (hh, hl, lh).
__global__ __launch_bounds__(256) void gemm_qkv_mfma(
    const u16* __restrict__ xh, const u16* __restrict__ xl,
    const u16* __restrict__ Wh0, const u16* __restrict__ Wl0,
    const u16* __restrict__ Wh1, const u16* __restrict__ Wl1,
    const u16* __restrict__ Wh2, const u16* __restrict__ Wl2,
    const float* __restrict__ bq, const float* __restrict__ bk, const float* __restrict__ bv,
    float* __restrict__ qh_o, float* __restrict__ Kh_o, float* __restrict__ Vh_o)
{
    __shared__ u16 Ah[4096], Al[4096], Bh[4096], Bl[4096];   // 8 frags x 512 each
    const int tid = threadIdx.x;
    const int w = tid >> 6, lane = tid & 63;
    const int wr = w >> 1, wc = w & 1;
    const int lrow = lane & 15, lk8 = (lane >> 4) << 3;
    const int mt = blockIdx.x, yb = blockIdx.y;
    const int which = yb / 6, ct = yb - which * 6;
    const u16* Bp_h = which == 0 ? Wh0 : (which == 1 ? Wh1 : Wh2);
    const u16* Bp_l = which == 0 ? Wl0 : (which == 1 ? Wl1 : Wl2);
    const int row0 = mt * 128, col0 = ct * 128;

    // per-lane global offsets for this wave's two staged fragments (A and B)
    const size_t a0 = (size_t)(row0 + (2 * w + 0) * 16 + lrow) * 768 + lk8;
    const size_t a1 = a0 + 16 * 768;
    const size_t b0 = (size_t)(col0 + (2 * w + 0) * 16 + lrow) * 768 + lk8;
    const size_t b1 = b0 + 16 * 768;
    u16* lAh0 = Ah + (2 * w) * 512; u16* lAh1 = lAh0 + 512;
    u16* lAl0 = Al + (2 * w) * 512; u16* lAl1 = lAl0 + 512;
    u16* lBh0 = Bh + (2 * w) * 512; u16* lBh1 = lBh0 + 512;
    u16* lBl0 = Bl + (2 * w) * 512; u16* lBl1 = lBl0 + 512;

    f32x4 acc[4][4];
#pragma unroll
    for (int i = 0; i < 4; ++i)
#pragma unroll
        for (int j = 0; j < 4; ++j) acc[i][j] = (f32x4){0.f, 0.f, 0.f, 0.f};

    for (int k0 = 0; k0 < 768; k0 += 32) {
        gload_lds16(xh + a0 + k0, lAh0);
        gload_lds16(xh + a1 + k0, lAh1);
        gload_lds16(xl + a0 + k0, lAl0);
        gload_lds16(xl + a1 + k0, lAl1);
        gload_lds16(Bp_h + b0 + k0, lBh0);
        gload_lds16(Bp_h + b1 + k0, lBh1);
        gload_lds16(Bp_l + b0 + k0, lBl0);
        gload_lds16(Bp_l + b1 + k0, lBl1);
        __syncthreads();
        bf16x8 aH[4], aL[4], bH[4], bL[4];
        const int lo8 = lane * 8;
#pragma unroll
        for (int i = 0; i < 4; ++i) {
            aH[i] = *(const bf16x8*)(Ah + (wr * 4 + i) * 512 + lo8);
            aL[i] = *(const bf16x8*)(Al + (wr * 4 + i) * 512 + lo8);
            bH[i] = *(const bf16x8*)(Bh + (wc * 4 + i) * 512 + lo8);
            bL[i] = *(const bf16x8*)(Bl + (wc * 4 + i) * 512 + lo8);
        }
#pragma unroll
        for (int mi = 0; mi < 4; ++mi)
#pragma unroll
            for (int ni = 0; ni < 4; ++ni) {
                acc[mi][ni] = __builtin_amdgcn_mfma_f32_16x16x32_bf16(aH[mi], bH[ni], acc[mi][ni], 0, 0, 0);
                acc[mi][ni] = __builtin_amdgcn_mfma_f32_16x16x32_bf16(aH[mi], bL[ni], acc[mi][ni], 0, 0, 0);
                acc[mi][ni] = __builtin_amdgcn_mfma_f32_16x16x32_bf16(aL[mi], bH[ni], acc[mi][ni], 0, 0, 0);
            }
        __syncthreads();
    }

    const float* bias = which == 0 ? bq : (which == 1 ? bk : bv);
    const int h = ct * 2 + wc;                     // head for this wave's 64-col strip
    const int rbase = row0 + wr * 64 + ((lane >> 4) << 2);
#pragma unroll
    for (int ni = 0; ni < 4; ++ni) {
        const int hd = ni * 16 + lrow;
        const float bv_ = bias[h * 64 + hd];
#pragma unroll
        for (int mi = 0; mi < 4; ++mi) {
            f32x4 a = acc[mi][ni];
#pragma unroll
            for (int r = 0; r < 4; ++r) {
                int row = rbase + mi * 16 + r;     // global token row in [0, 9216)
                int bb = row / 576;
                int nn = row - bb * 576;
                float val = a[r] + bv_;
                if (which == 0)
                    qh_o[(((size_t)(bb * 12 + h)) * 576 + nn) * 64 + hd] = val;
                else if (which == 1)
                    Kh_o[(((size_t)(bb * 12 + h)) * 704 + nn) * 64 + hd] = val;
                else
                    Vh_o[(((size_t)(bb * 12 + h)) * 704 + nn) * 64 + hd] = val;
            }
        }
    }
}

// ---------------- kernel 5: output projection (split-bf16 MFMA) ----------------
__global__ __launch_bounds__(256) void gemm_o_mfma(
    const u16* __restrict__ Oh, const u16* __restrict__ Ol,
    const u16* __restrict__ Wh, const u16* __restrict__ Wl,
    const float* __restrict__ bo, float* __restrict__ out)
{
    __shared__ u16 Ah[4096], Al[4096], Bh[4096], Bl[4096];
    const int tid = threadIdx.x;
    const int w = tid >> 6, lane = tid & 63;
    const int wr = w >> 1, wc = w & 1;
    const int lrow = lane & 15, lk8 = (lane >> 4) << 3;
    const int mt = blockIdx.x, ct = blockIdx.y;
    const int row0 = mt * 128, col0 = ct * 128;

    const size_t a0 = (size_t)(row0 + (2 * w + 0) * 16 + lrow) * 768 + lk8;
    const size_t a1 = a0 + 16 * 768;
    const size_t b0 = (size_t)(col0 + (2 * w + 0) * 16 + lrow) * 768 + lk8;
    const size_t b1 = b0 + 16 * 768;
    u16* lAh0 = Ah + (2 * w) * 512; u16* lAh1 = lAh0 + 512;
    u16* lAl0 = Al + (2 * w) * 512; u16* lAl1 = lAl0 + 512;
    u16* lBh0 = Bh + (2 * w) * 512; u16* lBh1 = lBh0 + 512;
    u16* lBl0 = Bl + (2 * w) * 512; u16* lBl1 = lBl0 + 512;

    f32x4 acc[4][4];
#pragma unroll
    for (int i = 0; i < 4; ++i)
#pragma unroll
        for (int j = 0; j < 4; ++j) acc[i][j] = (f32x4){0.f, 0.f, 0.f, 0.f};

    for (int k0 = 0; k0 < 768; k0 += 32) {
        gload_lds16(Oh + a0 + k0, lAh0);
        gload_lds16(Oh + a1 + k0, lAh1);
        gload_lds16(Ol + a0 + k0, lAl0);
        gload_lds16(Ol + a1 + k0, lAl1);
        gload_lds16(Wh + b0 + k0, lBh0);
        gload_lds16(Wh + b1 + k0, lBh1);
        gload_lds16(Wl + b0 + k0, lBl0);
        gload_lds16(Wl + b1 + k0, lBl1);
        __syncthreads();
        bf16x8 aH[4], aL[4], bH[4], bL[4];
        const int lo8 = lane * 8;
#pragma unroll
        for (int i = 0; i < 4; ++i) {
            aH[i] = *(const bf16x8*)(Ah + (wr * 4 + i) * 512 + lo8);
            aL[i] = *(const bf16x8*)(Al + (wr * 4 + i) * 512 + lo8);
            bH[i] = *(const bf16x8*)(Bh + (wc * 4 + i) * 512 + lo8);
            bL[i] = *(const bf16x8*)(Bl + (wc * 4 + i) * 512 + lo8);
        }
#pragma unroll
        for (int mi = 0; mi < 4; ++mi)
#pragma unroll
            for (int ni = 0; ni < 4; ++ni) {
                acc[mi][ni] = __builtin_amdgcn_mfma_f32_16x16x32_bf16(aH[mi], bH[ni], acc[mi][ni], 0, 0, 0);
                acc[mi][ni] = __builtin_amdgcn_mfma_f32_16x16x32_bf16(aH[mi], bL[ni], acc[mi][ni], 0, 0, 0);
                acc[mi][ni] = __builtin_amdgcn_mfma_f32_16x16x32_bf16(aL[mi], bH[ni], acc[mi][ni], 0, 0, 0);
            }
        __syncthreads();
    }

    const int rbase = row0 + wr * 64 + ((lane >> 4) << 2);
#pragma unroll
    for (int ni = 0; ni < 4; ++ni) {
        const int colg = col0 + wc * 64 + ni * 16 + lrow;
        const float bv_ = bo[colg];
#pragma unroll
        for (int mi = 0; mi < 4; ++mi) {
            f32x4 a = acc[mi][ni];
#pragma unroll
            for (int r = 0; r < 4; ++r) {
                int row = rbase + mi * 16 + r;
                out[(size_t)row * 768 + colg] = a[r] + bv_;
            }
        }
    }
}

// ---------------- kernel 2: expmap0 on q (in place) + x2 ----------------
__global__ __launch_bounds__(256) void expmap_q_kernel(
    float* __restrict__ qh, float* __restrict__ x2q, const float* __restrict__ curv_raw)
{
    const float c  = softplus_f(curv_raw[0]);
    const float sc = sqrtf(c);
    const int wid = threadIdx.x >> 6, lane = threadIdx.x & 63;
    const int row = blockIdx.x * 4 + wid;          // < B*H*N
    const size_t off = (size_t)row * 64 + lane;
    float u = qh[off];
    float n2 = wred_sum64(u * u);
    float n2o;
    float f = expmap0_factor(n2, sc, &n2o);
    qh[off] = u * f;
    if (lane == 0) x2q[row] = n2o;
}

// ---------------- kernel 3: build K_h/V_h (expmap + centroid rows) + y2,gamma ----------------
__global__ __launch_bounds__(256) void build_kv_kernel(
    float* __restrict__ Kh, float* __restrict__ Vh, const float* __restrict__ cent,
    float* __restrict__ y2g, float* __restrict__ gam, float* __restrict__ gm1,
    const float* __restrict__ curv_raw)
{
    const float c  = softplus_f(curv_raw[0]);
    const float sc = sqrtf(c);
    const int wid = threadIdx.x >> 6, lane = threadIdx.x & 63;
    const int g = blockIdx.x * 4 + wid;            // < B*H*J
    const int hj = g % (H_ * J_);
    const int h = hj / J_, j = hj % J_;
    const size_t off = (size_t)g * 64 + lane;
    float kx, vx;
    if (j < N_) { kx = Kh[off]; vx = Vh[off]; }
    else        { float cv = cent[(((size_t)h) * M_ + (j - N_)) * 64 + lane]; kx = cv; vx = cv; }
    float n2k = wred_sum64(kx * kx);
    float n2v = wred_sum64(vx * vx);
    float y2o, v2o;
    float fk = expmap0_factor(n2k, sc, &y2o);
    float fv = expmap0_factor(n2v, sc, &v2o);
    Kh[off] = kx * fk;
    Vh[off] = vx * fv;
    if (lane == 0) {
        y2g[g] = y2o;
        float gmm = 2.f / fmaxf(1.f - c * v2o, 1e-15f);
        gam[g] = gmm;
        gm1[g] = gmm - 1.f;
    }
}

// ---------------- kernel 4: fused hyperbolic attention ----------------
// Per block: one (b,h) pair, 64 q rows. Online-softmax over 11 j-tiles of 64.
// Softmax normalizer cancels in nom/den; epilogue folds mobius_half+logmap0 and
// writes the hi/lo bf16 split of O for the MFMA output projection.
__global__ __launch_bounds__(256) void attn_kernel(
    const float* __restrict__ qh, const float* __restrict__ Kh, const float* __restrict__ Vh,
    const float* __restrict__ x2q, const float* __restrict__ y2g,
    const float* __restrict__ gam, const float* __restrict__ gm1,
    const float* __restrict__ sigma_raw, const float* __restrict__ curv_raw,
    u16* __restrict__ Oh, u16* __restrict__ Ol)
{
    __shared__ float qT[64][68];   // qT[kk][r]
    __shared__ float KV[64][68];   // phase S: KT[kk][j] ; phase PV: gV[j][hd]
    __shared__ float wTs[64][68];  // wTs[j][r]
    __shared__ float x2s[64], y2s[64], gm1s[64];

    const int blk = blockIdx.x;
    const int qt = blk % 9;
    const int bh = blk / 9;
    const int b = bh / 12, h = bh % 12;
    const float c  = softplus_f(curv_raw[0]);
    const float sc = sqrtf(c);
    const float sig = softplus_f(sigma_raw[h]) + 1e-6f;
    const float coef = -2.f / (c * sig * sig);   // logit = coef * artanh(arg)^2

    const int tid = threadIdx.x, ty = tid >> 4, tx = tid & 15;
    const int sr = tid >> 4, sc4 = tid & 15;

    const size_t qbase = (size_t)bh * 576 + qt * 64;
#pragma unroll
    for (int s = 0; s < 4; ++s) {
        int r = sr + s * 16;
        float4 a4 = *(const float4*)&qh[(qbase + r) * 64 + sc4 * 4];
        qT[sc4*4+0][r] = a4.x; qT[sc4*4+1][r] = a4.y; qT[sc4*4+2][r] = a4.z; qT[sc4*4+3][r] = a4.w;
    }
    if (tid < 64) x2s[tid] = x2q[qbase + tid];

    float nom[4][4] = {};
    float den[4] = {};
    float mrow[4] = {-1e30f, -1e30f, -1e30f, -1e30f};
    const size_t kvbase = (size_t)bh * 704;

    for (int jt = 0; jt < 11; ++jt) {
        const size_t jb = kvbase + jt * 64;
        // ---- stage K tile (transposed) + per-j scalars
#pragma unroll
        for (int s = 0; s < 4; ++s) {
            int r = sr + s * 16;
            float4 a4 = *(const float4*)&Kh[(jb + r) * 64 + sc4 * 4];
            KV[sc4*4+0][r] = a4.x; KV[sc4*4+1][r] = a4.y; KV[sc4*4+2][r] = a4.z; KV[sc4*4+3][r] = a4.w;
        }
        if (tid < 64) { y2s[tid] = y2g[jb + tid]; gm1s[tid] = gm1[jb + tid]; }
        __syncthreads();

        // ---- S = q . K^T  (xy inner products)
        float s4[4][4] = {};
#pragma unroll 16
        for (int kk = 0; kk < 64; ++kk) {
            float4 a4 = *(const float4*)&qT[kk][ty * 4];
            float4 k4 = *(const float4*)&KV[kk][tx * 4];
            float av[4] = {a4.x, a4.y, a4.z, a4.w};
            float kv[4] = {k4.x, k4.y, k4.z, k4.w};
#pragma unroll
            for (int u = 0; u < 4; ++u)
#pragma unroll
                for (int v = 0; v < 4; ++v)
                    s4[u][v] = fmaf(av[u], kv[v], s4[u][v]);
        }

        // ---- xy -> logit
#pragma unroll
        for (int u = 0; u < 4; ++u) {
            float x2 = x2s[ty * 4 + u];
            float Bc = fmaf(-c, x2, 1.f);
#pragma unroll
            for (int v = 0; v < 4; ++v) {
                float xy = s4[u][v];
                float y2 = y2s[tx * 4 + v];
                float A = 1.f - 2.f * c * xy + c * y2;
                float num2 = A * A * x2 - 2.f * A * Bc * xy + Bc * Bc * y2;
                float dn = 1.f - 2.f * c * xy + c * c * x2 * y2;
                float arg = sc * sqrtf(fmaxf(num2, 0.f)) / fmaxf(dn, 1e-15f);
                arg = fminf(arg, 1.f - 1e-7f);
                float t = artanh_fast(arg);
                s4[u][v] = coef * t * t;
            }
        }

        // ---- online softmax (unnormalized) + den accumulation + write wT
        float sclr[4];
#pragma unroll
        for (int u = 0; u < 4; ++u) {
            float tm = fmaxf(fmaxf(s4[u][0], s4[u][1]), fmaxf(s4[u][2], s4[u][3]));
#pragma unroll
            for (int msk = 1; msk < 16; msk <<= 1) tm = fmaxf(tm, __shfl_xor(tm, msk, 64));
            float mnew = fmaxf(mrow[u], tm);
            float scl = __expf(mrow[u] - mnew);
            mrow[u] = mnew; sclr[u] = scl;
            float dl = 0.f;
#pragma unroll
            for (int v = 0; v < 4; ++v) {
                float w = __expf(s4[u][v] - mnew);
                s4[u][v] = w;
                dl = fmaf(w, gm1s[tx * 4 + v], dl);
            }
#pragma unroll
            for (int msk = 1; msk < 16; msk <<= 1) dl += __shfl_xor(dl, msk, 64);
            den[u] = fmaf(den[u], scl, dl);
#pragma unroll
            for (int v = 0; v < 4; ++v) wTs[tx * 4 + v][ty * 4 + u] = s4[u][v];
        }
        __syncthreads();

        // ---- stage gamma*V into KV (row-major [j][hd])
#pragma unroll
        for (int s = 0; s < 4; ++s) {
            int r = sr + s * 16;
            float gg = gam[jb + r];
            float4 a4 = *(const float4*)&Vh[(jb + r) * 64 + sc4 * 4];
            a4.x *= gg; a4.y *= gg; a4.z *= gg; a4.w *= gg;
            *(float4*)&KV[r][sc4 * 4] = a4;
        }
        __syncthreads();

        // ---- PV: nom[r][hd] += sum_j w[r][j] * gV[j][hd]
#pragma unroll
        for (int u = 0; u < 4; ++u) {
            float s_ = sclr[u];
#pragma unroll
            for (int v = 0; v < 4; ++v) nom[u][v] *= s_;
        }
#pragma unroll 16
        for (int jl = 0; jl < 64; ++jl) {
            float4 w4 = *(const float4*)&wTs[jl][ty * 4];
            float4 v4 = *(const float4*)&KV[jl][tx * 4];
            float wv[4] = {w4.x, w4.y, w4.z, w4.w};
            float vv[4] = {v4.x, v4.y, v4.z, v4.w};
#pragma unroll
            for (int u = 0; u < 4; ++u)
#pragma unroll
                for (int v = 0; v < 4; ++v)
                    nom[u][v] = fmaf(wv[u], vv[v], nom[u][v]);
        }
        __syncthreads();
    }

    // ---- epilogue: two_mean = nom/den ; O = 0.5*artanh(sc*n)/(sc*n) * two_mean
#pragma unroll
    for (int u = 0; u < 4; ++u) {
        float d = den[u];
        d = (d >= 0.f) ? fmaxf(d, 1e-10f) : fminf(d, -1e-10f);
        float rd = 1.f / d;
        float o[4];
        float n2 = 0.f;
#pragma unroll
        for (int v = 0; v < 4; ++v) { o[v] = nom[u][v] * rd; n2 = fmaf(o[v], o[v], n2); }
#pragma unroll
        for (int msk = 1; msk < 16; msk <<= 1) n2 += __shfl_xor(n2, msk, 64);
        float nrm = sqrtf(fmaxf(n2, 1e-15f));
        float arg = fminf(sc * nrm, 1.f - 1e-7f);
        float t = artanh_fast(arg);
        float f = 0.5f * t / (sc * nrm);
        int nrow = qt * 64 + ty * 4 + u;
        size_t dst = (((size_t)b * 576 + nrow) * 768) + h * 64 + tx * 4;
        u16x4 hs, ls;
#pragma unroll
        for (int v = 0; v < 4; ++v) {
            float val = o[v] * f;
            u16 hb = bf16_rne(val);
            hs[v] = hb;
            ls[v] = bf16_rne(val - bf16_tof(hb));
        }
        *(u16x4*)&Oh[dst] = hs;
        *(u16x4*)&Ol[dst] = ls;
    }
}

// ---------------- launcher ----------------
extern "C" void kernel_launch(void* const* d_in, const int* in_sizes, int n_in,
                              void* d_out, int out_size, void* d_ws, size_t ws_size,
                              hipStream_t stream) {
    (void)in_sizes; (void)n_in; (void)out_size; (void)ws_size;
    const float* x    = (const float*)d_in[0];
    const float* Wq   = (const float*)d_in[1];
    const float* bq   = (const float*)d_in[2];
    const float* Wk   = (const float*)d_in[3];
    const float* bk   = (const float*)d_in[4];
    const float* Wv   = (const float*)d_in[5];
    const float* bv   = (const float*)d_in[6];
    const float* Wo   = (const float*)d_in[7];
    const float* bo   = (const float*)d_in[8];
    const float* cent = (const float*)d_in[9];
    const float* curv = (const float*)d_in[10];
    const float* sigr = (const float*)d_in[11];
    float* out = (float*)d_out;

    const size_t QH  = (size_t)B_ * H_ * N_ * 64;   // 7,077,888
    const size_t KVH = (size_t)B_ * H_ * J_ * 64;   // 8,650,752
    const size_t WSZ = (size_t)D_ * D_;             // 589,824

    float* fp = (float*)d_ws;
    float* qh   = fp;            fp += QH;
    float* Kh   = fp;            fp += KVH;
    float* Vh   = fp;            fp += KVH;
    float* x2q  = fp;            fp += (size_t)B_ * H_ * N_;
    float* y2g  = fp;            fp += (size_t)B_ * H_ * J_;
    float* gam  = fp;            fp += (size_t)B_ * H_ * J_;
    float* gm1  = fp;            fp += (size_t)B_ * H_ * J_;
    u16* up = (u16*)fp;
    u16* xh  = up;  up += QH;
    u16* xl  = up;  up += QH;
    u16* Wqh = up;  up += WSZ;
    u16* Wql = up;  up += WSZ;
    u16* Wkh = up;  up += WSZ;
    u16* Wkl = up;  up += WSZ;
    u16* Wvh = up;  up += WSZ;
    u16* Wvl = up;  up += WSZ;
    u16* Woh = up;  up += WSZ;
    u16* Wol = up;  up += WSZ;
    u16* Oh  = up;  up += QH;
    u16* Ol  = up;  up += QH;

    // 0: hi/lo splits
    split_bf16_kernel<<<(int)(QH / 4 + 255) / 256, 256, 0, stream>>>(x, xh, xl, (int)(QH / 4));
    split_bf16_kernel<<<(int)(WSZ / 4 + 255) / 256, 256, 0, stream>>>(Wq, Wqh, Wql, (int)(WSZ / 4));
    split_bf16_kernel<<<(int)(WSZ / 4 + 255) / 256, 256, 0, stream>>>(Wk, Wkh, Wkl, (int)(WSZ / 4));
    split_bf16_kernel<<<(int)(WSZ / 4 + 255) / 256, 256, 0, stream>>>(Wv, Wvh, Wvl, (int)(WSZ / 4));
    split_bf16_kernel<<<(int)(WSZ / 4 + 255) / 256, 256, 0, stream>>>(Wo, Woh, Wol, (int)(WSZ / 4));

    // 1: QKV projections (MFMA)
    gemm_qkv_mfma<<<dim3(72, 18), 256, 0, stream>>>(xh, xl, Wqh, Wql, Wkh, Wkl, Wvh, Wvl,
                                                    bq, bk, bv, qh, Kh, Vh);
    // 2,3: hyperbolic maps
    expmap_q_kernel<<<27648, 256, 0, stream>>>(qh, x2q, curv);
    build_kv_kernel<<<33792, 256, 0, stream>>>(Kh, Vh, cent, y2g, gam, gm1, curv);
    // 4: fused attention (writes bf16 hi/lo O)
    attn_kernel<<<1728, 256, 0, stream>>>(qh, Kh, Vh, x2q, y2g, gam, gm1, sigr, curv, Oh, Ol);
    // 5: output projection (MFMA)
    gemm_o_mfma<<<dim3(72, 6), 256, 0, stream>>>(Oh, Ol, Woh, Wol, bo, out);
}

// Round 3
// 789.102 us; speedup vs baseline: 1.6924x; 1.0086x over previous
//
#include <hip/hip_runtime.h>
#include <cstdint>
#include <cstddef>

#define B_  16
#define N_  576
#define D_  768
#define H_  12
#define HD_ 64
#define M_  128
#define J_  704   // N_ + M_

typedef unsigned short u16;
typedef __attribute__((ext_vector_type(8))) short bf16x8;
typedef __attribute__((ext_vector_type(4))) float f32x4;
typedef __attribute__((ext_vector_type(4))) unsigned short u16x4;
typedef __attribute__((ext_vector_type(8))) unsigned short u16x8;

// ---------------- helpers ----------------

__device__ __forceinline__ float softplus_f(float x) {
    return (x > 20.f) ? x : log1pf(expf(x));
}

__device__ __forceinline__ float wred_sum64(float v) {
#pragma unroll
    for (int m = 1; m < 64; m <<= 1) v += __shfl_xor(v, m, 64);
    return v;
}

__device__ __forceinline__ u16 bf16_rne(float f) {
    unsigned int u = __float_as_uint(f);
    unsigned int r = u + 0x7FFFu + ((u >> 16) & 1u);
    return (u16)(r >> 16);
}
__device__ __forceinline__ float bf16_tof(u16 h) {
    return __uint_as_float(((unsigned int)h) << 16);
}

// expmap0 total multiplier for a row with raw sumsq n2; also returns final ||out||^2
__device__ __forceinline__ float expmap0_factor(float n2, float sc, float* n2out) {
    const float ATANH_1M1E5 = 6.1030335f;     // artanh(1 - 1e-5)
    float n0 = sqrtf(fmaxf(n2, 1e-15f));
    float maxtan = ATANH_1M1E5 / sc;
    float f1 = fminf(1.f, maxtan / n0);       // pre-clip
    float n1 = n0 * f1;
    float a  = sc * n1;
    float th = tanhf(a);
    float yfac  = th / a;                     // y = u * f1 * yfac
    float ynorm = th / sc;
    float lim   = (1.f - 1e-5f) / sc;
    float f2 = fminf(1.f, lim / ynorm);       // post-clip
    float fn = ynorm * f2;
    *n2out = fn * fn;
    return f1 * yfac * f2;
}

__device__ __forceinline__ float artanh_fast(float z) {  // z in [0, 1-1e-7]
    return 0.5f * __logf((1.f + z) / (1.f - z));
}

// global -> LDS direct copy, 16B per lane (wave-uniform LDS base + lane*16)
typedef const __attribute__((address_space(1))) unsigned int* gas_u32;
typedef __attribute__((address_space(3))) unsigned int* las_u32;
__device__ __forceinline__ void gload_lds16(const u16* g, u16* l) {
    __builtin_amdgcn_global_load_lds((gas_u32)(const void*)g, (las_u32)(void*)l, 16, 0, 0);
}

// ---------------- kernel 0: f32 -> bf16 hi/lo split ----------------
__global__ __launch_bounds__(256) void split_bf16_kernel(
    const float* __restrict__ src, u16* __restrict__ hi, u16* __restrict__ lo, int n4)
{
    int i = blockIdx.x * 256 + threadIdx.x;
    if (i >= n4) return;
    float4 v = ((const float4*)src)[i];
    u16x4 h, l;
    h[0] = bf16_rne(v.x); l[0] = bf16_rne(v.x - bf16_tof(h[0]));
    h[1] = bf16_rne(v.y); l[1] = bf16_rne(v.y - bf16_tof(h[1]));
    h[2] = bf16_rne(v.z); l[2] = bf16_rne(v.z - bf16_tof(h[2]));
    h[3] = bf16_rne(v.w); l[3] = bf16_rne(v.w - bf16_tof(h[3]));
    ((u16x4*)hi)[i] = h;
    ((u16x4*)lo)[i] = l;
}

// ---------------- kernel 1: QKV projection (split-bf16 MFMA) ----------------
__global__ __launch_bounds__(256) void gemm_qkv_mfma(
    const u16* __restrict__ xh, const u16* __restrict__ xl,
    const u16* __restrict__ Wh0, const u16* __restrict__ Wl0,
    const u16* __restrict__ Wh1, const u16* __restrict__ Wl1,
    const u16* __restrict__ Wh2, const u16* __restrict__ Wl2,
    const float* __restrict__ bq, const float* __restrict__ bk, const float* __restrict__ bv,
    float* __restrict__ qh_o, float* __restrict__ Kh_o, float* __restrict__ Vh_o)
{
    __shared__ u16 Ah[4096], Al[4096], Bh[4096], Bl[4096];   // 8 frags x 512 each
    const int tid = threadIdx.x;
    const int w = tid >> 6, lane = tid & 63;
    const int wr = w >> 1, wc = w & 1;
    const int lrow = lane & 15, lk8 = (lane >> 4) << 3;
    const int mt = blockIdx.x, yb = blockIdx.y;
    const int which = yb / 6, ct = yb - which * 6;
    const u16* Bp_h = which == 0 ? Wh0 : (which == 1 ? Wh1 : Wh2);
    const u16* Bp_l = which == 0 ? Wl0 : (which == 1 ? Wl1 : Wl2);
    const int row0 = mt * 128, col0 = ct * 128;

    const size_t a0 = (size_t)(row0 + (2 * w + 0) * 16 + lrow) * 768 + lk8;
    const size_t a1 = a0 + 16 * 768;
    const size_t b0 = (size_t)(col0 + (2 * w + 0) * 16 + lrow) * 768 + lk8;
    const size_t b1 = b0 + 16 * 768;
    u16* lAh0 = Ah + (2 * w) * 512; u16* lAh1 = lAh0 + 512;
    u16* lAl0 = Al + (2 * w) * 512; u16* lAl1 = lAl0 + 512;
    u16* lBh0 = Bh + (2 * w) * 512; u16* lBh1 = lBh0 + 512;
    u16* lBl0 = Bl + (2 * w) * 512; u16* lBl1 = lBl0 + 512;

    f32x4 acc[4][4];
#pragma unroll
    for (int i = 0; i < 4; ++i)
#pragma unroll
        for (int j = 0; j < 4; ++j) acc[i][j] = (f32x4){0.f, 0.f, 0.f, 0.f};

    for (int k0 = 0; k0 < 768; k0 += 32) {
        gload_lds16(xh + a0 + k0, lAh0);
        gload_lds16(xh + a1 + k0, lAh1);
        gload_lds16(xl + a0 + k0, lAl0);
        gload_lds16(xl + a1 + k0, lAl1);
        gload_lds16(Bp_h + b0 + k0, lBh0);
        gload_lds16(Bp_h + b1 + k0, lBh1);
        gload_lds16(Bp_l + b0 + k0, lBl0);
        gload_lds16(Bp_l + b1 + k0, lBl1);
        __syncthreads();
        bf16x8 aH[4], aL[4], bH[4], bL[4];
        const int lo8 = lane * 8;
#pragma unroll
        for (int i = 0; i < 4; ++i) {
            aH[i] = *(const bf16x8*)(Ah + (wr * 4 + i) * 512 + lo8);
            aL[i] = *(const bf16x8*)(Al + (wr * 4 + i) * 512 + lo8);
            bH[i] = *(const bf16x8*)(Bh + (wc * 4 + i) * 512 + lo8);
            bL[i] = *(const bf16x8*)(Bl + (wc * 4 + i) * 512 + lo8);
        }
#pragma unroll
        for (int mi = 0; mi < 4; ++mi)
#pragma unroll
            for (int ni = 0; ni < 4; ++ni) {
                acc[mi][ni] = __builtin_amdgcn_mfma_f32_16x16x32_bf16(aH[mi], bH[ni], acc[mi][ni], 0, 0, 0);
                acc[mi][ni] = __builtin_amdgcn_mfma_f32_16x16x32_bf16(aH[mi], bL[ni], acc[mi][ni], 0, 0, 0);
                acc[mi][ni] = __builtin_amdgcn_mfma_f32_16x16x32_bf16(aL[mi], bH[ni], acc[mi][ni], 0, 0, 0);
            }
        __syncthreads();
    }

    const float* bias = which == 0 ? bq : (which == 1 ? bk : bv);
    const int h = ct * 2 + wc;
    const int rbase = row0 + wr * 64 + ((lane >> 4) << 2);
#pragma unroll
    for (int ni = 0; ni < 4; ++ni) {
        const int hd = ni * 16 + lrow;
        const float bv_ = bias[h * 64 + hd];
#pragma unroll
        for (int mi = 0; mi < 4; ++mi) {
            f32x4 a = acc[mi][ni];
#pragma unroll
            for (int r = 0; r < 4; ++r) {
                int row = rbase + mi * 16 + r;
                int bb = row / 576;
                int nn = row - bb * 576;
                float val = a[r] + bv_;
                if (which == 0)
                    qh_o[(((size_t)(bb * 12 + h)) * 576 + nn) * 64 + hd] = val;
                else if (which == 1)
                    Kh_o[(((size_t)(bb * 12 + h)) * 704 + nn) * 64 + hd] = val;
                else
                    Vh_o[(((size_t)(bb * 12 + h)) * 704 + nn) * 64 + hd] = val;
            }
        }
    }
}

// ---------------- kernel 5: output projection (split-bf16 MFMA) ----------------
__global__ __launch_bounds__(256) void gemm_o_mfma(
    const u16* __restrict__ Oh, const u16* __restrict__ Ol,
    const u16* __restrict__ Wh, const u16* __restrict__ Wl,
    const float* __restrict__ bo, float* __restrict__ out)
{
    __shared__ u16 Ah[4096], Al[4096], Bh[4096], Bl[4096];
    const int tid = threadIdx.x;
    const int w = tid >> 6, lane = tid & 63;
    const int wr = w >> 1, wc = w & 1;
    const int lrow = lane & 15, lk8 = (lane >> 4) << 3;
    const int mt = blockIdx.x, ct = blockIdx.y;
    const int row0 = mt * 128, col0 = ct * 128;

    const size_t a0 = (size_t)(row0 + (2 * w + 0) * 16 + lrow) * 768 + lk8;
    const size_t a1 = a0 + 16 * 768;
    const size_t b0 = (size_t)(col0 + (2 * w + 0) * 16 + lrow) * 768 + lk8;
    const size_t b1 = b0 + 16 * 768;
    u16* lAh0 = Ah + (2 * w) * 512; u16* lAh1 = lAh0 + 512;
    u16* lAl0 = Al + (2 * w) * 512; u16* lAl1 = lAl0 + 512;
    u16* lBh0 = Bh + (2 * w) * 512; u16* lBh1 = lBh0 + 512;
    u16* lBl0 = Bl + (2 * w) * 512; u16* lBl1 = lBl0 + 512;

    f32x4 acc[4][4];
#pragma unroll
    for (int i = 0; i < 4; ++i)
#pragma unroll
        for (int j = 0; j < 4; ++j) acc[i][j] = (f32x4){0.f, 0.f, 0.f, 0.f};

    for (int k0 = 0; k0 < 768; k0 += 32) {
        gload_lds16(Oh + a0 + k0, lAh0);
        gload_lds16(Oh + a1 + k0, lAh1);
        gload_lds16(Ol + a0 + k0, lAl0);
        gload_lds16(Ol + a1 + k0, lAl1);
        gload_lds16(Wh + b0 + k0, lBh0);
        gload_lds16(Wh + b1 + k0, lBh1);
        gload_lds16(Wl + b0 + k0, lBl0);
        gload_lds16(Wl + b1 + k0, lBl1);
        __syncthreads();
        bf16x8 aH[4], aL[4], bH[4], bL[4];
        const int lo8 = lane * 8;
#pragma unroll
        for (int i = 0; i < 4; ++i) {
            aH[i] = *(const bf16x8*)(Ah + (wr * 4 + i) * 512 + lo8);
            aL[i] = *(const bf16x8*)(Al + (wr * 4 + i) * 512 + lo8);
            bH[i] = *(const bf16x8*)(Bh + (wc * 4 + i) * 512 + lo8);
            bL[i] = *(const bf16x8*)(Bl + (wc * 4 + i) * 512 + lo8);
        }
#pragma unroll
        for (int mi = 0; mi < 4; ++mi)
#pragma unroll
            for (int ni = 0; ni < 4; ++ni) {
                acc[mi][ni] = __builtin_amdgcn_mfma_f32_16x16x32_bf16(aH[mi], bH[ni], acc[mi][ni], 0, 0, 0);
                acc[mi][ni] = __builtin_amdgcn_mfma_f32_16x16x32_bf16(aH[mi], bL[ni], acc[mi][ni], 0, 0, 0);
                acc[mi][ni] = __builtin_amdgcn_mfma_f32_16x16x32_bf16(aL[mi], bH[ni], acc[mi][ni], 0, 0, 0);
            }
        __syncthreads();
    }

    const int rbase = row0 + wr * 64 + ((lane >> 4) << 2);
#pragma unroll
    for (int ni = 0; ni < 4; ++ni) {
        const int colg = col0 + wc * 64 + ni * 16 + lrow;
        const float bv_ = bo[colg];
#pragma unroll
        for (int mi = 0; mi < 4; ++mi) {
            f32x4 a = acc[mi][ni];
#pragma unroll
            for (int r = 0; r < 4; ++r) {
                int row = rbase + mi * 16 + r;
                out[(size_t)row * 768 + colg] = a[r] + bv_;
            }
        }
    }
}

// ---------------- kernel 2: expmap0 on q -> 3-plane bf16 split + x2 ----------------
__global__ __launch_bounds__(256) void expmap_q_kernel(
    const float* __restrict__ qh, u16* __restrict__ Qb0, u16* __restrict__ Qb1,
    u16* __restrict__ Qb2, float* __restrict__ x2q, const float* __restrict__ curv_raw)
{
    const float c  = softplus_f(curv_raw[0]);
    const float sc = sqrtf(c);
    const int wid = threadIdx.x >> 6, lane = threadIdx.x & 63;
    const int row = blockIdx.x * 4 + wid;          // < B*H*N
    const size_t off = (size_t)row * 64 + lane;
    float u = qh[off];
    float n2 = wred_sum64(u * u);
    float n2o;
    float f = expmap0_factor(n2, sc, &n2o);
    float y = u * f;
    u16 h = bf16_rne(y);
    float r1 = y - bf16_tof(h);
    u16 m = bf16_rne(r1);
    u16 l = bf16_rne(r1 - bf16_tof(m));
    Qb0[off] = h; Qb1[off] = m; Qb2[off] = l;
    if (lane == 0) x2q[row] = n2o;
}

// ---------------- kernel 3: build K (3-plane bf16) + transposed gamma*V (2-plane) ----------------
__global__ __launch_bounds__(256) void build_kv_kernel(
    const float* __restrict__ Khf, const float* __restrict__ Vhf, const float* __restrict__ cent,
    u16* __restrict__ Kb0, u16* __restrict__ Kb1, u16* __restrict__ Kb2,
    u16* __restrict__ gV0, u16* __restrict__ gV1,
    float* __restrict__ y2g, float* __restrict__ gm1,
    const float* __restrict__ curv_raw)
{
    __shared__ float gvt_s[64][65];
    const float c  = softplus_f(curv_raw[0]);
    const float sc = sqrtf(c);
    const int bx = blockIdx.x;
    const int bh = bx / 11, jt = bx - bh * 11;
    const int h = bh % 12;
    const int w = threadIdx.x >> 6, lane = threadIdx.x & 63;

#pragma unroll 4
    for (int i = 0; i < 16; ++i) {
        const int j = jt * 64 + w * 16 + i;
        const size_t g = (size_t)bh * 704 + j;
        float kx, vx;
        if (j < 576) { kx = Khf[g * 64 + lane]; vx = Vhf[g * 64 + lane]; }
        else         { float cv = cent[(((size_t)h) * 128 + (j - 576)) * 64 + lane]; kx = cv; vx = cv; }
        float n2k = wred_sum64(kx * kx);
        float n2v = wred_sum64(vx * vx);
        float y2o, v2o;
        float fk = expmap0_factor(n2k, sc, &y2o);
        float fv = expmap0_factor(n2v, sc, &v2o);
        float ky = kx * fk;
        u16 kh = bf16_rne(ky);
        float r1 = ky - bf16_tof(kh);
        u16 km = bf16_rne(r1);
        u16 kl = bf16_rne(r1 - bf16_tof(km));
        Kb0[g * 64 + lane] = kh; Kb1[g * 64 + lane] = km; Kb2[g * 64 + lane] = kl;
        float gmm = 2.f / fmaxf(1.f - c * v2o, 1e-15f);
        gvt_s[lane][w * 16 + i] = vx * fv * gmm;
        if (lane == 0) { y2g[g] = y2o; gm1[g] = gmm - 1.f; }
    }
    __syncthreads();
    // write out transposed gamma*V tile: [bh][hd][704]
    const int hd = threadIdx.x >> 2, j0 = (threadIdx.x & 3) * 16;
    u16 hb[16], lb[16];
#pragma unroll
    for (int e = 0; e < 16; ++e) {
        float v = gvt_s[hd][j0 + e];
        hb[e] = bf16_rne(v);
        lb[e] = bf16_rne(v - bf16_tof(hb[e]));
    }
    const size_t dst = ((size_t)bh * 64 + hd) * 704 + jt * 64 + j0;
    *(u16x8*)(gV0 + dst)     = *(u16x8*)&hb[0];
    *(u16x8*)(gV0 + dst + 8) = *(u16x8*)&hb[8];
    *(u16x8*)(gV1 + dst)     = *(u16x8*)&lb[0];
    *(u16x8*)(gV1 + dst + 8) = *(u16x8*)&lb[8];
}

// ---------------- kernel 4: fused hyperbolic attention (MFMA) ----------------
// Block = (bh, qtile of 64 rows); 4 waves x 16 q-rows. No __syncthreads.
// S = QK^T via 6-pass 3-component bf16 MFMA (f32-accurate); PV via 3-pass hi/lo.
__global__ __launch_bounds__(256) void attn_kernel(
    const u16* __restrict__ Qb0, const u16* __restrict__ Qb1, const u16* __restrict__ Qb2,
    const u16* __restrict__ Kb0, const u16* __restrict__ Kb1, const u16* __restrict__ Kb2,
    const u16* __restrict__ gV0, const u16* __restrict__ gV1,
    const float* __restrict__ x2q, const float* __restrict__ y2g, const float* __restrict__ gm1,
    const float* __restrict__ sigma_raw, const float* __restrict__ curv_raw,
    u16* __restrict__ Oh, u16* __restrict__ Ol)
{
    __shared__ u16 wb_hi[4][16][64];
    __shared__ u16 wb_lo[4][16][64];

    const int blk = blockIdx.x;
    const int qt = blk % 9;
    const int bh = blk / 9;
    const int b = bh / 12, h = bh % 12;
    const float c  = softplus_f(curv_raw[0]);
    const float sc = sqrtf(c);
    const float sig = softplus_f(sigma_raw[h]) + 1e-6f;
    const float coef = -2.f / (c * sig * sig);

    const int tid = threadIdx.x;
    const int w = tid >> 6, lane = tid & 63;
    const int lr = lane & 15, lg = lane >> 4, lo8 = lg * 8;

    const size_t qbase = (size_t)bh * 576 + qt * 64;
    const size_t kvbase = (size_t)bh * 704;

    // Q A-frags (3 components x 2 k-halves)
    bf16x8 aQh[2], aQm[2], aQl[2];
    {
        const size_t qrow = (qbase + w * 16 + lr) * 64;
#pragma unroll
        for (int kt = 0; kt < 2; ++kt) {
            const size_t o = qrow + kt * 32 + lo8;
            aQh[kt] = *(const bf16x8*)(Qb0 + o);
            aQm[kt] = *(const bf16x8*)(Qb1 + o);
            aQl[kt] = *(const bf16x8*)(Qb2 + o);
        }
    }
    float x2r[4];
#pragma unroll
    for (int r = 0; r < 4; ++r) x2r[r] = x2q[qbase + w * 16 + lg * 4 + r];

    f32x4 pv[4];
#pragma unroll
    for (int i = 0; i < 4; ++i) pv[i] = (f32x4){0.f, 0.f, 0.f, 0.f};
    float den[4] = {0.f, 0.f, 0.f, 0.f};
    float mrow[4] = {-1e30f, -1e30f, -1e30f, -1e30f};

    u16* wbh = &wb_hi[w][0][0];
    u16* wbl = &wb_lo[w][0][0];

    for (int jt = 0; jt < 11; ++jt) {
        const int jb = jt * 64;
        f32x4 sf[4];
        float y2v[4], gm1v[4];
#pragma unroll
        for (int jf = 0; jf < 4; ++jf) {
            const size_t jrow = kvbase + jb + jf * 16 + lr;
            y2v[jf] = y2g[jrow];
            gm1v[jf] = gm1[jrow];
            const size_t rowb = jrow * 64;
            f32x4 s = (f32x4){0.f, 0.f, 0.f, 0.f};
#pragma unroll
            for (int kt = 0; kt < 2; ++kt) {
                const size_t o = rowb + kt * 32 + lo8;
                bf16x8 kh = *(const bf16x8*)(Kb0 + o);
                bf16x8 km = *(const bf16x8*)(Kb1 + o);
                bf16x8 kl = *(const bf16x8*)(Kb2 + o);
                s = __builtin_amdgcn_mfma_f32_16x16x32_bf16(aQh[kt], kh, s, 0, 0, 0);
                s = __builtin_amdgcn_mfma_f32_16x16x32_bf16(aQh[kt], km, s, 0, 0, 0);
                s = __builtin_amdgcn_mfma_f32_16x16x32_bf16(aQm[kt], kh, s, 0, 0, 0);
                s = __builtin_amdgcn_mfma_f32_16x16x32_bf16(aQm[kt], km, s, 0, 0, 0);
                s = __builtin_amdgcn_mfma_f32_16x16x32_bf16(aQh[kt], kl, s, 0, 0, 0);
                s = __builtin_amdgcn_mfma_f32_16x16x32_bf16(aQl[kt], kh, s, 0, 0, 0);
            }
            sf[jf] = s;
        }

        // xy -> logit
#pragma unroll
        for (int jf = 0; jf < 4; ++jf) {
            const float y2 = y2v[jf];
#pragma unroll
            for (int r = 0; r < 4; ++r) {
                const float x2 = x2r[r];
                const float Bc = fmaf(-c, x2, 1.f);
                float xy = sf[jf][r];
                float A = 1.f - 2.f * c * xy + c * y2;
                float num2 = A * A * x2 - 2.f * A * Bc * xy + Bc * Bc * y2;
                float dn = 1.f - 2.f * c * xy + c * c * x2 * y2;
                float arg = sc * sqrtf(fmaxf(num2, 0.f)) / fmaxf(dn, 1e-15f);
                arg = fminf(arg, 1.f - 1e-7f);
                float t = artanh_fast(arg);
                sf[jf][r] = coef * t * t;
            }
        }

        // online softmax (unnormalized), den, rescale pv
        float sclr[4];
#pragma unroll
        for (int r = 0; r < 4; ++r) {
            float tm = fmaxf(fmaxf(sf[0][r], sf[1][r]), fmaxf(sf[2][r], sf[3][r]));
#pragma unroll
            for (int msk = 1; msk < 16; msk <<= 1) tm = fmaxf(tm, __shfl_xor(tm, msk, 64));
            float mnew = fmaxf(mrow[r], tm);
            float scl = __expf(mrow[r] - mnew);
            mrow[r] = mnew; sclr[r] = scl;
            float dl = 0.f;
#pragma unroll
            for (int jf = 0; jf < 4; ++jf) {
                float wv_ = __expf(sf[jf][r] - mnew);
                sf[jf][r] = wv_;
                dl = fmaf(wv_, gm1v[jf], dl);
            }
#pragma unroll
            for (int msk = 1; msk < 16; msk <<= 1) dl += __shfl_xor(dl, msk, 64);
            den[r] = fmaf(den[r], scl, dl);
#pragma unroll
            for (int hf = 0; hf < 4; ++hf) pv[hf][r] *= scl;
        }

        // W -> wave-private LDS (hi/lo, XOR-swizzled)
#pragma unroll
        for (int r = 0; r < 4; ++r) {
            const int row = lg * 4 + r;
            const int sw = (row & 7) << 3;
#pragma unroll
            for (int jf = 0; jf < 4; ++jf) {
                const int colu = (jf * 16 + lr) ^ sw;
                float wv_ = sf[jf][r];
                u16 hb = bf16_rne(wv_);
                wbh[row * 64 + colu] = hb;
                wbl[row * 64 + colu] = bf16_rne(wv_ - bf16_tof(hb));
            }
        }

        // read W back as A-frags
        bf16x8 aWh[2], aWl[2];
        {
            const int sw = (lr & 7) << 3;
#pragma unroll
            for (int kt = 0; kt < 2; ++kt) {
                const int colu = (kt * 32 + lo8) ^ sw;
                aWh[kt] = *(const bf16x8*)(wbh + lr * 64 + colu);
                aWl[kt] = *(const bf16x8*)(wbl + lr * 64 + colu);
            }
        }

        // PV: pv += W x (gamma*V)
#pragma unroll
        for (int hf = 0; hf < 4; ++hf) {
            const size_t vrow = ((size_t)bh * 64 + hf * 16 + lr) * 704 + jb;
#pragma unroll
            for (int kt = 0; kt < 2; ++kt) {
                const size_t o = vrow + kt * 32 + lo8;
                bf16x8 vh = *(const bf16x8*)(gV0 + o);
                bf16x8 vl = *(const bf16x8*)(gV1 + o);
                pv[hf] = __builtin_amdgcn_mfma_f32_16x16x32_bf16(aWh[kt], vh, pv[hf], 0, 0, 0);
                pv[hf] = __builtin_amdgcn_mfma_f32_16x16x32_bf16(aWh[kt], vl, pv[hf], 0, 0, 0);
                pv[hf] = __builtin_amdgcn_mfma_f32_16x16x32_bf16(aWl[kt], vh, pv[hf], 0, 0, 0);
            }
        }
    }

    // epilogue: two_mean = pv/den ; O = 0.5*artanh(sc*n)/(sc*n) * two_mean
#pragma unroll
    for (int r = 0; r < 4; ++r) {
        float d = den[r];
        d = (d >= 0.f) ? fmaxf(d, 1e-10f) : fminf(d, -1e-10f);
        float rd = 1.f / d;
        float o_[4];
        float n2 = 0.f;
#pragma unroll
        for (int hf = 0; hf < 4; ++hf) { o_[hf] = pv[hf][r] * rd; n2 = fmaf(o_[hf], o_[hf], n2); }
#pragma unroll
        for (int msk = 1; msk < 16; msk <<= 1) n2 += __shfl_xor(n2, msk, 64);
        float nrm = sqrtf(fmaxf(n2, 1e-15f));
        float arg = fminf(sc * nrm, 1.f - 1e-7f);
        float t = artanh_fast(arg);
        float f = 0.5f * t / (sc * nrm);
        const int nrow = qt * 64 + w * 16 + lg * 4 + r;
        const size_t dst = ((size_t)(b * 576 + nrow)) * 768 + h * 64;
#pragma unroll
        for (int hf = 0; hf < 4; ++hf) {
            float val = o_[hf] * f;
            u16 hb = bf16_rne(val);
            Oh[dst + hf * 16 + lr] = hb;
            Ol[dst + hf * 16 + lr] = bf16_rne(val - bf16_tof(hb));
        }
    }
}

// ---------------- launcher ----------------
extern "C" void kernel_launch(void* const* d_in, const int* in_sizes, int n_in,
                              void* d_out, int out_size, void* d_ws, size_t ws_size,
                              hipStream_t stream) {
    (void)in_sizes; (void)n_in; (void)out_size; (void)ws_size;
    const float* x    = (const float*)d_in[0];
    const float* Wq   = (const float*)d_in[1];
    const float* bq   = (const float*)d_in[2];
    const float* Wk   = (const float*)d_in[3];
    const float* bk   = (const float*)d_in[4];
    const float* Wv   = (const float*)d_in[5];
    const float* bv   = (const float*)d_in[6];
    const float* Wo   = (const float*)d_in[7];
    const float* bo   = (const float*)d_in[8];
    const float* cent = (const float*)d_in[9];
    const float* curv = (const float*)d_in[10];
    const float* sigr = (const float*)d_in[11];
    float* out = (float*)d_out;

    const size_t QH  = (size_t)B_ * H_ * N_ * 64;   // 7,077,888
    const size_t KVH = (size_t)B_ * H_ * J_ * 64;   // 8,650,752
    const size_t WSZ = (size_t)D_ * D_;             // 589,824

    float* fp = (float*)d_ws;
    float* qh   = fp;            fp += QH;
    float* Khf  = fp;            fp += KVH;
    float* Vhf  = fp;            fp += KVH;
    float* x2q  = fp;            fp += (size_t)B_ * H_ * N_;
    float* y2g  = fp;            fp += (size_t)B_ * H_ * J_;
    float* gm1  = fp;            fp += (size_t)B_ * H_ * J_;
    u16* up = (u16*)fp;
    u16* xh  = up;  up += QH;     // aliased with Oh (xh dead before attn writes Oh)
    u16* xl  = up;  up += QH;     // aliased with Ol
    u16* Oh  = xh;
    u16* Ol  = xl;
    u16* Wqh = up;  up += WSZ;
    u16* Wql = up;  up += WSZ;
    u16* Wkh = up;  up += WSZ;
    u16* Wkl = up;  up += WSZ;
    u16* Wvh = up;  up += WSZ;
    u16* Wvl = up;  up += WSZ;
    u16* Woh = up;  up += WSZ;
    u16* Wol = up;  up += WSZ;
    u16* Qb  = up;  up += 3 * QH;
    u16* Kb  = up;  up += 3 * KVH;
    u16* gV  = up;  up += 2 * KVH;

    u16* Qb0 = Qb;           u16* Qb1 = Qb + QH;   u16* Qb2 = Qb + 2 * QH;
    u16* Kb0 = Kb;           u16* Kb1 = Kb + KVH;  u16* Kb2 = Kb + 2 * KVH;
    u16* gV0 = gV;           u16* gV1 = gV + KVH;

    // 0: hi/lo splits of x and weights
    split_bf16_kernel<<<(int)(QH / 4 + 255) / 256, 256, 0, stream>>>(x, xh, xl, (int)(QH / 4));
    split_bf16_kernel<<<(int)(WSZ / 4 + 255) / 256, 256, 0, stream>>>(Wq, Wqh, Wql, (int)(WSZ / 4));
    split_bf16_kernel<<<(int)(WSZ / 4 + 255) / 256, 256, 0, stream>>>(Wk, Wkh, Wkl, (int)(WSZ / 4));
    split_bf16_kernel<<<(int)(WSZ / 4 + 255) / 256, 256, 0, stream>>>(Wv, Wvh, Wvl, (int)(WSZ / 4));
    split_bf16_kernel<<<(int)(WSZ / 4 + 255) / 256, 256, 0, stream>>>(Wo, Woh, Wol, (int)(WSZ / 4));

    // 1: QKV projections (MFMA)
    gemm_qkv_mfma<<<dim3(72, 18), 256, 0, stream>>>(xh, xl, Wqh, Wql, Wkh, Wkl, Wvh, Wvl,
                                                    bq, bk, bv, qh, Khf, Vhf);
    // 2,3: hyperbolic maps -> MFMA-ready operands
    expmap_q_kernel<<<27648, 256, 0, stream>>>(qh, Qb0, Qb1, Qb2, x2q, curv);
    build_kv_kernel<<<2112, 256, 0, stream>>>(Khf, Vhf, cent, Kb0, Kb1, Kb2, gV0, gV1,
                                              y2g, gm1, curv);
    // 4: fused attention (MFMA, barrier-free)
    attn_kernel<<<1728, 256, 0, stream>>>(Qb0, Qb1, Qb2, Kb0, Kb1, Kb2, gV0, gV1,
                                          x2q, y2g, gm1, sigr, curv, Oh, Ol);
    // 5: output projection (MFMA)
    gemm_o_mfma<<<dim3(72, 6), 256, 0, stream>>>(Oh, Ol, Woh, Wol, bo, out);
}

// Round 4
// 753.567 us; speedup vs baseline: 1.7722x; 1.0472x over previous
//
#include <hip/hip_runtime.h>
#include <cstdint>
#include <cstddef>

#define B_  16
#define N_  576
#define D_  768
#define H_  12
#define HD_ 64
#define M_  128
#define J_  704   // N_ + M_

typedef unsigned short u16;
typedef __attribute__((ext_vector_type(8))) short bf16x8;
typedef __attribute__((ext_vector_type(4))) float f32x4;
typedef __attribute__((ext_vector_type(4))) unsigned short u16x4;
typedef __attribute__((ext_vector_type(8))) unsigned short u16x8;

// ---------------- helpers ----------------

__device__ __forceinline__ float softplus_f(float x) {
    return (x > 20.f) ? x : log1pf(expf(x));
}

__device__ __forceinline__ float wred_sum64(float v) {
#pragma unroll
    for (int m = 1; m < 64; m <<= 1) v += __shfl_xor(v, m, 64);
    return v;
}

__device__ __forceinline__ u16 bf16_rne(float f) {
    unsigned int u = __float_as_uint(f);
    unsigned int r = u + 0x7FFFu + ((u >> 16) & 1u);
    return (u16)(r >> 16);
}
__device__ __forceinline__ float bf16_tof(u16 h) {
    return __uint_as_float(((unsigned int)h) << 16);
}

// expmap0 total multiplier for a row with raw sumsq n2; also returns final ||out||^2
__device__ __forceinline__ float expmap0_factor(float n2, float sc, float* n2out) {
    const float ATANH_1M1E5 = 6.1030335f;     // artanh(1 - 1e-5)
    float n0 = sqrtf(fmaxf(n2, 1e-15f));
    float maxtan = ATANH_1M1E5 / sc;
    float f1 = fminf(1.f, maxtan / n0);       // pre-clip
    float n1 = n0 * f1;
    float a  = sc * n1;
    float th = tanhf(a);
    float yfac  = th / a;                     // y = u * f1 * yfac
    float ynorm = th / sc;
    float lim   = (1.f - 1e-5f) / sc;
    float f2 = fminf(1.f, lim / ynorm);       // post-clip
    float fn = ynorm * f2;
    *n2out = fn * fn;
    return f1 * yfac * f2;
}

__device__ __forceinline__ float artanh_fast(float z) {  // z in [0, 1-1e-7]
    return 0.5f * __logf((1.f + z) / (1.f - z));
}

// global -> LDS direct copy, 16B per lane (wave-uniform LDS base + lane*16)
typedef const __attribute__((address_space(1))) unsigned int* gas_u32;
typedef __attribute__((address_space(3))) unsigned int* las_u32;
__device__ __forceinline__ void gload_lds16(const u16* g, u16* l) {
    __builtin_amdgcn_global_load_lds((gas_u32)(const void*)g, (las_u32)(void*)l, 16, 0, 0);
}

// ---------------- kernel 0: f32 -> bf16 hi/lo split ----------------
__global__ __launch_bounds__(256) void split_bf16_kernel(
    const float* __restrict__ src, u16* __restrict__ hi, u16* __restrict__ lo, int n4)
{
    int i = blockIdx.x * 256 + threadIdx.x;
    if (i >= n4) return;
    float4 v = ((const float4*)src)[i];
    u16x4 h, l;
    h[0] = bf16_rne(v.x); l[0] = bf16_rne(v.x - bf16_tof(h[0]));
    h[1] = bf16_rne(v.y); l[1] = bf16_rne(v.y - bf16_tof(h[1]));
    h[2] = bf16_rne(v.z); l[2] = bf16_rne(v.z - bf16_tof(h[2]));
    h[3] = bf16_rne(v.w); l[3] = bf16_rne(v.w - bf16_tof(h[3]));
    ((u16x4*)hi)[i] = h;
    ((u16x4*)lo)[i] = l;
}

// ---------------- kernel 1: QKV projection (split-bf16 MFMA) ----------------
__global__ __launch_bounds__(256) void gemm_qkv_mfma(
    const u16* __restrict__ xh, const u16* __restrict__ xl,
    const u16* __restrict__ Wh0, const u16* __restrict__ Wl0,
    const u16* __restrict__ Wh1, const u16* __restrict__ Wl1,
    const u16* __restrict__ Wh2, const u16* __restrict__ Wl2,
    const float* __restrict__ bq, const float* __restrict__ bk, const float* __restrict__ bv,
    float* __restrict__ qh_o, float* __restrict__ Kh_o, float* __restrict__ Vh_o)
{
    __shared__ u16 Ah[4096], Al[4096], Bh[4096], Bl[4096];   // 8 frags x 512 each
    const int tid = threadIdx.x;
    const int w = tid >> 6, lane = tid & 63;
    const int wr = w >> 1, wc = w & 1;
    const int lrow = lane & 15, lk8 = (lane >> 4) << 3;
    const int mt = blockIdx.x, yb = blockIdx.y;
    const int which = yb / 6, ct = yb - which * 6;
    const u16* Bp_h = which == 0 ? Wh0 : (which == 1 ? Wh1 : Wh2);
    const u16* Bp_l = which == 0 ? Wl0 : (which == 1 ? Wl1 : Wl2);
    const int row0 = mt * 128, col0 = ct * 128;

    const size_t a0 = (size_t)(row0 + (2 * w + 0) * 16 + lrow) * 768 + lk8;
    const size_t a1 = a0 + 16 * 768;
    const size_t b0 = (size_t)(col0 + (2 * w + 0) * 16 + lrow) * 768 + lk8;
    const size_t b1 = b0 + 16 * 768;
    u16* lAh0 = Ah + (2 * w) * 512; u16* lAh1 = lAh0 + 512;
    u16* lAl0 = Al + (2 * w) * 512; u16* lAl1 = lAl0 + 512;
    u16* lBh0 = Bh + (2 * w) * 512; u16* lBh1 = lBh0 + 512;
    u16* lBl0 = Bl + (2 * w) * 512; u16* lBl1 = lBl0 + 512;

    f32x4 acc[4][4];
#pragma unroll
    for (int i = 0; i < 4; ++i)
#pragma unroll
        for (int j = 0; j < 4; ++j) acc[i][j] = (f32x4){0.f, 0.f, 0.f, 0.f};

    for (int k0 = 0; k0 < 768; k0 += 32) {
        gload_lds16(xh + a0 + k0, lAh0);
        gload_lds16(xh + a1 + k0, lAh1);
        gload_lds16(xl + a0 + k0, lAl0);
        gload_lds16(xl + a1 + k0, lAl1);
        gload_lds16(Bp_h + b0 + k0, lBh0);
        gload_lds16(Bp_h + b1 + k0, lBh1);
        gload_lds16(Bp_l + b0 + k0, lBl0);
        gload_lds16(Bp_l + b1 + k0, lBl1);
        __syncthreads();
        bf16x8 aH[4], aL[4], bH[4], bL[4];
        const int lo8 = lane * 8;
#pragma unroll
        for (int i = 0; i < 4; ++i) {
            aH[i] = *(const bf16x8*)(Ah + (wr * 4 + i) * 512 + lo8);
            aL[i] = *(const bf16x8*)(Al + (wr * 4 + i) * 512 + lo8);
            bH[i] = *(const bf16x8*)(Bh + (wc * 4 + i) * 512 + lo8);
            bL[i] = *(const bf16x8*)(Bl + (wc * 4 + i) * 512 + lo8);
        }
#pragma unroll
        for (int mi = 0; mi < 4; ++mi)
#pragma unroll
            for (int ni = 0; ni < 4; ++ni) {
                acc[mi][ni] = __builtin_amdgcn_mfma_f32_16x16x32_bf16(aH[mi], bH[ni], acc[mi][ni], 0, 0, 0);
                acc[mi][ni] = __builtin_amdgcn_mfma_f32_16x16x32_bf16(aH[mi], bL[ni], acc[mi][ni], 0, 0, 0);
                acc[mi][ni] = __builtin_amdgcn_mfma_f32_16x16x32_bf16(aL[mi], bH[ni], acc[mi][ni], 0, 0, 0);
            }
        __syncthreads();
    }

    const float* bias = which == 0 ? bq : (which == 1 ? bk : bv);
    const int h = ct * 2 + wc;
    const int rbase = row0 + wr * 64 + ((lane >> 4) << 2);
#pragma unroll
    for (int ni = 0; ni < 4; ++ni) {
        const int hd = ni * 16 + lrow;
        const float bv_ = bias[h * 64 + hd];
#pragma unroll
        for (int mi = 0; mi < 4; ++mi) {
            f32x4 a = acc[mi][ni];
#pragma unroll
            for (int r = 0; r < 4; ++r) {
                int row = rbase + mi * 16 + r;
                int bb = row / 576;
                int nn = row - bb * 576;
                float val = a[r] + bv_;
                if (which == 0)
                    qh_o[(((size_t)(bb * 12 + h)) * 576 + nn) * 64 + hd] = val;
                else if (which == 1)
                    Kh_o[(((size_t)(bb * 12 + h)) * 704 + nn) * 64 + hd] = val;
                else
                    Vh_o[(((size_t)(bb * 12 + h)) * 704 + nn) * 64 + hd] = val;
            }
        }
    }
}

// ---------------- kernel 5: output projection (split-bf16 MFMA) ----------------
__global__ __launch_bounds__(256) void gemm_o_mfma(
    const u16* __restrict__ Oh, const u16* __restrict__ Ol,
    const u16* __restrict__ Wh, const u16* __restrict__ Wl,
    const float* __restrict__ bo, float* __restrict__ out)
{
    __shared__ u16 Ah[4096], Al[4096], Bh[4096], Bl[4096];
    const int tid = threadIdx.x;
    const int w = tid >> 6, lane = tid & 63;
    const int wr = w >> 1, wc = w & 1;
    const int lrow = lane & 15, lk8 = (lane >> 4) << 3;
    const int mt = blockIdx.x, ct = blockIdx.y;
    const int row0 = mt * 128, col0 = ct * 128;

    const size_t a0 = (size_t)(row0 + (2 * w + 0) * 16 + lrow) * 768 + lk8;
    const size_t a1 = a0 + 16 * 768;
    const size_t b0 = (size_t)(col0 + (2 * w + 0) * 16 + lrow) * 768 + lk8;
    const size_t b1 = b0 + 16 * 768;
    u16* lAh0 = Ah + (2 * w) * 512; u16* lAh1 = lAh0 + 512;
    u16* lAl0 = Al + (2 * w) * 512; u16* lAl1 = lAl0 + 512;
    u16* lBh0 = Bh + (2 * w) * 512; u16* lBh1 = lBh0 + 512;
    u16* lBl0 = Bl + (2 * w) * 512; u16* lBl1 = lBl0 + 512;

    f32x4 acc[4][4];
#pragma unroll
    for (int i = 0; i < 4; ++i)
#pragma unroll
        for (int j = 0; j < 4; ++j) acc[i][j] = (f32x4){0.f, 0.f, 0.f, 0.f};

    for (int k0 = 0; k0 < 768; k0 += 32) {
        gload_lds16(Oh + a0 + k0, lAh0);
        gload_lds16(Oh + a1 + k0, lAh1);
        gload_lds16(Ol + a0 + k0, lAl0);
        gload_lds16(Ol + a1 + k0, lAl1);
        gload_lds16(Wh + b0 + k0, lBh0);
        gload_lds16(Wh + b1 + k0, lBh1);
        gload_lds16(Wl + b0 + k0, lBl0);
        gload_lds16(Wl + b1 + k0, lBl1);
        __syncthreads();
        bf16x8 aH[4], aL[4], bH[4], bL[4];
        const int lo8 = lane * 8;
#pragma unroll
        for (int i = 0; i < 4; ++i) {
            aH[i] = *(const bf16x8*)(Ah + (wr * 4 + i) * 512 + lo8);
            aL[i] = *(const bf16x8*)(Al + (wr * 4 + i) * 512 + lo8);
            bH[i] = *(const bf16x8*)(Bh + (wc * 4 + i) * 512 + lo8);
            bL[i] = *(const bf16x8*)(Bl + (wc * 4 + i) * 512 + lo8);
        }
#pragma unroll
        for (int mi = 0; mi < 4; ++mi)
#pragma unroll
            for (int ni = 0; ni < 4; ++ni) {
                acc[mi][ni] = __builtin_amdgcn_mfma_f32_16x16x32_bf16(aH[mi], bH[ni], acc[mi][ni], 0, 0, 0);
                acc[mi][ni] = __builtin_amdgcn_mfma_f32_16x16x32_bf16(aH[mi], bL[ni], acc[mi][ni], 0, 0, 0);
                acc[mi][ni] = __builtin_amdgcn_mfma_f32_16x16x32_bf16(aL[mi], bH[ni], acc[mi][ni], 0, 0, 0);
            }
        __syncthreads();
    }

    const int rbase = row0 + wr * 64 + ((lane >> 4) << 2);
#pragma unroll
    for (int ni = 0; ni < 4; ++ni) {
        const int colg = col0 + wc * 64 + ni * 16 + lrow;
        const float bv_ = bo[colg];
#pragma unroll
        for (int mi = 0; mi < 4; ++mi) {
            f32x4 a = acc[mi][ni];
#pragma unroll
            for (int r = 0; r < 4; ++r) {
                int row = rbase + mi * 16 + r;
                out[(size_t)row * 768 + colg] = a[r] + bv_;
            }
        }
    }
}

// ---------------- kernel 2: expmap0 on q -> 3-plane bf16 split + x2 ----------------
__global__ __launch_bounds__(256) void expmap_q_kernel(
    const float* __restrict__ qh, u16* __restrict__ Qb0, u16* __restrict__ Qb1,
    u16* __restrict__ Qb2, float* __restrict__ x2q, const float* __restrict__ curv_raw)
{
    const float c  = softplus_f(curv_raw[0]);
    const float sc = sqrtf(c);
    const int wid = threadIdx.x >> 6, lane = threadIdx.x & 63;
    const int row = blockIdx.x * 4 + wid;          // < B*H*N
    const size_t off = (size_t)row * 64 + lane;
    float u = qh[off];
    float n2 = wred_sum64(u * u);
    float n2o;
    float f = expmap0_factor(n2, sc, &n2o);
    float y = u * f;
    u16 h = bf16_rne(y);
    float r1 = y - bf16_tof(h);
    u16 m = bf16_rne(r1);
    u16 l = bf16_rne(r1 - bf16_tof(m));
    Qb0[off] = h; Qb1[off] = m; Qb2[off] = l;
    if (lane == 0) x2q[row] = n2o;
}

// ---------------- kernel 3: build K (3-plane bf16) + transposed gamma*V (2-plane) ----------------
__global__ __launch_bounds__(256) void build_kv_kernel(
    const float* __restrict__ Khf, const float* __restrict__ Vhf, const float* __restrict__ cent,
    u16* __restrict__ Kb0, u16* __restrict__ Kb1, u16* __restrict__ Kb2,
    u16* __restrict__ gV0, u16* __restrict__ gV1,
    float* __restrict__ y2g, float* __restrict__ gm1,
    const float* __restrict__ curv_raw)
{
    __shared__ float gvt_s[64][65];
    const float c  = softplus_f(curv_raw[0]);
    const float sc = sqrtf(c);
    const int bx = blockIdx.x;
    const int bh = bx / 11, jt = bx - bh * 11;
    const int h = bh % 12;
    const int w = threadIdx.x >> 6, lane = threadIdx.x & 63;

#pragma unroll 4
    for (int i = 0; i < 16; ++i) {
        const int j = jt * 64 + w * 16 + i;
        const size_t g = (size_t)bh * 704 + j;
        float kx, vx;
        if (j < 576) { kx = Khf[g * 64 + lane]; vx = Vhf[g * 64 + lane]; }
        else         { float cv = cent[(((size_t)h) * 128 + (j - 576)) * 64 + lane]; kx = cv; vx = cv; }
        float n2k = wred_sum64(kx * kx);
        float n2v = wred_sum64(vx * vx);
        float y2o, v2o;
        float fk = expmap0_factor(n2k, sc, &y2o);
        float fv = expmap0_factor(n2v, sc, &v2o);
        float ky = kx * fk;
        u16 kh = bf16_rne(ky);
        float r1 = ky - bf16_tof(kh);
        u16 km = bf16_rne(r1);
        u16 kl = bf16_rne(r1 - bf16_tof(km));
        Kb0[g * 64 + lane] = kh; Kb1[g * 64 + lane] = km; Kb2[g * 64 + lane] = kl;
        float gmm = 2.f / fmaxf(1.f - c * v2o, 1e-15f);
        gvt_s[lane][w * 16 + i] = vx * fv * gmm;
        if (lane == 0) { y2g[g] = y2o; gm1[g] = gmm - 1.f; }
    }
    __syncthreads();
    // write out transposed gamma*V tile: [bh][hd][704]
    const int hd = threadIdx.x >> 2, j0 = (threadIdx.x & 3) * 16;
    u16 hb[16], lb[16];
#pragma unroll
    for (int e = 0; e < 16; ++e) {
        float v = gvt_s[hd][j0 + e];
        hb[e] = bf16_rne(v);
        lb[e] = bf16_rne(v - bf16_tof(hb[e]));
    }
    const size_t dst = ((size_t)bh * 64 + hd) * 704 + jt * 64 + j0;
    *(u16x8*)(gV0 + dst)     = *(u16x8*)&hb[0];
    *(u16x8*)(gV0 + dst + 8) = *(u16x8*)&hb[8];
    *(u16x8*)(gV1 + dst)     = *(u16x8*)&lb[0];
    *(u16x8*)(gV1 + dst + 8) = *(u16x8*)&lb[8];
}

// ---------------- kernel 4: fused hyperbolic attention (MFMA) ----------------
// Block = (bh, qtile of 64 rows); 4 waves x 16 q-rows. No __syncthreads.
// XCD-affinity swizzle: all 9 q-tile blocks of a bh land on the same XCD so
// K/gammaV stream from that XCD's L2 instead of 8 HBM copies.
__global__ __launch_bounds__(256) void attn_kernel(
    const u16* __restrict__ Qb0, const u16* __restrict__ Qb1, const u16* __restrict__ Qb2,
    const u16* __restrict__ Kb0, const u16* __restrict__ Kb1, const u16* __restrict__ Kb2,
    const u16* __restrict__ gV0, const u16* __restrict__ gV1,
    const float* __restrict__ x2q, const float* __restrict__ y2g, const float* __restrict__ gm1,
    const float* __restrict__ sigma_raw, const float* __restrict__ curv_raw,
    u16* __restrict__ Oh, u16* __restrict__ Ol)
{
    __shared__ u16 wb_hi[4][16][64];
    __shared__ u16 wb_lo[4][16][64];

    const int blk = blockIdx.x;
    // XCD swizzle (8 XCDs, 1728 = 8 * 216 blocks, 216 = 24 bh-groups * 9 qt)
    const int xcd = blk & 7;
    const int serial = blk >> 3;
    const int bhg = serial / 9;
    const int qt = serial - bhg * 9;
    const int bh = bhg * 8 + xcd;
    const int b = bh / 12, h = bh % 12;
    const float c  = softplus_f(curv_raw[0]);
    const float sc = sqrtf(c);
    const float sig = softplus_f(sigma_raw[h]) + 1e-6f;
    const float coef = -2.f / (c * sig * sig);

    const int tid = threadIdx.x;
    const int w = tid >> 6, lane = tid & 63;
    const int lr = lane & 15, lg = lane >> 4, lo8 = lg * 8;

    const size_t qbase = (size_t)bh * 576 + qt * 64;
    const size_t kvbase = (size_t)bh * 704;

    // Q A-frags (3 components x 2 k-halves)
    bf16x8 aQh[2], aQm[2], aQl[2];
    {
        const size_t qrow = (qbase + w * 16 + lr) * 64;
#pragma unroll
        for (int kt = 0; kt < 2; ++kt) {
            const size_t o = qrow + kt * 32 + lo8;
            aQh[kt] = *(const bf16x8*)(Qb0 + o);
            aQm[kt] = *(const bf16x8*)(Qb1 + o);
            aQl[kt] = *(const bf16x8*)(Qb2 + o);
        }
    }
    float x2r[4];
#pragma unroll
    for (int r = 0; r < 4; ++r) x2r[r] = x2q[qbase + w * 16 + lg * 4 + r];

    f32x4 pv[4];
#pragma unroll
    for (int i = 0; i < 4; ++i) pv[i] = (f32x4){0.f, 0.f, 0.f, 0.f};
    float den[4] = {0.f, 0.f, 0.f, 0.f};
    float mrow[4] = {-1e30f, -1e30f, -1e30f, -1e30f};

    u16* wbh = &wb_hi[w][0][0];
    u16* wbl = &wb_lo[w][0][0];

    for (int jt = 0; jt < 11; ++jt) {
        const int jb = jt * 64;
        f32x4 sf[4];
        float y2v[4], gm1v[4];
#pragma unroll
        for (int jf = 0; jf < 4; ++jf) {
            const size_t jrow = kvbase + jb + jf * 16 + lr;
            y2v[jf] = y2g[jrow];
            gm1v[jf] = gm1[jrow];
            const size_t rowb = jrow * 64;
            f32x4 s = (f32x4){0.f, 0.f, 0.f, 0.f};
#pragma unroll
            for (int kt = 0; kt < 2; ++kt) {
                const size_t o = rowb + kt * 32 + lo8;
                bf16x8 kh = *(const bf16x8*)(Kb0 + o);
                bf16x8 km = *(const bf16x8*)(Kb1 + o);
                bf16x8 kl = *(const bf16x8*)(Kb2 + o);
                s = __builtin_amdgcn_mfma_f32_16x16x32_bf16(aQh[kt], kh, s, 0, 0, 0);
                s = __builtin_amdgcn_mfma_f32_16x16x32_bf16(aQh[kt], km, s, 0, 0, 0);
                s = __builtin_amdgcn_mfma_f32_16x16x32_bf16(aQm[kt], kh, s, 0, 0, 0);
                s = __builtin_amdgcn_mfma_f32_16x16x32_bf16(aQm[kt], km, s, 0, 0, 0);
                s = __builtin_amdgcn_mfma_f32_16x16x32_bf16(aQh[kt], kl, s, 0, 0, 0);
                s = __builtin_amdgcn_mfma_f32_16x16x32_bf16(aQl[kt], kh, s, 0, 0, 0);
            }
            sf[jf] = s;
        }

        // xy -> logit
#pragma unroll
        for (int jf = 0; jf < 4; ++jf) {
            const float y2 = y2v[jf];
#pragma unroll
            for (int r = 0; r < 4; ++r) {
                const float x2 = x2r[r];
                const float Bc = fmaf(-c, x2, 1.f);
                float xy = sf[jf][r];
                float A = 1.f - 2.f * c * xy + c * y2;
                float num2 = A * A * x2 - 2.f * A * Bc * xy + Bc * Bc * y2;
                float dn = 1.f - 2.f * c * xy + c * c * x2 * y2;
                float arg = sc * sqrtf(fmaxf(num2, 0.f)) / fmaxf(dn, 1e-15f);
                arg = fminf(arg, 1.f - 1e-7f);
                float t = artanh_fast(arg);
                sf[jf][r] = coef * t * t;
            }
        }

        // online softmax (unnormalized), den, rescale pv
        float sclr[4];
#pragma unroll
        for (int r = 0; r < 4; ++r) {
            float tm = fmaxf(fmaxf(sf[0][r], sf[1][r]), fmaxf(sf[2][r], sf[3][r]));
#pragma unroll
            for (int msk = 1; msk < 16; msk <<= 1) tm = fmaxf(tm, __shfl_xor(tm, msk, 64));
            float mnew = fmaxf(mrow[r], tm);
            float scl = __expf(mrow[r] - mnew);
            mrow[r] = mnew; sclr[r] = scl;
            float dl = 0.f;
#pragma unroll
            for (int jf = 0; jf < 4; ++jf) {
                float wv_ = __expf(sf[jf][r] - mnew);
                sf[jf][r] = wv_;
                dl = fmaf(wv_, gm1v[jf], dl);
            }
#pragma unroll
            for (int msk = 1; msk < 16; msk <<= 1) dl += __shfl_xor(dl, msk, 64);
            den[r] = fmaf(den[r], scl, dl);
#pragma unroll
            for (int hf = 0; hf < 4; ++hf) pv[hf][r] *= scl;
        }

        // W -> wave-private LDS (hi/lo, XOR-swizzled)
#pragma unroll
        for (int r = 0; r < 4; ++r) {
            const int row = lg * 4 + r;
            const int sw = (row & 7) << 3;
#pragma unroll
            for (int jf = 0; jf < 4; ++jf) {
                const int colu = (jf * 16 + lr) ^ sw;
                float wv_ = sf[jf][r];
                u16 hb = bf16_rne(wv_);
                wbh[row * 64 + colu] = hb;
                wbl[row * 64 + colu] = bf16_rne(wv_ - bf16_tof(hb));
            }
        }

        // read W back as A-frags
        bf16x8 aWh[2], aWl[2];
        {
            const int sw = (lr & 7) << 3;
#pragma unroll
            for (int kt = 0; kt < 2; ++kt) {
                const int colu = (kt * 32 + lo8) ^ sw;
                aWh[kt] = *(const bf16x8*)(wbh + lr * 64 + colu);
                aWl[kt] = *(const bf16x8*)(wbl + lr * 64 + colu);
            }
        }

        // PV: pv += W x (gamma*V)
#pragma unroll
        for (int hf = 0; hf < 4; ++hf) {
            const size_t vrow = ((size_t)bh * 64 + hf * 16 + lr) * 704 + jb;
#pragma unroll
            for (int kt = 0; kt < 2; ++kt) {
                const size_t o = vrow + kt * 32 + lo8;
                bf16x8 vh = *(const bf16x8*)(gV0 + o);
                bf16x8 vl = *(const bf16x8*)(gV1 + o);
                pv[hf] = __builtin_amdgcn_mfma_f32_16x16x32_bf16(aWh[kt], vh, pv[hf], 0, 0, 0);
                pv[hf] = __builtin_amdgcn_mfma_f32_16x16x32_bf16(aWh[kt], vl, pv[hf], 0, 0, 0);
                pv[hf] = __builtin_amdgcn_mfma_f32_16x16x32_bf16(aWl[kt], vh, pv[hf], 0, 0, 0);
            }
        }
    }

    // epilogue: two_mean = pv/den ; O = 0.5*artanh(sc*n)/(sc*n) * two_mean
#pragma unroll
    for (int r = 0; r < 4; ++r) {
        float d = den[r];
        d = (d >= 0.f) ? fmaxf(d, 1e-10f) : fminf(d, -1e-10f);
        float rd = 1.f / d;
        float o_[4];
        float n2 = 0.f;
#pragma unroll
        for (int hf = 0; hf < 4; ++hf) { o_[hf] = pv[hf][r] * rd; n2 = fmaf(o_[hf], o_[hf], n2); }
#pragma unroll
        for (int msk = 1; msk < 16; msk <<= 1) n2 += __shfl_xor(n2, msk, 64);
        float nrm = sqrtf(fmaxf(n2, 1e-15f));
        float arg = fminf(sc * nrm, 1.f - 1e-7f);
        float t = artanh_fast(arg);
        float f = 0.5f * t / (sc * nrm);
        const int nrow = qt * 64 + w * 16 + lg * 4 + r;
        const size_t dst = ((size_t)(b * 576 + nrow)) * 768 + h * 64;
#pragma unroll
        for (int hf = 0; hf < 4; ++hf) {
            float val = o_[hf] * f;
            u16 hb = bf16_rne(val);
            Oh[dst + hf * 16 + lr] = hb;
            Ol[dst + hf * 16 + lr] = bf16_rne(val - bf16_tof(hb));
        }
    }
}

// ---------------- launcher ----------------
extern "C" void kernel_launch(void* const* d_in, const int* in_sizes, int n_in,
                              void* d_out, int out_size, void* d_ws, size_t ws_size,
                              hipStream_t stream) {
    (void)in_sizes; (void)n_in; (void)out_size; (void)ws_size;
    const float* x    = (const float*)d_in[0];
    const float* Wq   = (const float*)d_in[1];
    const float* bq   = (const float*)d_in[2];
    const float* Wk   = (const float*)d_in[3];
    const float* bk   = (const float*)d_in[4];
    const float* Wv   = (const float*)d_in[5];
    const float* bv   = (const float*)d_in[6];
    const float* Wo   = (const float*)d_in[7];
    const float* bo   = (const float*)d_in[8];
    const float* cent = (const float*)d_in[9];
    const float* curv = (const float*)d_in[10];
    const float* sigr = (const float*)d_in[11];
    float* out = (float*)d_out;

    const size_t QH  = (size_t)B_ * H_ * N_ * 64;   // 7,077,888
    const size_t KVH = (size_t)B_ * H_ * J_ * 64;   // 8,650,752
    const size_t WSZ = (size_t)D_ * D_;             // 589,824

    float* fp = (float*)d_ws;
    float* qh   = fp;            fp += QH;
    float* Khf  = fp;            fp += KVH;
    float* Vhf  = fp;            fp += KVH;
    float* x2q  = fp;            fp += (size_t)B_ * H_ * N_;
    float* y2g  = fp;            fp += (size_t)B_ * H_ * J_;
    float* gm1  = fp;            fp += (size_t)B_ * H_ * J_;
    u16* up = (u16*)fp;
    u16* xh  = up;  up += QH;     // aliased with Oh (xh dead before attn writes Oh)
    u16* xl  = up;  up += QH;     // aliased with Ol
    u16* Oh  = xh;
    u16* Ol  = xl;
    u16* Wqh = up;  up += WSZ;
    u16* Wql = up;  up += WSZ;
    u16* Wkh = up;  up += WSZ;
    u16* Wkl = up;  up += WSZ;
    u16* Wvh = up;  up += WSZ;
    u16* Wvl = up;  up += WSZ;
    u16* Woh = up;  up += WSZ;
    u16* Wol = up;  up += WSZ;
    u16* Qb  = up;  up += 3 * QH;
    u16* Kb  = up;  up += 3 * KVH;
    u16* gV  = up;  up += 2 * KVH;

    u16* Qb0 = Qb;           u16* Qb1 = Qb + QH;   u16* Qb2 = Qb + 2 * QH;
    u16* Kb0 = Kb;           u16* Kb1 = Kb + KVH;  u16* Kb2 = Kb + 2 * KVH;
    u16* gV0 = gV;           u16* gV1 = gV + KVH;

    // 0: hi/lo splits of x and weights
    split_bf16_kernel<<<(int)(QH / 4 + 255) / 256, 256, 0, stream>>>(x, xh, xl, (int)(QH / 4));
    split_bf16_kernel<<<(int)(WSZ / 4 + 255) / 256, 256, 0, stream>>>(Wq, Wqh, Wql, (int)(WSZ / 4));
    split_bf16_kernel<<<(int)(WSZ / 4 + 255) / 256, 256, 0, stream>>>(Wk, Wkh, Wkl, (int)(WSZ / 4));
    split_bf16_kernel<<<(int)(WSZ / 4 + 255) / 256, 256, 0, stream>>>(Wv, Wvh, Wvl, (int)(WSZ / 4));
    split_bf16_kernel<<<(int)(WSZ / 4 + 255) / 256, 256, 0, stream>>>(Wo, Woh, Wol, (int)(WSZ / 4));

    // 1: QKV projections (MFMA)
    gemm_qkv_mfma<<<dim3(72, 18), 256, 0, stream>>>(xh, xl, Wqh, Wql, Wkh, Wkl, Wvh, Wvl,
                                                    bq, bk, bv, qh, Khf, Vhf);
    // 2,3: hyperbolic maps -> MFMA-ready operands
    expmap_q_kernel<<<27648, 256, 0, stream>>>(qh, Qb0, Qb1, Qb2, x2q, curv);
    build_kv_kernel<<<2112, 256, 0, stream>>>(Khf, Vhf, cent, Kb0, Kb1, Kb2, gV0, gV1,
                                              y2g, gm1, curv);
    // 4: fused attention (MFMA, barrier-free, XCD-affine)
    attn_kernel<<<1728, 256, 0, stream>>>(Qb0, Qb1, Qb2, Kb0, Kb1, Kb2, gV0, gV1,
                                          x2q, y2g, gm1, sigr, curv, Oh, Ol);
    // 5: output projection (MFMA)
    gemm_o_mfma<<<dim3(72, 6), 256, 0, stream>>>(Oh, Ol, Woh, Wol, bo, out);
}

// Round 5
// 596.748 us; speedup vs baseline: 2.2380x; 1.2628x over previous
//
#include <hip/hip_runtime.h>
#include <cstdint>
#include <cstddef>

#define B_  16
#define N_  576
#define D_  768
#define H_  12
#define HD_ 64
#define M_  128
#define J_  704   // N_ + M_

typedef unsigned short u16;
typedef __attribute__((ext_vector_type(8))) short bf16x8;
typedef __attribute__((ext_vector_type(4))) float f32x4;
typedef __attribute__((ext_vector_type(4))) unsigned short u16x4;
typedef __attribute__((ext_vector_type(8))) unsigned short u16x8;

// ---------------- helpers ----------------

__device__ __forceinline__ float softplus_f(float x) {
    return (x > 20.f) ? x : log1pf(expf(x));
}

__device__ __forceinline__ float wred_sum64(float v) {
#pragma unroll
    for (int m = 1; m < 64; m <<= 1) v += __shfl_xor(v, m, 64);
    return v;
}

__device__ __forceinline__ u16 bf16_rne(float f) {
    unsigned int u = __float_as_uint(f);
    unsigned int r = u + 0x7FFFu + ((u >> 16) & 1u);
    return (u16)(r >> 16);
}
__device__ __forceinline__ float bf16_tof(u16 h) {
    return __uint_as_float(((unsigned int)h) << 16);
}

// expmap0 total multiplier for a row with raw sumsq n2; also returns final ||out||^2
__device__ __forceinline__ float expmap0_factor(float n2, float sc, float* n2out) {
    const float ATANH_1M1E5 = 6.1030335f;     // artanh(1 - 1e-5)
    float n0 = sqrtf(fmaxf(n2, 1e-15f));
    float maxtan = ATANH_1M1E5 / sc;
    float f1 = fminf(1.f, maxtan / n0);       // pre-clip
    float n1 = n0 * f1;
    float a  = sc * n1;
    float th = tanhf(a);
    float yfac  = th / a;                     // y = u * f1 * yfac
    float ynorm = th / sc;
    float lim   = (1.f - 1e-5f) / sc;
    float f2 = fminf(1.f, lim / ynorm);       // post-clip
    float fn = ynorm * f2;
    *n2out = fn * fn;
    return f1 * yfac * f2;
}

__device__ __forceinline__ float artanh_fast(float z) {  // z in [0, 1-1e-7]
    return 0.5f * __logf((1.f + z) / (1.f - z));
}

// global -> LDS direct copy, 16B per lane (wave-uniform LDS base + lane*16)
typedef const __attribute__((address_space(1))) unsigned int* gas_u32;
typedef __attribute__((address_space(3))) unsigned int* las_u32;
__device__ __forceinline__ void gload_lds16(const u16* g, u16* l) {
    __builtin_amdgcn_global_load_lds((gas_u32)(const void*)g, (las_u32)(void*)l, 16, 0, 0);
}

// ---------------- kernel 0: f32 -> bf16 hi/lo split ----------------
__global__ __launch_bounds__(256) void split_bf16_kernel(
    const float* __restrict__ src, u16* __restrict__ hi, u16* __restrict__ lo, int n4)
{
    int i = blockIdx.x * 256 + threadIdx.x;
    if (i >= n4) return;
    float4 v = ((const float4*)src)[i];
    u16x4 h, l;
    h[0] = bf16_rne(v.x); l[0] = bf16_rne(v.x - bf16_tof(h[0]));
    h[1] = bf16_rne(v.y); l[1] = bf16_rne(v.y - bf16_tof(h[1]));
    h[2] = bf16_rne(v.z); l[2] = bf16_rne(v.z - bf16_tof(h[2]));
    h[3] = bf16_rne(v.w); l[3] = bf16_rne(v.w - bf16_tof(h[3]));
    ((u16x4*)hi)[i] = h;
    ((u16x4*)lo)[i] = l;
}

// ---------------- kernel 1: QKV projection (split-bf16 MFMA) ----------------
__global__ __launch_bounds__(256) void gemm_qkv_mfma(
    const u16* __restrict__ xh, const u16* __restrict__ xl,
    const u16* __restrict__ Wh0, const u16* __restrict__ Wl0,
    const u16* __restrict__ Wh1, const u16* __restrict__ Wl1,
    const u16* __restrict__ Wh2, const u16* __restrict__ Wl2,
    const float* __restrict__ bq, const float* __restrict__ bk, const float* __restrict__ bv,
    float* __restrict__ qh_o, float* __restrict__ Kh_o, float* __restrict__ Vh_o)
{
    __shared__ u16 Ah[4096], Al[4096], Bh[4096], Bl[4096];   // 8 frags x 512 each
    const int tid = threadIdx.x;
    const int w = tid >> 6, lane = tid & 63;
    const int wr = w >> 1, wc = w & 1;
    const int lrow = lane & 15, lk8 = (lane >> 4) << 3;
    const int mt = blockIdx.x, yb = blockIdx.y;
    const int which = yb / 6, ct = yb - which * 6;
    const u16* Bp_h = which == 0 ? Wh0 : (which == 1 ? Wh1 : Wh2);
    const u16* Bp_l = which == 0 ? Wl0 : (which == 1 ? Wl1 : Wl2);
    const int row0 = mt * 128, col0 = ct * 128;

    const size_t a0 = (size_t)(row0 + (2 * w + 0) * 16 + lrow) * 768 + lk8;
    const size_t a1 = a0 + 16 * 768;
    const size_t b0 = (size_t)(col0 + (2 * w + 0) * 16 + lrow) * 768 + lk8;
    const size_t b1 = b0 + 16 * 768;
    u16* lAh0 = Ah + (2 * w) * 512; u16* lAh1 = lAh0 + 512;
    u16* lAl0 = Al + (2 * w) * 512; u16* lAl1 = lAl0 + 512;
    u16* lBh0 = Bh + (2 * w) * 512; u16* lBh1 = lBh0 + 512;
    u16* lBl0 = Bl + (2 * w) * 512; u16* lBl1 = lBl0 + 512;

    f32x4 acc[4][4];
#pragma unroll
    for (int i = 0; i < 4; ++i)
#pragma unroll
        for (int j = 0; j < 4; ++j) acc[i][j] = (f32x4){0.f, 0.f, 0.f, 0.f};

    for (int k0 = 0; k0 < 768; k0 += 32) {
        gload_lds16(xh + a0 + k0, lAh0);
        gload_lds16(xh + a1 + k0, lAh1);
        gload_lds16(xl + a0 + k0, lAl0);
        gload_lds16(xl + a1 + k0, lAl1);
        gload_lds16(Bp_h + b0 + k0, lBh0);
        gload_lds16(Bp_h + b1 + k0, lBh1);
        gload_lds16(Bp_l + b0 + k0, lBl0);
        gload_lds16(Bp_l + b1 + k0, lBl1);
        __syncthreads();
        bf16x8 aH[4], aL[4], bH[4], bL[4];
        const int lo8 = lane * 8;
#pragma unroll
        for (int i = 0; i < 4; ++i) {
            aH[i] = *(const bf16x8*)(Ah + (wr * 4 + i) * 512 + lo8);
            aL[i] = *(const bf16x8*)(Al + (wr * 4 + i) * 512 + lo8);
            bH[i] = *(const bf16x8*)(Bh + (wc * 4 + i) * 512 + lo8);
            bL[i] = *(const bf16x8*)(Bl + (wc * 4 + i) * 512 + lo8);
        }
#pragma unroll
        for (int mi = 0; mi < 4; ++mi)
#pragma unroll
            for (int ni = 0; ni < 4; ++ni) {
                acc[mi][ni] = __builtin_amdgcn_mfma_f32_16x16x32_bf16(aH[mi], bH[ni], acc[mi][ni], 0, 0, 0);
                acc[mi][ni] = __builtin_amdgcn_mfma_f32_16x16x32_bf16(aH[mi], bL[ni], acc[mi][ni], 0, 0, 0);
                acc[mi][ni] = __builtin_amdgcn_mfma_f32_16x16x32_bf16(aL[mi], bH[ni], acc[mi][ni], 0, 0, 0);
            }
        __syncthreads();
    }

    const float* bias = which == 0 ? bq : (which == 1 ? bk : bv);
    const int h = ct * 2 + wc;
    const int rbase = row0 + wr * 64 + ((lane >> 4) << 2);
#pragma unroll
    for (int ni = 0; ni < 4; ++ni) {
        const int hd = ni * 16 + lrow;
        const float bv_ = bias[h * 64 + hd];
#pragma unroll
        for (int mi = 0; mi < 4; ++mi) {
            f32x4 a = acc[mi][ni];
#pragma unroll
            for (int r = 0; r < 4; ++r) {
                int row = rbase + mi * 16 + r;
                int bb = row / 576;
                int nn = row - bb * 576;
                float val = a[r] + bv_;
                if (which == 0)
                    qh_o[(((size_t)(bb * 12 + h)) * 576 + nn) * 64 + hd] = val;
                else if (which == 1)
                    Kh_o[(((size_t)(bb * 12 + h)) * 704 + nn) * 64 + hd] = val;
                else
                    Vh_o[(((size_t)(bb * 12 + h)) * 704 + nn) * 64 + hd] = val;
            }
        }
    }
}

// ---------------- kernel 5: output projection (split-bf16 MFMA) ----------------
__global__ __launch_bounds__(256) void gemm_o_mfma(
    const u16* __restrict__ Oh, const u16* __restrict__ Ol,
    const u16* __restrict__ Wh, const u16* __restrict__ Wl,
    const float* __restrict__ bo, float* __restrict__ out)
{
    __shared__ u16 Ah[4096], Al[4096], Bh[4096], Bl[4096];
    const int tid = threadIdx.x;
    const int w = tid >> 6, lane = tid & 63;
    const int wr = w >> 1, wc = w & 1;
    const int lrow = lane & 15, lk8 = (lane >> 4) << 3;
    const int mt = blockIdx.x, ct = blockIdx.y;
    const int row0 = mt * 128, col0 = ct * 128;

    const size_t a0 = (size_t)(row0 + (2 * w + 0) * 16 + lrow) * 768 + lk8;
    const size_t a1 = a0 + 16 * 768;
    const size_t b0 = (size_t)(col0 + (2 * w + 0) * 16 + lrow) * 768 + lk8;
    const size_t b1 = b0 + 16 * 768;
    u16* lAh0 = Ah + (2 * w) * 512; u16* lAh1 = lAh0 + 512;
    u16* lAl0 = Al + (2 * w) * 512; u16* lAl1 = lAl0 + 512;
    u16* lBh0 = Bh + (2 * w) * 512; u16* lBh1 = lBh0 + 512;
    u16* lBl0 = Bl + (2 * w) * 512; u16* lBl1 = lBl0 + 512;

    f32x4 acc[4][4];
#pragma unroll
    for (int i = 0; i < 4; ++i)
#pragma unroll
        for (int j = 0; j < 4; ++j) acc[i][j] = (f32x4){0.f, 0.f, 0.f, 0.f};

    for (int k0 = 0; k0 < 768; k0 += 32) {
        gload_lds16(Oh + a0 + k0, lAh0);
        gload_lds16(Oh + a1 + k0, lAh1);
        gload_lds16(Ol + a0 + k0, lAl0);
        gload_lds16(Ol + a1 + k0, lAl1);
        gload_lds16(Wh + b0 + k0, lBh0);
        gload_lds16(Wh + b1 + k0, lBh1);
        gload_lds16(Wl + b0 + k0, lBl0);
        gload_lds16(Wl + b1 + k0, lBl1);
        __syncthreads();
        bf16x8 aH[4], aL[4], bH[4], bL[4];
        const int lo8 = lane * 8;
#pragma unroll
        for (int i = 0; i < 4; ++i) {
            aH[i] = *(const bf16x8*)(Ah + (wr * 4 + i) * 512 + lo8);
            aL[i] = *(const bf16x8*)(Al + (wr * 4 + i) * 512 + lo8);
            bH[i] = *(const bf16x8*)(Bh + (wc * 4 + i) * 512 + lo8);
            bL[i] = *(const bf16x8*)(Bl + (wc * 4 + i) * 512 + lo8);
        }
#pragma unroll
        for (int mi = 0; mi < 4; ++mi)
#pragma unroll
            for (int ni = 0; ni < 4; ++ni) {
                acc[mi][ni] = __builtin_amdgcn_mfma_f32_16x16x32_bf16(aH[mi], bH[ni], acc[mi][ni], 0, 0, 0);
                acc[mi][ni] = __builtin_amdgcn_mfma_f32_16x16x32_bf16(aH[mi], bL[ni], acc[mi][ni], 0, 0, 0);
                acc[mi][ni] = __builtin_amdgcn_mfma_f32_16x16x32_bf16(aL[mi], bH[ni], acc[mi][ni], 0, 0, 0);
            }
        __syncthreads();
    }

    const int rbase = row0 + wr * 64 + ((lane >> 4) << 2);
#pragma unroll
    for (int ni = 0; ni < 4; ++ni) {
        const int colg = col0 + wc * 64 + ni * 16 + lrow;
        const float bv_ = bo[colg];
#pragma unroll
        for (int mi = 0; mi < 4; ++mi) {
            f32x4 a = acc[mi][ni];
#pragma unroll
            for (int r = 0; r < 4; ++r) {
                int row = rbase + mi * 16 + r;
                out[(size_t)row * 768 + colg] = a[r] + bv_;
            }
        }
    }
}

// ---------------- kernel 2: expmap0 on q -> 3-plane bf16 split + x2 ----------------
__global__ __launch_bounds__(256) void expmap_q_kernel(
    const float* __restrict__ qh, u16* __restrict__ Qb0, u16* __restrict__ Qb1,
    u16* __restrict__ Qb2, float* __restrict__ x2q, const float* __restrict__ curv_raw)
{
    const float c  = softplus_f(curv_raw[0]);
    const float sc = sqrtf(c);
    const int wid = threadIdx.x >> 6, lane = threadIdx.x & 63;
    const int row = blockIdx.x * 4 + wid;          // < B*H*N
    const size_t off = (size_t)row * 64 + lane;
    float u = qh[off];
    float n2 = wred_sum64(u * u);
    float n2o;
    float f = expmap0_factor(n2, sc, &n2o);
    float y = u * f;
    u16 h = bf16_rne(y);
    float r1 = y - bf16_tof(h);
    u16 m = bf16_rne(r1);
    u16 l = bf16_rne(r1 - bf16_tof(m));
    Qb0[off] = h; Qb1[off] = m; Qb2[off] = l;
    if (lane == 0) x2q[row] = n2o;
}

// ---------------- kernel 3: build K (3-plane bf16) + transposed gamma*V (2-plane) ----------------
__global__ __launch_bounds__(256) void build_kv_kernel(
    const float* __restrict__ Khf, const float* __restrict__ Vhf, const float* __restrict__ cent,
    u16* __restrict__ Kb0, u16* __restrict__ Kb1, u16* __restrict__ Kb2,
    u16* __restrict__ gV0, u16* __restrict__ gV1,
    float* __restrict__ y2g, float* __restrict__ gm1,
    const float* __restrict__ curv_raw)
{
    __shared__ float gvt_s[64][65];
    const float c  = softplus_f(curv_raw[0]);
    const float sc = sqrtf(c);
    const int bx = blockIdx.x;
    const int bh = bx / 11, jt = bx - bh * 11;
    const int h = bh % 12;
    const int w = threadIdx.x >> 6, lane = threadIdx.x & 63;

#pragma unroll 4
    for (int i = 0; i < 16; ++i) {
        const int j = jt * 64 + w * 16 + i;
        const size_t g = (size_t)bh * 704 + j;
        float kx, vx;
        if (j < 576) { kx = Khf[g * 64 + lane]; vx = Vhf[g * 64 + lane]; }
        else         { float cv = cent[(((size_t)h) * 128 + (j - 576)) * 64 + lane]; kx = cv; vx = cv; }
        float n2k = wred_sum64(kx * kx);
        float n2v = wred_sum64(vx * vx);
        float y2o, v2o;
        float fk = expmap0_factor(n2k, sc, &y2o);
        float fv = expmap0_factor(n2v, sc, &v2o);
        float ky = kx * fk;
        u16 kh = bf16_rne(ky);
        float r1 = ky - bf16_tof(kh);
        u16 km = bf16_rne(r1);
        u16 kl = bf16_rne(r1 - bf16_tof(km));
        Kb0[g * 64 + lane] = kh; Kb1[g * 64 + lane] = km; Kb2[g * 64 + lane] = kl;
        float gmm = 2.f / fmaxf(1.f - c * v2o, 1e-15f);
        gvt_s[lane][w * 16 + i] = vx * fv * gmm;
        if (lane == 0) { y2g[g] = y2o; gm1[g] = gmm - 1.f; }
    }
    __syncthreads();
    // write out transposed gamma*V tile: [bh][hd][704]
    const int hd = threadIdx.x >> 2, j0 = (threadIdx.x & 3) * 16;
    u16 hb[16], lb[16];
#pragma unroll
    for (int e = 0; e < 16; ++e) {
        float v = gvt_s[hd][j0 + e];
        hb[e] = bf16_rne(v);
        lb[e] = bf16_rne(v - bf16_tof(hb[e]));
    }
    const size_t dst = ((size_t)bh * 64 + hd) * 704 + jt * 64 + j0;
    *(u16x8*)(gV0 + dst)     = *(u16x8*)&hb[0];
    *(u16x8*)(gV0 + dst + 8) = *(u16x8*)&hb[8];
    *(u16x8*)(gV1 + dst)     = *(u16x8*)&lb[0];
    *(u16x8*)(gV1 + dst + 8) = *(u16x8*)&lb[8];
}

// ---------------- kernel 4: fused hyperbolic attention (MFMA, LDS-staged K/V) ----------------
// Block = (bh, qtile of 64 rows); 4 waves x 16 q-rows sharing LDS-staged K/gammaV.
// K double-buffered (prefetch next tile during S-phase); gammaV staged at iter top,
// consumed after mid-iteration barrier. XOR-swizzled LDS (inverse-swizzled global src).
__global__ __launch_bounds__(256) void attn_kernel(
    const u16* __restrict__ Qb0, const u16* __restrict__ Qb1, const u16* __restrict__ Qb2,
    const u16* __restrict__ Kb0, const u16* __restrict__ Kb1, const u16* __restrict__ Kb2,
    const u16* __restrict__ gV0, const u16* __restrict__ gV1,
    const float* __restrict__ x2q, const float* __restrict__ y2g, const float* __restrict__ gm1,
    const float* __restrict__ sigma_raw, const float* __restrict__ curv_raw,
    u16* __restrict__ Oh, u16* __restrict__ Ol)
{
    __shared__ __align__(16) u16 Kst[2][3][4096];  // [buf][plane][row*64 + swizzled col]
    __shared__ __align__(16) u16 Vst[2][4096];     // [plane][row*64 + swizzled col]
    __shared__ __align__(16) u16 wb_hi[4][1024];
    __shared__ __align__(16) u16 wb_lo[4][1024];

    const int blk = blockIdx.x;
    // XCD swizzle (8 XCDs, 1728 = 8 * 216 blocks, 216 = 24 bh-groups * 9 qt)
    const int xcd = blk & 7;
    const int serial = blk >> 3;
    const int bhg = serial / 9;
    const int qt = serial - bhg * 9;
    const int bh = bhg * 8 + xcd;
    const int b = bh / 12, h = bh % 12;
    const float c  = softplus_f(curv_raw[0]);
    const float sc = sqrtf(c);
    const float sig = softplus_f(sigma_raw[h]) + 1e-6f;
    const float coef = -2.f / (c * sig * sig);

    const int tid = threadIdx.x;
    const int w = tid >> 6, lane = tid & 63;
    const int lr = lane & 15, lg = lane >> 4, lo8 = lg * 8;
    const int swl = (lr & 7) << 3;

    const size_t qbase = (size_t)bh * 576 + qt * 64;
    const size_t kvbase = (size_t)bh * 704;

    // staging geometry: chunk c = (rr*4 + w)*64 + lane covers LDS row c>>3, col (c&7)*8;
    // source col is inverse-swizzled: 8*((c&7) ^ (row&7))
    int srow[2], scol[2];
#pragma unroll
    for (int rr = 0; rr < 2; ++rr) {
        int cch = (rr * 4 + w) * 64 + lane;
        srow[rr] = cch >> 3;
        scol[rr] = ((cch & 7) ^ (srow[rr] & 7)) << 3;
    }
    const u16* K0r = Kb0 + kvbase * 64;
    const u16* K1r = Kb1 + kvbase * 64;
    const u16* K2r = Kb2 + kvbase * 64;
    const u16* V0r = gV0 + (size_t)bh * 64 * 704;
    const u16* V1r = gV1 + (size_t)bh * 64 * 704;

    // Q A-frags (3 components x 2 k-halves)
    bf16x8 aQh[2], aQm[2], aQl[2];
    {
        const size_t qrow = (qbase + w * 16 + lr) * 64;
#pragma unroll
        for (int kt = 0; kt < 2; ++kt) {
            const size_t o = qrow + kt * 32 + lo8;
            aQh[kt] = *(const bf16x8*)(Qb0 + o);
            aQm[kt] = *(const bf16x8*)(Qb1 + o);
            aQl[kt] = *(const bf16x8*)(Qb2 + o);
        }
    }
    float x2r[4];
#pragma unroll
    for (int r = 0; r < 4; ++r) x2r[r] = x2q[qbase + w * 16 + lg * 4 + r];

    f32x4 pv[4];
#pragma unroll
    for (int i = 0; i < 4; ++i) pv[i] = (f32x4){0.f, 0.f, 0.f, 0.f};
    float den[4] = {0.f, 0.f, 0.f, 0.f};
    float mrow[4] = {-1e30f, -1e30f, -1e30f, -1e30f};

    u16* wbh = &wb_hi[w][0];
    u16* wbl = &wb_lo[w][0];

    // prologue: stage K(0) into Kst[0]
#pragma unroll
    for (int rr = 0; rr < 2; ++rr) {
        const size_t so = (size_t)srow[rr] * 64 + scol[rr];
        u16* lbase0 = &Kst[0][0][(rr * 4 + w) * 512];
        u16* lbase1 = &Kst[0][1][(rr * 4 + w) * 512];
        u16* lbase2 = &Kst[0][2][(rr * 4 + w) * 512];
        gload_lds16(K0r + so, lbase0);
        gload_lds16(K1r + so, lbase1);
        gload_lds16(K2r + so, lbase2);
    }
    __syncthreads();

    int cur = 0;
    for (int jt = 0; jt < 11; ++jt) {
        const int jb = jt * 64;

        // prefetch next K tile into Kst[cur^1] (drains at mid-iter barrier)
        if (jt < 10) {
#pragma unroll
            for (int rr = 0; rr < 2; ++rr) {
                const size_t so = (size_t)(jb + 64 + srow[rr]) * 64 + scol[rr];
                gload_lds16(K0r + so, &Kst[cur ^ 1][0][(rr * 4 + w) * 512]);
                gload_lds16(K1r + so, &Kst[cur ^ 1][1][(rr * 4 + w) * 512]);
                gload_lds16(K2r + so, &Kst[cur ^ 1][2][(rr * 4 + w) * 512]);
            }
        }
        // stage gammaV for this tile (consumed after mid-iter barrier)
#pragma unroll
        for (int rr = 0; rr < 2; ++rr) {
            const size_t so = (size_t)srow[rr] * 704 + jb + scol[rr];
            gload_lds16(V0r + so, &Vst[0][(rr * 4 + w) * 512]);
            gload_lds16(V1r + so, &Vst[1][(rr * 4 + w) * 512]);
        }

        // ---- S-phase: QK^T from Kst[cur]
        const u16* kp0 = &Kst[cur][0][0];
        const u16* kp1 = &Kst[cur][1][0];
        const u16* kp2 = &Kst[cur][2][0];
        f32x4 sf[4];
        float y2v[4], gm1v[4];
#pragma unroll
        for (int jf = 0; jf < 4; ++jf) {
            const size_t jrow = kvbase + jb + jf * 16 + lr;
            y2v[jf] = y2g[jrow];
            gm1v[jf] = gm1[jrow];
            const int rb = (jf * 16 + lr) * 64;
            f32x4 s = (f32x4){0.f, 0.f, 0.f, 0.f};
#pragma unroll
            for (int kt = 0; kt < 2; ++kt) {
                const int o = rb + ((kt * 32 + lo8) ^ swl);
                bf16x8 kh = *(const bf16x8*)(kp0 + o);
                bf16x8 km = *(const bf16x8*)(kp1 + o);
                bf16x8 kl = *(const bf16x8*)(kp2 + o);
                s = __builtin_amdgcn_mfma_f32_16x16x32_bf16(aQh[kt], kh, s, 0, 0, 0);
                s = __builtin_amdgcn_mfma_f32_16x16x32_bf16(aQh[kt], km, s, 0, 0, 0);
                s = __builtin_amdgcn_mfma_f32_16x16x32_bf16(aQm[kt], kh, s, 0, 0, 0);
                s = __builtin_amdgcn_mfma_f32_16x16x32_bf16(aQm[kt], km, s, 0, 0, 0);
                s = __builtin_amdgcn_mfma_f32_16x16x32_bf16(aQh[kt], kl, s, 0, 0, 0);
                s = __builtin_amdgcn_mfma_f32_16x16x32_bf16(aQl[kt], kh, s, 0, 0, 0);
            }
            sf[jf] = s;
        }

        // ---- xy -> logit
#pragma unroll
        for (int jf = 0; jf < 4; ++jf) {
            const float y2 = y2v[jf];
#pragma unroll
            for (int r = 0; r < 4; ++r) {
                const float x2 = x2r[r];
                const float Bc = fmaf(-c, x2, 1.f);
                float xy = sf[jf][r];
                float A = 1.f - 2.f * c * xy + c * y2;
                float num2 = A * A * x2 - 2.f * A * Bc * xy + Bc * Bc * y2;
                float dn = 1.f - 2.f * c * xy + c * c * x2 * y2;
                float arg = sc * sqrtf(fmaxf(num2, 0.f)) / fmaxf(dn, 1e-15f);
                arg = fminf(arg, 1.f - 1e-7f);
                float t = artanh_fast(arg);
                sf[jf][r] = coef * t * t;
            }
        }

        // ---- online softmax (unnormalized), den, rescale pv
        float sclr[4];
#pragma unroll
        for (int r = 0; r < 4; ++r) {
            float tm = fmaxf(fmaxf(sf[0][r], sf[1][r]), fmaxf(sf[2][r], sf[3][r]));
#pragma unroll
            for (int msk = 1; msk < 16; msk <<= 1) tm = fmaxf(tm, __shfl_xor(tm, msk, 64));
            float mnew = fmaxf(mrow[r], tm);
            float scl = __expf(mrow[r] - mnew);
            mrow[r] = mnew; sclr[r] = scl;
            float dl = 0.f;
#pragma unroll
            for (int jf = 0; jf < 4; ++jf) {
                float wv_ = __expf(sf[jf][r] - mnew);
                sf[jf][r] = wv_;
                dl = fmaf(wv_, gm1v[jf], dl);
            }
#pragma unroll
            for (int msk = 1; msk < 16; msk <<= 1) dl += __shfl_xor(dl, msk, 64);
            den[r] = fmaf(den[r], scl, dl);
#pragma unroll
            for (int hf = 0; hf < 4; ++hf) pv[hf][r] *= scl;
        }

        // ---- W -> wave-private LDS (hi/lo, XOR-swizzled)
#pragma unroll
        for (int r = 0; r < 4; ++r) {
            const int row = lg * 4 + r;
            const int sw = (row & 7) << 3;
#pragma unroll
            for (int jf = 0; jf < 4; ++jf) {
                const int colu = (jf * 16 + lr) ^ sw;
                float wv_ = sf[jf][r];
                u16 hb = bf16_rne(wv_);
                wbh[row * 64 + colu] = hb;
                wbl[row * 64 + colu] = bf16_rne(wv_ - bf16_tof(hb));
            }
        }

        __syncthreads();   // V staged (vmcnt drained); K prefetch also landed

        // ---- read W back as A-frags
        bf16x8 aWh[2], aWl[2];
#pragma unroll
        for (int kt = 0; kt < 2; ++kt) {
            const int colu = (kt * 32 + lo8) ^ swl;
            aWh[kt] = *(const bf16x8*)(wbh + lr * 64 + colu);
            aWl[kt] = *(const bf16x8*)(wbl + lr * 64 + colu);
        }

        // ---- PV: pv += W x (gamma*V) from Vst
#pragma unroll
        for (int hf = 0; hf < 4; ++hf) {
            const int rb = (hf * 16 + lr) * 64;
#pragma unroll
            for (int kt = 0; kt < 2; ++kt) {
                const int o = rb + ((kt * 32 + lo8) ^ swl);
                bf16x8 vh = *(const bf16x8*)(&Vst[0][o]);
                bf16x8 vl = *(const bf16x8*)(&Vst[1][o]);
                pv[hf] = __builtin_amdgcn_mfma_f32_16x16x32_bf16(aWh[kt], vh, pv[hf], 0, 0, 0);
                pv[hf] = __builtin_amdgcn_mfma_f32_16x16x32_bf16(aWh[kt], vl, pv[hf], 0, 0, 0);
                pv[hf] = __builtin_amdgcn_mfma_f32_16x16x32_bf16(aWl[kt], vh, pv[hf], 0, 0, 0);
            }
        }

        __syncthreads();   // all waves done with Vst & Kst[cur] before restage
        cur ^= 1;
    }

    // ---- epilogue: two_mean = pv/den ; O = 0.5*artanh(sc*n)/(sc*n) * two_mean
#pragma unroll
    for (int r = 0; r < 4; ++r) {
        float d = den[r];
        d = (d >= 0.f) ? fmaxf(d, 1e-10f) : fminf(d, -1e-10f);
        float rd = 1.f / d;
        float o_[4];
        float n2 = 0.f;
#pragma unroll
        for (int hf = 0; hf < 4; ++hf) { o_[hf] = pv[hf][r] * rd; n2 = fmaf(o_[hf], o_[hf], n2); }
#pragma unroll
        for (int msk = 1; msk < 16; msk <<= 1) n2 += __shfl_xor(n2, msk, 64);
        float nrm = sqrtf(fmaxf(n2, 1e-15f));
        float arg = fminf(sc * nrm, 1.f - 1e-7f);
        float t = artanh_fast(arg);
        float f = 0.5f * t / (sc * nrm);
        const int nrow = qt * 64 + w * 16 + lg * 4 + r;
        const size_t dst = ((size_t)(b * 576 + nrow)) * 768 + h * 64;
#pragma unroll
        for (int hf = 0; hf < 4; ++hf) {
            float val = o_[hf] * f;
            u16 hb = bf16_rne(val);
            Oh[dst + hf * 16 + lr] = hb;
            Ol[dst + hf * 16 + lr] = bf16_rne(val - bf16_tof(hb));
        }
    }
}

// ---------------- launcher ----------------
extern "C" void kernel_launch(void* const* d_in, const int* in_sizes, int n_in,
                              void* d_out, int out_size, void* d_ws, size_t ws_size,
                              hipStream_t stream) {
    (void)in_sizes; (void)n_in; (void)out_size; (void)ws_size;
    const float* x    = (const float*)d_in[0];
    const float* Wq   = (const float*)d_in[1];
    const float* bq   = (const float*)d_in[2];
    const float* Wk   = (const float*)d_in[3];
    const float* bk   = (const float*)d_in[4];
    const float* Wv   = (const float*)d_in[5];
    const float* bv   = (const float*)d_in[6];
    const float* Wo   = (const float*)d_in[7];
    const float* bo   = (const float*)d_in[8];
    const float* cent = (const float*)d_in[9];
    const float* curv = (const float*)d_in[10];
    const float* sigr = (const float*)d_in[11];
    float* out = (float*)d_out;

    const size_t QH  = (size_t)B_ * H_ * N_ * 64;   // 7,077,888
    const size_t KVH = (size_t)B_ * H_ * J_ * 64;   // 8,650,752
    const size_t WSZ = (size_t)D_ * D_;             // 589,824

    float* fp = (float*)d_ws;
    float* qh   = fp;            fp += QH;
    float* Khf  = fp;            fp += KVH;
    float* Vhf  = fp;            fp += KVH;
    float* x2q  = fp;            fp += (size_t)B_ * H_ * N_;
    float* y2g  = fp;            fp += (size_t)B_ * H_ * J_;
    float* gm1  = fp;            fp += (size_t)B_ * H_ * J_;
    u16* up = (u16*)fp;
    u16* xh  = up;  up += QH;     // aliased with Oh (xh dead before attn writes Oh)
    u16* xl  = up;  up += QH;     // aliased with Ol
    u16* Oh  = xh;
    u16* Ol  = xl;
    u16* Wqh = up;  up += WSZ;
    u16* Wql = up;  up += WSZ;
    u16* Wkh = up;  up += WSZ;
    u16* Wkl = up;  up += WSZ;
    u16* Wvh = up;  up += WSZ;
    u16* Wvl = up;  up += WSZ;
    u16* Woh = up;  up += WSZ;
    u16* Wol = up;  up += WSZ;
    u16* Qb  = up;  up += 3 * QH;
    u16* Kb  = up;  up += 3 * KVH;
    u16* gV  = up;  up += 2 * KVH;

    u16* Qb0 = Qb;           u16* Qb1 = Qb + QH;   u16* Qb2 = Qb + 2 * QH;
    u16* Kb0 = Kb;           u16* Kb1 = Kb + KVH;  u16* Kb2 = Kb + 2 * KVH;
    u16* gV0 = gV;           u16* gV1 = gV + KVH;

    // 0: hi/lo splits of x and weights
    split_bf16_kernel<<<(int)(QH / 4 + 255) / 256, 256, 0, stream>>>(x, xh, xl, (int)(QH / 4));
    split_bf16_kernel<<<(int)(WSZ / 4 + 255) / 256, 256, 0, stream>>>(Wq, Wqh, Wql, (int)(WSZ / 4));
    split_bf16_kernel<<<(int)(WSZ / 4 + 255) / 256, 256, 0, stream>>>(Wk, Wkh, Wkl, (int)(WSZ / 4));
    split_bf16_kernel<<<(int)(WSZ / 4 + 255) / 256, 256, 0, stream>>>(Wv, Wvh, Wvl, (int)(WSZ / 4));
    split_bf16_kernel<<<(int)(WSZ / 4 + 255) / 256, 256, 0, stream>>>(Wo, Woh, Wol, (int)(WSZ / 4));

    // 1: QKV projections (MFMA)
    gemm_qkv_mfma<<<dim3(72, 18), 256, 0, stream>>>(xh, xl, Wqh, Wql, Wkh, Wkl, Wvh, Wvl,
                                                    bq, bk, bv, qh, Khf, Vhf);
    // 2,3: hyperbolic maps -> MFMA-ready operands
    expmap_q_kernel<<<27648, 256, 0, stream>>>(qh, Qb0, Qb1, Qb2, x2q, curv);
    build_kv_kernel<<<2112, 256, 0, stream>>>(Khf, Vhf, cent, Kb0, Kb1, Kb2, gV0, gV1,
                                              y2g, gm1, curv);
    // 4: fused attention (MFMA, LDS-staged, XCD-affine)
    attn_kernel<<<1728, 256, 0, stream>>>(Qb0, Qb1, Qb2, Kb0, Kb1, Kb2, gV0, gV1,
                                          x2q, y2g, gm1, sigr, curv, Oh, Ol);
    // 5: output projection (MFMA)
    gemm_o_mfma<<<dim3(72, 6), 256, 0, stream>>>(Oh, Ol, Woh, Wol, bo, out);
}

// Round 7
// 508.739 us; speedup vs baseline: 2.6251x; 1.1730x over previous
//
#include <hip/hip_runtime.h>
#include <cstdint>
#include <cstddef>

#define B_  16
#define N_  576
#define D_  768
#define H_  12
#define HD_ 64
#define M_  128
#define J_  704   // N_ + M_

typedef unsigned short u16;
typedef __attribute__((ext_vector_type(8))) short bf16x8;
typedef __attribute__((ext_vector_type(4))) float f32x4;
typedef __attribute__((ext_vector_type(4))) unsigned short u16x4;
typedef __attribute__((ext_vector_type(8))) unsigned short u16x8;

// ---------------- helpers ----------------

__device__ __forceinline__ float softplus_f(float x) {
    return (x > 20.f) ? x : log1pf(expf(x));
}

__device__ __forceinline__ float wred_sum64(float v) {
#pragma unroll
    for (int m = 1; m < 64; m <<= 1) v += __shfl_xor(v, m, 64);
    return v;
}

__device__ __forceinline__ u16 bf16_rne(float f) {
    unsigned int u = __float_as_uint(f);
    unsigned int r = u + 0x7FFFu + ((u >> 16) & 1u);
    return (u16)(r >> 16);
}
__device__ __forceinline__ float bf16_tof(u16 h) {
    return __uint_as_float(((unsigned int)h) << 16);
}

// expmap0 total multiplier for a row with raw sumsq n2; also returns final ||out||^2
__device__ __forceinline__ float expmap0_factor(float n2, float sc, float* n2out) {
    const float ATANH_1M1E5 = 6.1030335f;     // artanh(1 - 1e-5)
    float n0 = sqrtf(fmaxf(n2, 1e-15f));
    float maxtan = ATANH_1M1E5 / sc;
    float f1 = fminf(1.f, maxtan / n0);       // pre-clip
    float n1 = n0 * f1;
    float a  = sc * n1;
    float th = tanhf(a);
    float yfac  = th / a;                     // y = u * f1 * yfac
    float ynorm = th / sc;
    float lim   = (1.f - 1e-5f) / sc;
    float f2 = fminf(1.f, lim / ynorm);       // post-clip
    float fn = ynorm * f2;
    *n2out = fn * fn;
    return f1 * yfac * f2;
}

__device__ __forceinline__ float artanh_fast(float z) {  // z in [0, 1-1e-7]
    return 0.5f * __logf((1.f + z) / (1.f - z));
}

// global -> LDS direct copy, 16B per lane (wave-uniform LDS base + lane*16)
typedef const __attribute__((address_space(1))) unsigned int* gas_u32;
typedef __attribute__((address_space(3))) unsigned int* las_u32;
__device__ __forceinline__ void gload_lds16(const u16* g, u16* l) {
    __builtin_amdgcn_global_load_lds((gas_u32)(const void*)g, (las_u32)(void*)l, 16, 0, 0);
}

// ---------------- kernel 0: f32 -> bf16 hi/lo split ----------------
__global__ __launch_bounds__(256) void split_bf16_kernel(
    const float* __restrict__ src, u16* __restrict__ hi, u16* __restrict__ lo, int n4)
{
    int i = blockIdx.x * 256 + threadIdx.x;
    if (i >= n4) return;
    float4 v = ((const float4*)src)[i];
    u16x4 h, l;
    h[0] = bf16_rne(v.x); l[0] = bf16_rne(v.x - bf16_tof(h[0]));
    h[1] = bf16_rne(v.y); l[1] = bf16_rne(v.y - bf16_tof(h[1]));
    h[2] = bf16_rne(v.z); l[2] = bf16_rne(v.z - bf16_tof(h[2]));
    h[3] = bf16_rne(v.w); l[3] = bf16_rne(v.w - bf16_tof(h[3]));
    ((u16x4*)hi)[i] = h;
    ((u16x4*)lo)[i] = l;
}

// ---------------- kernel 1: QKV projection (split-bf16 MFMA) ----------------
__global__ __launch_bounds__(256) void gemm_qkv_mfma(
    const u16* __restrict__ xh, const u16* __restrict__ xl,
    const u16* __restrict__ Wh0, const u16* __restrict__ Wl0,
    const u16* __restrict__ Wh1, const u16* __restrict__ Wl1,
    const u16* __restrict__ Wh2, const u16* __restrict__ Wl2,
    const float* __restrict__ bq, const float* __restrict__ bk, const float* __restrict__ bv,
    float* __restrict__ qh_o, float* __restrict__ Kh_o, float* __restrict__ Vh_o)
{
    __shared__ u16 Ah[4096], Al[4096], Bh[4096], Bl[4096];   // 8 frags x 512 each
    const int tid = threadIdx.x;
    const int w = tid >> 6, lane = tid & 63;
    const int wr = w >> 1, wc = w & 1;
    const int lrow = lane & 15, lk8 = (lane >> 4) << 3;
    const int mt = blockIdx.x, yb = blockIdx.y;
    const int which = yb / 6, ct = yb - which * 6;
    const u16* Bp_h = which == 0 ? Wh0 : (which == 1 ? Wh1 : Wh2);
    const u16* Bp_l = which == 0 ? Wl0 : (which == 1 ? Wl1 : Wl2);
    const int row0 = mt * 128, col0 = ct * 128;

    const size_t a0 = (size_t)(row0 + (2 * w + 0) * 16 + lrow) * 768 + lk8;
    const size_t a1 = a0 + 16 * 768;
    const size_t b0 = (size_t)(col0 + (2 * w + 0) * 16 + lrow) * 768 + lk8;
    const size_t b1 = b0 + 16 * 768;
    u16* lAh0 = Ah + (2 * w) * 512; u16* lAh1 = lAh0 + 512;
    u16* lAl0 = Al + (2 * w) * 512; u16* lAl1 = lAl0 + 512;
    u16* lBh0 = Bh + (2 * w) * 512; u16* lBh1 = lBh0 + 512;
    u16* lBl0 = Bl + (2 * w) * 512; u16* lBl1 = lBl0 + 512;

    f32x4 acc[4][4];
#pragma unroll
    for (int i = 0; i < 4; ++i)
#pragma unroll
        for (int j = 0; j < 4; ++j) acc[i][j] = (f32x4){0.f, 0.f, 0.f, 0.f};

    for (int k0 = 0; k0 < 768; k0 += 32) {
        gload_lds16(xh + a0 + k0, lAh0);
        gload_lds16(xh + a1 + k0, lAh1);
        gload_lds16(xl + a0 + k0, lAl0);
        gload_lds16(xl + a1 + k0, lAl1);
        gload_lds16(Bp_h + b0 + k0, lBh0);
        gload_lds16(Bp_h + b1 + k0, lBh1);
        gload_lds16(Bp_l + b0 + k0, lBl0);
        gload_lds16(Bp_l + b1 + k0, lBl1);
        __syncthreads();
        bf16x8 aH[4], aL[4], bH[4], bL[4];
        const int lo8 = lane * 8;
#pragma unroll
        for (int i = 0; i < 4; ++i) {
            aH[i] = *(const bf16x8*)(Ah + (wr * 4 + i) * 512 + lo8);
            aL[i] = *(const bf16x8*)(Al + (wr * 4 + i) * 512 + lo8);
            bH[i] = *(const bf16x8*)(Bh + (wc * 4 + i) * 512 + lo8);
            bL[i] = *(const bf16x8*)(Bl + (wc * 4 + i) * 512 + lo8);
        }
#pragma unroll
        for (int mi = 0; mi < 4; ++mi)
#pragma unroll
            for (int ni = 0; ni < 4; ++ni) {
                acc[mi][ni] = __builtin_amdgcn_mfma_f32_16x16x32_bf16(aH[mi], bH[ni], acc[mi][ni], 0, 0, 0);
                acc[mi][ni] = __builtin_amdgcn_mfma_f32_16x16x32_bf16(aH[mi], bL[ni], acc[mi][ni], 0, 0, 0);
                acc[mi][ni] = __builtin_amdgcn_mfma_f32_16x16x32_bf16(aL[mi], bH[ni], acc[mi][ni], 0, 0, 0);
            }
        __syncthreads();
    }

    const float* bias = which == 0 ? bq : (which == 1 ? bk : bv);
    const int h = ct * 2 + wc;
    const int rbase = row0 + wr * 64 + ((lane >> 4) << 2);
#pragma unroll
    for (int ni = 0; ni < 4; ++ni) {
        const int hd = ni * 16 + lrow;
        const float bv_ = bias[h * 64 + hd];
#pragma unroll
        for (int mi = 0; mi < 4; ++mi) {
            f32x4 a = acc[mi][ni];
#pragma unroll
            for (int r = 0; r < 4; ++r) {
                int row = rbase + mi * 16 + r;
                int bb = row / 576;
                int nn = row - bb * 576;
                float val = a[r] + bv_;
                if (which == 0)
                    qh_o[(((size_t)(bb * 12 + h)) * 576 + nn) * 64 + hd] = val;
                else if (which == 1)
                    Kh_o[(((size_t)(bb * 12 + h)) * 704 + nn) * 64 + hd] = val;
                else
                    Vh_o[(((size_t)(bb * 12 + h)) * 704 + nn) * 64 + hd] = val;
            }
        }
    }
}

// ---------------- kernel 5: output projection (split-bf16 MFMA) ----------------
__global__ __launch_bounds__(256) void gemm_o_mfma(
    const u16* __restrict__ Oh, const u16* __restrict__ Ol,
    const u16* __restrict__ Wh, const u16* __restrict__ Wl,
    const float* __restrict__ bo, float* __restrict__ out)
{
    __shared__ u16 Ah[4096], Al[4096], Bh[4096], Bl[4096];
    const int tid = threadIdx.x;
    const int w = tid >> 6, lane = tid & 63;
    const int wr = w >> 1, wc = w & 1;
    const int lrow = lane & 15, lk8 = (lane >> 4) << 3;
    const int mt = blockIdx.x, ct = blockIdx.y;
    const int row0 = mt * 128, col0 = ct * 128;

    const size_t a0 = (size_t)(row0 + (2 * w + 0) * 16 + lrow) * 768 + lk8;
    const size_t a1 = a0 + 16 * 768;
    const size_t b0 = (size_t)(col0 + (2 * w + 0) * 16 + lrow) * 768 + lk8;
    const size_t b1 = b0 + 16 * 768;
    u16* lAh0 = Ah + (2 * w) * 512; u16* lAh1 = lAh0 + 512;
    u16* lAl0 = Al + (2 * w) * 512; u16* lAl1 = lAl0 + 512;
    u16* lBh0 = Bh + (2 * w) * 512; u16* lBh1 = lBh0 + 512;
    u16* lBl0 = Bl + (2 * w) * 512; u16* lBl1 = lBl0 + 512;

    f32x4 acc[4][4];
#pragma unroll
    for (int i = 0; i < 4; ++i)
#pragma unroll
        for (int j = 0; j < 4; ++j) acc[i][j] = (f32x4){0.f, 0.f, 0.f, 0.f};

    for (int k0 = 0; k0 < 768; k0 += 32) {
        gload_lds16(Oh + a0 + k0, lAh0);
        gload_lds16(Oh + a1 + k0, lAh1);
        gload_lds16(Ol + a0 + k0, lAl0);
        gload_lds16(Ol + a1 + k0, lAl1);
        gload_lds16(Wh + b0 + k0, lBh0);
        gload_lds16(Wh + b1 + k0, lBh1);
        gload_lds16(Wl + b0 + k0, lBl0);
        gload_lds16(Wl + b1 + k0, lBl1);
        __syncthreads();
        bf16x8 aH[4], aL[4], bH[4], bL[4];
        const int lo8 = lane * 8;
#pragma unroll
        for (int i = 0; i < 4; ++i) {
            aH[i] = *(const bf16x8*)(Ah + (wr * 4 + i) * 512 + lo8);
            aL[i] = *(const bf16x8*)(Al + (wr * 4 + i) * 512 + lo8);
            bH[i] = *(const bf16x8*)(Bh + (wc * 4 + i) * 512 + lo8);
            bL[i] = *(const bf16x8*)(Bl + (wc * 4 + i) * 512 + lo8);
        }
#pragma unroll
        for (int mi = 0; mi < 4; ++mi)
#pragma unroll
            for (int ni = 0; ni < 4; ++ni) {
                acc[mi][ni] = __builtin_amdgcn_mfma_f32_16x16x32_bf16(aH[mi], bH[ni], acc[mi][ni], 0, 0, 0);
                acc[mi][ni] = __builtin_amdgcn_mfma_f32_16x16x32_bf16(aH[mi], bL[ni], acc[mi][ni], 0, 0, 0);
                acc[mi][ni] = __builtin_amdgcn_mfma_f32_16x16x32_bf16(aL[mi], bH[ni], acc[mi][ni], 0, 0, 0);
            }
        __syncthreads();
    }

    const int rbase = row0 + wr * 64 + ((lane >> 4) << 2);
#pragma unroll
    for (int ni = 0; ni < 4; ++ni) {
        const int colg = col0 + wc * 64 + ni * 16 + lrow;
        const float bv_ = bo[colg];
#pragma unroll
        for (int mi = 0; mi < 4; ++mi) {
            f32x4 a = acc[mi][ni];
#pragma unroll
            for (int r = 0; r < 4; ++r) {
                int row = rbase + mi * 16 + r;
                out[(size_t)row * 768 + colg] = a[r] + bv_;
            }
        }
    }
}

// ---------------- kernel 2: expmap0 on q -> 3-plane bf16 split + x2 ----------------
__global__ __launch_bounds__(256) void expmap_q_kernel(
    const float* __restrict__ qh, u16* __restrict__ Qb0, u16* __restrict__ Qb1,
    u16* __restrict__ Qb2, float* __restrict__ x2q, const float* __restrict__ curv_raw)
{
    const float c  = softplus_f(curv_raw[0]);
    const float sc = sqrtf(c);
    const int wid = threadIdx.x >> 6, lane = threadIdx.x & 63;
    const int row = blockIdx.x * 4 + wid;          // < B*H*N
    const size_t off = (size_t)row * 64 + lane;
    float u = qh[off];
    float n2 = wred_sum64(u * u);
    float n2o;
    float f = expmap0_factor(n2, sc, &n2o);
    float y = u * f;
    u16 h = bf16_rne(y);
    float r1 = y - bf16_tof(h);
    u16 m = bf16_rne(r1);
    u16 l = bf16_rne(r1 - bf16_tof(m));
    Qb0[off] = h; Qb1[off] = m; Qb2[off] = l;
    if (lane == 0) x2q[row] = n2o;
}

// ---------------- kernel 3: build K (3-plane bf16) + transposed gamma*V (2-plane) ----------------
__global__ __launch_bounds__(256) void build_kv_kernel(
    const float* __restrict__ Khf, const float* __restrict__ Vhf, const float* __restrict__ cent,
    u16* __restrict__ Kb0, u16* __restrict__ Kb1, u16* __restrict__ Kb2,
    u16* __restrict__ gV0, u16* __restrict__ gV1,
    float* __restrict__ y2g, float* __restrict__ gm1,
    const float* __restrict__ curv_raw)
{
    __shared__ float gvt_s[64][65];
    const float c  = softplus_f(curv_raw[0]);
    const float sc = sqrtf(c);
    const int bx = blockIdx.x;
    const int bh = bx / 11, jt = bx - bh * 11;
    const int h = bh % 12;
    const int w = threadIdx.x >> 6, lane = threadIdx.x & 63;

#pragma unroll 4
    for (int i = 0; i < 16; ++i) {
        const int j = jt * 64 + w * 16 + i;
        const size_t g = (size_t)bh * 704 + j;
        float kx, vx;
        if (j < 576) { kx = Khf[g * 64 + lane]; vx = Vhf[g * 64 + lane]; }
        else         { float cv = cent[(((size_t)h) * 128 + (j - 576)) * 64 + lane]; kx = cv; vx = cv; }
        float n2k = wred_sum64(kx * kx);
        float n2v = wred_sum64(vx * vx);
        float y2o, v2o;
        float fk = expmap0_factor(n2k, sc, &y2o);
        float fv = expmap0_factor(n2v, sc, &v2o);
        float ky = kx * fk;
        u16 kh = bf16_rne(ky);
        float r1 = ky - bf16_tof(kh);
        u16 km = bf16_rne(r1);
        u16 kl = bf16_rne(r1 - bf16_tof(km));
        Kb0[g * 64 + lane] = kh; Kb1[g * 64 + lane] = km; Kb2[g * 64 + lane] = kl;
        float gmm = 2.f / fmaxf(1.f - c * v2o, 1e-15f);
        gvt_s[lane][w * 16 + i] = vx * fv * gmm;
        if (lane == 0) { y2g[g] = y2o; gm1[g] = gmm - 1.f; }
    }
    __syncthreads();
    // write out transposed gamma*V tile: [bh][hd][704]
    const int hd = threadIdx.x >> 2, j0 = (threadIdx.x & 3) * 16;
    u16 hb[16], lb[16];
#pragma unroll
    for (int e = 0; e < 16; ++e) {
        float v = gvt_s[hd][j0 + e];
        hb[e] = bf16_rne(v);
        lb[e] = bf16_rne(v - bf16_tof(hb[e]));
    }
    const size_t dst = ((size_t)bh * 64 + hd) * 704 + jt * 64 + j0;
    *(u16x8*)(gV0 + dst)     = *(u16x8*)&hb[0];
    *(u16x8*)(gV0 + dst + 8) = *(u16x8*)&hb[8];
    *(u16x8*)(gV1 + dst)     = *(u16x8*)&lb[0];
    *(u16x8*)(gV1 + dst + 8) = *(u16x8*)&lb[8];
}

// ---------------- kernel 4: fused hyperbolic attention (MFMA, LDS-staged K/V) ----------------
// No online max-shift: logits <= 0 always, and every row sees the near-origin
// centroids (max logit >= -79), so unnormalized exp never underflows to zero-den;
// gamma-1 >= 1 makes the reference's den clamp inert. Softmax normalizer cancels
// in nom/den. artanh via log2-difference: no IEEE-div sequences in the hot loop.
__global__ __launch_bounds__(256) void attn_kernel(
    const u16* __restrict__ Qb0, const u16* __restrict__ Qb1, const u16* __restrict__ Qb2,
    const u16* __restrict__ Kb0, const u16* __restrict__ Kb1, const u16* __restrict__ Kb2,
    const u16* __restrict__ gV0, const u16* __restrict__ gV1,
    const float* __restrict__ x2q, const float* __restrict__ y2g, const float* __restrict__ gm1,
    const float* __restrict__ sigma_raw, const float* __restrict__ curv_raw,
    u16* __restrict__ Oh, u16* __restrict__ Ol)
{
    __shared__ __align__(16) u16 Kst[2][3][4096];  // [buf][plane][row*64 + swizzled col]
    __shared__ __align__(16) u16 Vst[2][4096];     // [plane][row*64 + swizzled col]
    __shared__ __align__(16) u16 wb_hi[4][1024];
    __shared__ __align__(16) u16 wb_lo[4][1024];

    const int blk = blockIdx.x;
    // XCD swizzle (8 XCDs, 1728 = 8 * 216 blocks, 216 = 24 bh-groups * 9 qt)
    const int xcd = blk & 7;
    const int serial = blk >> 3;
    const int bhg = serial / 9;
    const int qt = serial - bhg * 9;
    const int bh = bhg * 8 + xcd;
    const int b = bh / 12, h = bh % 12;
    const float c  = softplus_f(curv_raw[0]);
    const float sc = sqrtf(c);
    const float sig = softplus_f(sigma_raw[h]) + 1e-6f;
    const float coef = -2.f / (c * sig * sig);   // logit = coef * artanh(arg)^2
    const float c2h  = coef * 0.25f * 0.6931471805599453f;  // exp2 basis: W = 2^(c2h*td^2)
    const float m2c  = -2.f * c;
    const float CLIP = 1.f - 1e-7f;

    const int tid = threadIdx.x;
    const int w = tid >> 6, lane = tid & 63;
    const int lr = lane & 15, lg = lane >> 4, lo8 = lg * 8;
    const int swl = (lr & 7) << 3;

    const size_t qbase = (size_t)bh * 576 + qt * 64;
    const size_t kvbase = (size_t)bh * 704;

    // staging geometry: chunk c = (rr*4 + w)*64 + lane covers LDS row c>>3, col (c&7)*8;
    // source col is inverse-swizzled: 8*((c&7) ^ (row&7))
    int srow[2], scol[2];
#pragma unroll
    for (int rr = 0; rr < 2; ++rr) {
        int cch = (rr * 4 + w) * 64 + lane;
        srow[rr] = cch >> 3;
        scol[rr] = ((cch & 7) ^ (srow[rr] & 7)) << 3;
    }
    const u16* K0r = Kb0 + kvbase * 64;
    const u16* K1r = Kb1 + kvbase * 64;
    const u16* K2r = Kb2 + kvbase * 64;
    const u16* V0r = gV0 + (size_t)bh * 64 * 704;
    const u16* V1r = gV1 + (size_t)bh * 64 * 704;

    // Q A-frags (3 components x 2 k-halves)
    bf16x8 aQh[2], aQm[2], aQl[2];
    {
        const size_t qrow = (qbase + w * 16 + lr) * 64;
#pragma unroll
        for (int kt = 0; kt < 2; ++kt) {
            const size_t o = qrow + kt * 32 + lo8;
            aQh[kt] = *(const bf16x8*)(Qb0 + o);
            aQm[kt] = *(const bf16x8*)(Qb1 + o);
            aQl[kt] = *(const bf16x8*)(Qb2 + o);
        }
    }
    float x2r[4], m2Bc[4], Bc2[4], ccx2[4];
#pragma unroll
    for (int r = 0; r < 4; ++r) {
        float x2 = x2q[qbase + w * 16 + lg * 4 + r];
        float Bc = fmaf(-c, x2, 1.f);
        x2r[r] = x2; m2Bc[r] = -2.f * Bc; Bc2[r] = Bc * Bc; ccx2[r] = c * c * x2;
    }

    f32x4 pv[4];
#pragma unroll
    for (int i = 0; i < 4; ++i) pv[i] = (f32x4){0.f, 0.f, 0.f, 0.f};
    float den[4] = {0.f, 0.f, 0.f, 0.f};

    u16* wbh = &wb_hi[w][0];
    u16* wbl = &wb_lo[w][0];

    // prologue: stage K(0) into Kst[0]
#pragma unroll
    for (int rr = 0; rr < 2; ++rr) {
        const size_t so = (size_t)srow[rr] * 64 + scol[rr];
        gload_lds16(K0r + so, &Kst[0][0][(rr * 4 + w) * 512]);
        gload_lds16(K1r + so, &Kst[0][1][(rr * 4 + w) * 512]);
        gload_lds16(K2r + so, &Kst[0][2][(rr * 4 + w) * 512]);
    }
    __syncthreads();

    int cur = 0;
    for (int jt = 0; jt < 11; ++jt) {
        const int jb = jt * 64;

        // prefetch next K tile into Kst[cur^1] (drains at mid-iter barrier)
        if (jt < 10) {
#pragma unroll
            for (int rr = 0; rr < 2; ++rr) {
                const size_t so = (size_t)(jb + 64 + srow[rr]) * 64 + scol[rr];
                gload_lds16(K0r + so, &Kst[cur ^ 1][0][(rr * 4 + w) * 512]);
                gload_lds16(K1r + so, &Kst[cur ^ 1][1][(rr * 4 + w) * 512]);
                gload_lds16(K2r + so, &Kst[cur ^ 1][2][(rr * 4 + w) * 512]);
            }
        }
        // stage gammaV for this tile (consumed after mid-iter barrier)
#pragma unroll
        for (int rr = 0; rr < 2; ++rr) {
            const size_t so = (size_t)srow[rr] * 704 + jb + scol[rr];
            gload_lds16(V0r + so, &Vst[0][(rr * 4 + w) * 512]);
            gload_lds16(V1r + so, &Vst[1][(rr * 4 + w) * 512]);
        }

        // ---- S-phase: QK^T from Kst[cur]
        const u16* kp0 = &Kst[cur][0][0];
        const u16* kp1 = &Kst[cur][1][0];
        const u16* kp2 = &Kst[cur][2][0];
        f32x4 sf[4];
        float y2v[4], gm1v[4];
#pragma unroll
        for (int jf = 0; jf < 4; ++jf) {
            const size_t jrow = kvbase + jb + jf * 16 + lr;
            y2v[jf] = y2g[jrow];
            gm1v[jf] = gm1[jrow];
            const int rb = (jf * 16 + lr) * 64;
            f32x4 s = (f32x4){0.f, 0.f, 0.f, 0.f};
#pragma unroll
            for (int kt = 0; kt < 2; ++kt) {
                const int o = rb + ((kt * 32 + lo8) ^ swl);
                bf16x8 kh = *(const bf16x8*)(kp0 + o);
                bf16x8 km = *(const bf16x8*)(kp1 + o);
                bf16x8 kl = *(const bf16x8*)(kp2 + o);
                s = __builtin_amdgcn_mfma_f32_16x16x32_bf16(aQh[kt], kh, s, 0, 0, 0);
                s = __builtin_amdgcn_mfma_f32_16x16x32_bf16(aQh[kt], km, s, 0, 0, 0);
                s = __builtin_amdgcn_mfma_f32_16x16x32_bf16(aQm[kt], kh, s, 0, 0, 0);
                s = __builtin_amdgcn_mfma_f32_16x16x32_bf16(aQm[kt], km, s, 0, 0, 0);
                s = __builtin_amdgcn_mfma_f32_16x16x32_bf16(aQh[kt], kl, s, 0, 0, 0);
                s = __builtin_amdgcn_mfma_f32_16x16x32_bf16(aQl[kt], kh, s, 0, 0, 0);
            }
            sf[jf] = s;
        }

        // ---- xy -> W = exp2(c2h * (log2(dn+s)-log2(dn-s))^2), division-free
#pragma unroll
        for (int jf = 0; jf < 4; ++jf) {
            const float y2 = y2v[jf];
            const float cy2 = c * y2;
#pragma unroll
            for (int r = 0; r < 4; ++r) {
                float xy = sf[jf][r];
                float one = fmaf(m2c, xy, 1.f);          // 1 - 2c*xy
                float A   = one + cy2;
                float dn  = fmaf(ccx2[r], y2, one);      // 1 - 2c*xy + c^2*x2*y2
                float u   = A * x2r[r];
                u = fmaf(m2Bc[r], xy, u);
                float num2 = fmaf(A, u, Bc2[r] * y2);
                num2 = fmaxf(num2, 0.f);
                float s = sqrtf(num2) * sc;
                float dnc = fmaxf(dn, 1e-15f);
                s = fminf(s, dnc * CLIP);                // folds the artanh arg clip
                float td = __builtin_amdgcn_logf(dnc + s) - __builtin_amdgcn_logf(dnc - s);
                float wv_ = __builtin_amdgcn_exp2f(c2h * td * td);
                sf[jf][r] = wv_;
                den[r] = fmaf(wv_, gm1v[jf], den[r]);
            }
        }

        // ---- W -> wave-private LDS (hi/lo, XOR-swizzled)
#pragma unroll
        for (int r = 0; r < 4; ++r) {
            const int row = lg * 4 + r;
            const int sw = (row & 7) << 3;
#pragma unroll
            for (int jf = 0; jf < 4; ++jf) {
                const int colu = (jf * 16 + lr) ^ sw;
                float wv_ = sf[jf][r];
                u16 hb = bf16_rne(wv_);
                wbh[row * 64 + colu] = hb;
                wbl[row * 64 + colu] = bf16_rne(wv_ - bf16_tof(hb));
            }
        }

        __syncthreads();   // V staged (vmcnt drained); K prefetch also landed

        // ---- read W back as A-frags
        bf16x8 aWh[2], aWl[2];
#pragma unroll
        for (int kt = 0; kt < 2; ++kt) {
            const int colu = (kt * 32 + lo8) ^ swl;
            aWh[kt] = *(const bf16x8*)(wbh + lr * 64 + colu);
            aWl[kt] = *(const bf16x8*)(wbl + lr * 64 + colu);
        }

        // ---- PV: pv += W x (gamma*V) from Vst
#pragma unroll
        for (int hf = 0; hf < 4; ++hf) {
            const int rb = (hf * 16 + lr) * 64;
#pragma unroll
            for (int kt = 0; kt < 2; ++kt) {
                const int o = rb + ((kt * 32 + lo8) ^ swl);
                bf16x8 vh = *(const bf16x8*)(&Vst[0][o]);
                bf16x8 vl = *(const bf16x8*)(&Vst[1][o]);
                pv[hf] = __builtin_amdgcn_mfma_f32_16x16x32_bf16(aWh[kt], vh, pv[hf], 0, 0, 0);
                pv[hf] = __builtin_amdgcn_mfma_f32_16x16x32_bf16(aWh[kt], vl, pv[hf], 0, 0, 0);
                pv[hf] = __builtin_amdgcn_mfma_f32_16x16x32_bf16(aWl[kt], vh, pv[hf], 0, 0, 0);
            }
        }

        __syncthreads();   // all waves done with Vst & Kst[cur] before restage
        cur ^= 1;
    }

    // ---- epilogue: reduce den across the 16 j-lanes, then
    //      two_mean = pv/den ; O = 0.5*artanh(sc*n)/(sc*n) * two_mean
#pragma unroll
    for (int r = 0; r < 4; ++r) {
        float d = den[r];
#pragma unroll
        for (int msk = 1; msk < 16; msk <<= 1) d += __shfl_xor(d, msk, 64);
        float rd = 1.f / d;                      // den > 0 always (gamma-1 >= 1)
        float o_[4];
        float n2 = 0.f;
#pragma unroll
        for (int hf = 0; hf < 4; ++hf) { o_[hf] = pv[hf][r] * rd; n2 = fmaf(o_[hf], o_[hf], n2); }
#pragma unroll
        for (int msk = 1; msk < 16; msk <<= 1) n2 += __shfl_xor(n2, msk, 64);
        float nrm = sqrtf(fmaxf(n2, 1e-15f));
        float arg = fminf(sc * nrm, 1.f - 1e-7f);
        float t = artanh_fast(arg);
        float f = 0.5f * t / (sc * nrm);
        const int nrow = qt * 64 + w * 16 + lg * 4 + r;
        const size_t dst = ((size_t)(b * 576 + nrow)) * 768 + h * 64;
#pragma unroll
        for (int hf = 0; hf < 4; ++hf) {
            float val = o_[hf] * f;
            u16 hb = bf16_rne(val);
            Oh[dst + hf * 16 + lr] = hb;
            Ol[dst + hf * 16 + lr] = bf16_rne(val - bf16_tof(hb));
        }
    }
}

// ---------------- launcher ----------------
extern "C" void kernel_launch(void* const* d_in, const int* in_sizes, int n_in,
                              void* d_out, int out_size, void* d_ws, size_t ws_size,
                              hipStream_t stream) {
    (void)in_sizes; (void)n_in; (void)out_size; (void)ws_size;
    const float* x    = (const float*)d_in[0];
    const float* Wq   = (const float*)d_in[1];
    const float* bq   = (const float*)d_in[2];
    const float* Wk   = (const float*)d_in[3];
    const float* bk   = (const float*)d_in[4];
    const float* Wv   = (const float*)d_in[5];
    const float* bv   = (const float*)d_in[6];
    const float* Wo   = (const float*)d_in[7];
    const float* bo   = (const float*)d_in[8];
    const float* cent = (const float*)d_in[9];
    const float* curv = (const float*)d_in[10];
    const float* sigr = (const float*)d_in[11];
    float* out = (float*)d_out;

    const size_t QH  = (size_t)B_ * H_ * N_ * 64;   // 7,077,888
    const size_t KVH = (size_t)B_ * H_ * J_ * 64;   // 8,650,752
    const size_t WSZ = (size_t)D_ * D_;             // 589,824

    float* fp = (float*)d_ws;
    float* qh   = fp;            fp += QH;
    float* Khf  = fp;            fp += KVH;
    float* Vhf  = fp;            fp += KVH;
    float* x2q  = fp;            fp += (size_t)B_ * H_ * N_;
    float* y2g  = fp;            fp += (size_t)B_ * H_ * J_;
    float* gm1  = fp;            fp += (size_t)B_ * H_ * J_;
    u16* up = (u16*)fp;
    u16* xh  = up;  up += QH;     // aliased with Oh (xh dead before attn writes Oh)
    u16* xl  = up;  up += QH;     // aliased with Ol
    u16* Oh  = xh;
    u16* Ol  = xl;
    u16* Wqh = up;  up += WSZ;
    u16* Wql = up;  up += WSZ;
    u16* Wkh = up;  up += WSZ;
    u16* Wkl = up;  up += WSZ;
    u16* Wvh = up;  up += WSZ;
    u16* Wvl = up;  up += WSZ;
    u16* Woh = up;  up += WSZ;
    u16* Wol = up;  up += WSZ;
    u16* Qb  = up;  up += 3 * QH;
    u16* Kb  = up;  up += 3 * KVH;
    u16* gV  = up;  up += 2 * KVH;

    u16* Qb0 = Qb;           u16* Qb1 = Qb + QH;   u16* Qb2 = Qb + 2 * QH;
    u16* Kb0 = Kb;           u16* Kb1 = Kb + KVH;  u16* Kb2 = Kb + 2 * KVH;
    u16* gV0 = gV;           u16* gV1 = gV + KVH;

    // 0: hi/lo splits of x and weights
    split_bf16_kernel<<<(int)(QH / 4 + 255) / 256, 256, 0, stream>>>(x, xh, xl, (int)(QH / 4));
    split_bf16_kernel<<<(int)(WSZ / 4 + 255) / 256, 256, 0, stream>>>(Wq, Wqh, Wql, (int)(WSZ / 4));
    split_bf16_kernel<<<(int)(WSZ / 4 + 255) / 256, 256, 0, stream>>>(Wk, Wkh, Wkl, (int)(WSZ / 4));
    split_bf16_kernel<<<(int)(WSZ / 4 + 255) / 256, 256, 0, stream>>>(Wv, Wvh, Wvl, (int)(WSZ / 4));
    split_bf16_kernel<<<(int)(WSZ / 4 + 255) / 256, 256, 0, stream>>>(Wo, Woh, Wol, (int)(WSZ / 4));

    // 1: QKV projections (MFMA)
    gemm_qkv_mfma<<<dim3(72, 18), 256, 0, stream>>>(xh, xl, Wqh, Wql, Wkh, Wkl, Wvh, Wvl,
                                                    bq, bk, bv, qh, Khf, Vhf);
    // 2,3: hyperbolic maps -> MFMA-ready operands
    expmap_q_kernel<<<27648, 256, 0, stream>>>(qh, Qb0, Qb1, Qb2, x2q, curv);
    build_kv_kernel<<<2112, 256, 0, stream>>>(Khf, Vhf, cent, Kb0, Kb1, Kb2, gV0, gV1,
                                              y2g, gm1, curv);
    // 4: fused attention (MFMA, LDS-staged, XCD-affine, no-shift softmax)
    attn_kernel<<<1728, 256, 0, stream>>>(Qb0, Qb1, Qb2, Kb0, Kb1, Kb2, gV0, gV1,
                                          x2q, y2g, gm1, sigr, curv, Oh, Ol);
    // 5: output projection (MFMA)
    gemm_o_mfma<<<dim3(72, 6), 256, 0, stream>>>(Oh, Ol, Woh, Wol, bo, out);
}

// Round 8
// 458.689 us; speedup vs baseline: 2.9116x; 1.1091x over previous
//
#include <hip/hip_runtime.h>
#include <cstdint>
#include <cstddef>

#define B_  16
#define N_  576
#define D_  768
#define H_  12
#define HD_ 64
#define M_  128
#define J_  704   // N_ + M_

typedef unsigned short u16;
typedef __attribute__((ext_vector_type(8))) short bf16x8;
typedef __attribute__((ext_vector_type(4))) float f32x4;
typedef __attribute__((ext_vector_type(4))) unsigned short u16x4;
typedef __attribute__((ext_vector_type(8))) unsigned short u16x8;

// ---------------- helpers ----------------

__device__ __forceinline__ float softplus_f(float x) {
    return (x > 20.f) ? x : log1pf(expf(x));
}

__device__ __forceinline__ float wred_sum64(float v) {
#pragma unroll
    for (int m = 1; m < 64; m <<= 1) v += __shfl_xor(v, m, 64);
    return v;
}

__device__ __forceinline__ u16 bf16_rne(float f) {
    unsigned int u = __float_as_uint(f);
    unsigned int r = u + 0x7FFFu + ((u >> 16) & 1u);
    return (u16)(r >> 16);
}
__device__ __forceinline__ float bf16_tof(u16 h) {
    return __uint_as_float(((unsigned int)h) << 16);
}

// expmap0 total multiplier for a row with raw sumsq n2; also returns final ||out||^2
__device__ __forceinline__ float expmap0_factor(float n2, float sc, float* n2out) {
    const float ATANH_1M1E5 = 6.1030335f;     // artanh(1 - 1e-5)
    float n0 = sqrtf(fmaxf(n2, 1e-15f));
    float maxtan = ATANH_1M1E5 / sc;
    float f1 = fminf(1.f, maxtan / n0);       // pre-clip
    float n1 = n0 * f1;
    float a  = sc * n1;
    float th = tanhf(a);
    float yfac  = th / a;                     // y = u * f1 * yfac
    float ynorm = th / sc;
    float lim   = (1.f - 1e-5f) / sc;
    float f2 = fminf(1.f, lim / ynorm);       // post-clip
    float fn = ynorm * f2;
    *n2out = fn * fn;
    return f1 * yfac * f2;
}

__device__ __forceinline__ float artanh_fast(float z) {  // z in [0, 1-1e-7]
    return 0.5f * __logf((1.f + z) / (1.f - z));
}

// global -> LDS direct copy, 16B per lane (wave-uniform LDS base + lane*16)
typedef const __attribute__((address_space(1))) unsigned int* gas_u32;
typedef __attribute__((address_space(3))) unsigned int* las_u32;
__device__ __forceinline__ void gload_lds16(const u16* g, u16* l) {
    __builtin_amdgcn_global_load_lds((gas_u32)(const void*)g, (las_u32)(void*)l, 16, 0, 0);
}

// ---------------- kernel 0a: f32 -> bf16 hi/lo split (x) ----------------
__global__ __launch_bounds__(256) void split_bf16_kernel(
    const float* __restrict__ src, u16* __restrict__ hi, u16* __restrict__ lo, int n4)
{
    int i = blockIdx.x * 256 + threadIdx.x;
    if (i >= n4) return;
    float4 v = ((const float4*)src)[i];
    u16x4 h, l;
    h[0] = bf16_rne(v.x); l[0] = bf16_rne(v.x - bf16_tof(h[0]));
    h[1] = bf16_rne(v.y); l[1] = bf16_rne(v.y - bf16_tof(h[1]));
    h[2] = bf16_rne(v.z); l[2] = bf16_rne(v.z - bf16_tof(h[2]));
    h[3] = bf16_rne(v.w); l[3] = bf16_rne(v.w - bf16_tof(h[3]));
    ((u16x4*)hi)[i] = h;
    ((u16x4*)lo)[i] = l;
}

// ---------------- kernel 0b: split all 4 weight matrices in one launch ----------------
__global__ __launch_bounds__(256) void split_w4_kernel(
    const float* __restrict__ W0, const float* __restrict__ W1,
    const float* __restrict__ W2, const float* __restrict__ W3,
    u16* __restrict__ H0, u16* __restrict__ L0, u16* __restrict__ H1, u16* __restrict__ L1,
    u16* __restrict__ H2, u16* __restrict__ L2, u16* __restrict__ H3, u16* __restrict__ L3)
{
    int i = blockIdx.x * 256 + threadIdx.x;   // < WSZ/4 = 147456
    const int wsel = blockIdx.y;
    const float* src = wsel == 0 ? W0 : (wsel == 1 ? W1 : (wsel == 2 ? W2 : W3));
    u16* hi = wsel == 0 ? H0 : (wsel == 1 ? H1 : (wsel == 2 ? H2 : H3));
    u16* lo = wsel == 0 ? L0 : (wsel == 1 ? L1 : (wsel == 2 ? L2 : L3));
    float4 v = ((const float4*)src)[i];
    u16x4 h, l;
    h[0] = bf16_rne(v.x); l[0] = bf16_rne(v.x - bf16_tof(h[0]));
    h[1] = bf16_rne(v.y); l[1] = bf16_rne(v.y - bf16_tof(h[1]));
    h[2] = bf16_rne(v.z); l[2] = bf16_rne(v.z - bf16_tof(h[2]));
    h[3] = bf16_rne(v.w); l[3] = bf16_rne(v.w - bf16_tof(h[3]));
    ((u16x4*)hi)[i] = h;
    ((u16x4*)lo)[i] = l;
}

// ---------------- kernel 1: QKV projection (split-bf16 MFMA, XCD-banded) ----------------
__global__ __launch_bounds__(256) void gemm_qkv_mfma(
    const u16* __restrict__ xh, const u16* __restrict__ xl,
    const u16* __restrict__ Wh0, const u16* __restrict__ Wl0,
    const u16* __restrict__ Wh1, const u16* __restrict__ Wl1,
    const u16* __restrict__ Wh2, const u16* __restrict__ Wl2,
    const float* __restrict__ bq, const float* __restrict__ bk, const float* __restrict__ bv,
    float* __restrict__ qh_o, float* __restrict__ Kh_o, float* __restrict__ Vh_o)
{
    __shared__ u16 Ah[4096], Al[4096], Bh[4096], Bl[4096];   // 8 frags x 512 each
    const int tid = threadIdx.x;
    const int w = tid >> 6, lane = tid & 63;
    const int wr = w >> 1, wc = w & 1;
    const int lrow = lane & 15, lk8 = (lane >> 4) << 3;
    // XCD-band swizzle: 1296 blocks = 8 XCDs x (9 mt x 18 yb); each XCD owns a
    // contiguous 9-tile M-band so its A-panel stays resident in the XCD L2.
    const int bid = blockIdx.x;
    const int xcd = bid & 7, ser = bid >> 3;       // ser < 162
    const int mt = xcd * 9 + (ser % 9);
    const int yb = ser / 9;                        // < 18
    const int which = yb / 6, ct = yb - which * 6;
    const u16* Bp_h = which == 0 ? Wh0 : (which == 1 ? Wh1 : Wh2);
    const u16* Bp_l = which == 0 ? Wl0 : (which == 1 ? Wl1 : Wl2);
    const int row0 = mt * 128, col0 = ct * 128;

    const size_t a0 = (size_t)(row0 + (2 * w + 0) * 16 + lrow) * 768 + lk8;
    const size_t a1 = a0 + 16 * 768;
    const size_t b0 = (size_t)(col0 + (2 * w + 0) * 16 + lrow) * 768 + lk8;
    const size_t b1 = b0 + 16 * 768;
    u16* lAh0 = Ah + (2 * w) * 512; u16* lAh1 = lAh0 + 512;
    u16* lAl0 = Al + (2 * w) * 512; u16* lAl1 = lAl0 + 512;
    u16* lBh0 = Bh + (2 * w) * 512; u16* lBh1 = lBh0 + 512;
    u16* lBl0 = Bl + (2 * w) * 512; u16* lBl1 = lBl0 + 512;

    f32x4 acc[4][4];
#pragma unroll
    for (int i = 0; i < 4; ++i)
#pragma unroll
        for (int j = 0; j < 4; ++j) acc[i][j] = (f32x4){0.f, 0.f, 0.f, 0.f};

    for (int k0 = 0; k0 < 768; k0 += 32) {
        gload_lds16(xh + a0 + k0, lAh0);
        gload_lds16(xh + a1 + k0, lAh1);
        gload_lds16(xl + a0 + k0, lAl0);
        gload_lds16(xl + a1 + k0, lAl1);
        gload_lds16(Bp_h + b0 + k0, lBh0);
        gload_lds16(Bp_h + b1 + k0, lBh1);
        gload_lds16(Bp_l + b0 + k0, lBl0);
        gload_lds16(Bp_l + b1 + k0, lBl1);
        __syncthreads();
        bf16x8 aH[4], aL[4], bH[4], bL[4];
        const int lo8 = lane * 8;
#pragma unroll
        for (int i = 0; i < 4; ++i) {
            aH[i] = *(const bf16x8*)(Ah + (wr * 4 + i) * 512 + lo8);
            aL[i] = *(const bf16x8*)(Al + (wr * 4 + i) * 512 + lo8);
            bH[i] = *(const bf16x8*)(Bh + (wc * 4 + i) * 512 + lo8);
            bL[i] = *(const bf16x8*)(Bl + (wc * 4 + i) * 512 + lo8);
        }
#pragma unroll
        for (int mi = 0; mi < 4; ++mi)
#pragma unroll
            for (int ni = 0; ni < 4; ++ni) {
                acc[mi][ni] = __builtin_amdgcn_mfma_f32_16x16x32_bf16(aH[mi], bH[ni], acc[mi][ni], 0, 0, 0);
                acc[mi][ni] = __builtin_amdgcn_mfma_f32_16x16x32_bf16(aH[mi], bL[ni], acc[mi][ni], 0, 0, 0);
                acc[mi][ni] = __builtin_amdgcn_mfma_f32_16x16x32_bf16(aL[mi], bH[ni], acc[mi][ni], 0, 0, 0);
            }
        __syncthreads();
    }

    const float* bias = which == 0 ? bq : (which == 1 ? bk : bv);
    const int h = ct * 2 + wc;
    const int rbase = row0 + wr * 64 + ((lane >> 4) << 2);
#pragma unroll
    for (int ni = 0; ni < 4; ++ni) {
        const int hd = ni * 16 + lrow;
        const float bv_ = bias[h * 64 + hd];
#pragma unroll
        for (int mi = 0; mi < 4; ++mi) {
            f32x4 a = acc[mi][ni];
#pragma unroll
            for (int r = 0; r < 4; ++r) {
                int row = rbase + mi * 16 + r;
                int bb = row / 576;
                int nn = row - bb * 576;
                float val = a[r] + bv_;
                size_t dst = (((size_t)(bb * 12 + h)) * 576 + nn) * 64 + hd;
                if (which == 0)      qh_o[dst] = val;
                else if (which == 1) Kh_o[dst] = val;
                else                 Vh_o[dst] = val;
            }
        }
    }
}

// ---------------- kernel 5: output projection (split-bf16 MFMA, XCD-banded) ----------------
__global__ __launch_bounds__(256) void gemm_o_mfma(
    const u16* __restrict__ Oh, const u16* __restrict__ Ol,
    const u16* __restrict__ Wh, const u16* __restrict__ Wl,
    const float* __restrict__ bo, float* __restrict__ out)
{
    __shared__ u16 Ah[4096], Al[4096], Bh[4096], Bl[4096];
    const int tid = threadIdx.x;
    const int w = tid >> 6, lane = tid & 63;
    const int wr = w >> 1, wc = w & 1;
    const int lrow = lane & 15, lk8 = (lane >> 4) << 3;
    // 432 blocks = 8 XCDs x (9 mt x 6 ct)
    const int bid = blockIdx.x;
    const int xcd = bid & 7, ser = bid >> 3;       // ser < 54
    const int mt = xcd * 9 + (ser % 9);
    const int ct = ser / 9;                        // < 6
    const int row0 = mt * 128, col0 = ct * 128;

    const size_t a0 = (size_t)(row0 + (2 * w + 0) * 16 + lrow) * 768 + lk8;
    const size_t a1 = a0 + 16 * 768;
    const size_t b0 = (size_t)(col0 + (2 * w + 0) * 16 + lrow) * 768 + lk8;
    const size_t b1 = b0 + 16 * 768;
    u16* lAh0 = Ah + (2 * w) * 512; u16* lAh1 = lAh0 + 512;
    u16* lAl0 = Al + (2 * w) * 512; u16* lAl1 = lAl0 + 512;
    u16* lBh0 = Bh + (2 * w) * 512; u16* lBh1 = lBh0 + 512;
    u16* lBl0 = Bl + (2 * w) * 512; u16* lBl1 = lBl0 + 512;

    f32x4 acc[4][4];
#pragma unroll
    for (int i = 0; i < 4; ++i)
#pragma unroll
        for (int j = 0; j < 4; ++j) acc[i][j] = (f32x4){0.f, 0.f, 0.f, 0.f};

    for (int k0 = 0; k0 < 768; k0 += 32) {
        gload_lds16(Oh + a0 + k0, lAh0);
        gload_lds16(Oh + a1 + k0, lAh1);
        gload_lds16(Ol + a0 + k0, lAl0);
        gload_lds16(Ol + a1 + k0, lAl1);
        gload_lds16(Wh + b0 + k0, lBh0);
        gload_lds16(Wh + b1 + k0, lBh1);
        gload_lds16(Wl + b0 + k0, lBl0);
        gload_lds16(Wl + b1 + k0, lBl1);
        __syncthreads();
        bf16x8 aH[4], aL[4], bH[4], bL[4];
        const int lo8 = lane * 8;
#pragma unroll
        for (int i = 0; i < 4; ++i) {
            aH[i] = *(const bf16x8*)(Ah + (wr * 4 + i) * 512 + lo8);
            aL[i] = *(const bf16x8*)(Al + (wr * 4 + i) * 512 + lo8);
            bH[i] = *(const bf16x8*)(Bh + (wc * 4 + i) * 512 + lo8);
            bL[i] = *(const bf16x8*)(Bl + (wc * 4 + i) * 512 + lo8);
        }
#pragma unroll
        for (int mi = 0; mi < 4; ++mi)
#pragma unroll
            for (int ni = 0; ni < 4; ++ni) {
                acc[mi][ni] = __builtin_amdgcn_mfma_f32_16x16x32_bf16(aH[mi], bH[ni], acc[mi][ni], 0, 0, 0);
                acc[mi][ni] = __builtin_amdgcn_mfma_f32_16x16x32_bf16(aH[mi], bL[ni], acc[mi][ni], 0, 0, 0);
                acc[mi][ni] = __builtin_amdgcn_mfma_f32_16x16x32_bf16(aL[mi], bH[ni], acc[mi][ni], 0, 0, 0);
            }
        __syncthreads();
    }

    const int rbase = row0 + wr * 64 + ((lane >> 4) << 2);
#pragma unroll
    for (int ni = 0; ni < 4; ++ni) {
        const int colg = col0 + wc * 64 + ni * 16 + lrow;
        const float bv_ = bo[colg];
#pragma unroll
        for (int mi = 0; mi < 4; ++mi) {
            f32x4 a = acc[mi][ni];
#pragma unroll
            for (int r = 0; r < 4; ++r) {
                int row = rbase + mi * 16 + r;
                out[(size_t)row * 768 + colg] = a[r] + bv_;
            }
        }
    }
}

// ---------------- kernel 2: fused hyperbolic maps ----------------
// Grid 3480: [0,1728) q-expmap (3-plane split + x2), [1728,3456) K/V token rows
// (K 3-plane + transposed gamma*V 2-plane + y2/gm1), [3456,3480) per-head
// centroid rows computed ONCE (shared across batch).
__global__ __launch_bounds__(256) void maps_kernel(
    const float* __restrict__ qh, const float* __restrict__ Khf, const float* __restrict__ Vhf,
    const float* __restrict__ cent,
    u16* __restrict__ Qb0, u16* __restrict__ Qb1, u16* __restrict__ Qb2,
    u16* __restrict__ Kb0, u16* __restrict__ Kb1, u16* __restrict__ Kb2,
    u16* __restrict__ Kc0, u16* __restrict__ Kc1, u16* __restrict__ Kc2,
    u16* __restrict__ gV0, u16* __restrict__ gV1,
    u16* __restrict__ gVc0, u16* __restrict__ gVc1,
    float* __restrict__ x2q, float* __restrict__ y2g, float* __restrict__ gm1,
    float* __restrict__ y2c, float* __restrict__ gm1c,
    const float* __restrict__ curv_raw)
{
    __shared__ float gvt_s[64][65];
    const float c  = softplus_f(curv_raw[0]);
    const float sc = sqrtf(c);
    const int bx = blockIdx.x;
    const int w = threadIdx.x >> 6, lane = threadIdx.x & 63;

    if (bx < 1728) {
        // ---- q path: 64 rows per block
        const size_t base = (size_t)bx * 64;
#pragma unroll 4
        for (int i = 0; i < 16; ++i) {
            const size_t row = base + w * 16 + i;
            const size_t off = row * 64 + lane;
            float u = qh[off];
            float n2 = wred_sum64(u * u);
            float n2o;
            float f = expmap0_factor(n2, sc, &n2o);
            float y = u * f;
            u16 h_ = bf16_rne(y);
            float r1 = y - bf16_tof(h_);
            u16 m_ = bf16_rne(r1);
            u16 l_ = bf16_rne(r1 - bf16_tof(m_));
            Qb0[off] = h_; Qb1[off] = m_; Qb2[off] = l_;
            if (lane == 0) x2q[row] = n2o;
        }
        return;
    }
    if (bx < 3456) {
        // ---- K/V token path
        const int t = bx - 1728;
        const int bh = t / 9, jt = t - (t / 9) * 9;
#pragma unroll 4
        for (int i = 0; i < 16; ++i) {
            const int j = jt * 64 + w * 16 + i;
            const size_t g = (size_t)bh * 576 + j;
            float kx = Khf[g * 64 + lane], vx = Vhf[g * 64 + lane];
            float n2k = wred_sum64(kx * kx);
            float n2v = wred_sum64(vx * vx);
            float y2o, v2o;
            float fk = expmap0_factor(n2k, sc, &y2o);
            float fv = expmap0_factor(n2v, sc, &v2o);
            float ky = kx * fk;
            u16 kh = bf16_rne(ky);
            float r1 = ky - bf16_tof(kh);
            u16 km = bf16_rne(r1);
            u16 kl = bf16_rne(r1 - bf16_tof(km));
            Kb0[g * 64 + lane] = kh; Kb1[g * 64 + lane] = km; Kb2[g * 64 + lane] = kl;
            float gmm = 2.f / fmaxf(1.f - c * v2o, 1e-15f);
            gvt_s[lane][w * 16 + i] = vx * fv * gmm;
            if (lane == 0) { y2g[g] = y2o; gm1[g] = gmm - 1.f; }
        }
        __syncthreads();
        const int hd = threadIdx.x >> 2, j0 = (threadIdx.x & 3) * 16;
        u16 hb[16], lb[16];
#pragma unroll
        for (int e = 0; e < 16; ++e) {
            float v = gvt_s[hd][j0 + e];
            hb[e] = bf16_rne(v);
            lb[e] = bf16_rne(v - bf16_tof(hb[e]));
        }
        const size_t dst = ((size_t)bh * 64 + hd) * 576 + jt * 64 + j0;
        *(u16x8*)(gV0 + dst)     = *(u16x8*)&hb[0];
        *(u16x8*)(gV0 + dst + 8) = *(u16x8*)&hb[8];
        *(u16x8*)(gV1 + dst)     = *(u16x8*)&lb[0];
        *(u16x8*)(gV1 + dst + 8) = *(u16x8*)&lb[8];
        return;
    }
    {
        // ---- centroid path: once per head (k and v identical -> single expmap)
        const int t = bx - 3456;          // < 24
        const int h = t >> 1, ct = t & 1;
#pragma unroll 4
        for (int i = 0; i < 16; ++i) {
            const int m = ct * 64 + w * 16 + i;
            const size_t g = (size_t)h * 128 + m;
            float cv = cent[g * 64 + lane];
            float n2 = wred_sum64(cv * cv);
            float n2o;
            float f = expmap0_factor(n2, sc, &n2o);
            float ky = cv * f;
            u16 kh = bf16_rne(ky);
            float r1 = ky - bf16_tof(kh);
            u16 km = bf16_rne(r1);
            u16 kl = bf16_rne(r1 - bf16_tof(km));
            Kc0[g * 64 + lane] = kh; Kc1[g * 64 + lane] = km; Kc2[g * 64 + lane] = kl;
            float gmm = 2.f / fmaxf(1.f - c * n2o, 1e-15f);
            gvt_s[lane][w * 16 + i] = ky * gmm;
            if (lane == 0) { y2c[g] = n2o; gm1c[g] = gmm - 1.f; }
        }
        __syncthreads();
        const int hd = threadIdx.x >> 2, j0 = (threadIdx.x & 3) * 16;
        u16 hb[16], lb[16];
#pragma unroll
        for (int e = 0; e < 16; ++e) {
            float v = gvt_s[hd][j0 + e];
            hb[e] = bf16_rne(v);
            lb[e] = bf16_rne(v - bf16_tof(hb[e]));
        }
        const size_t dst = ((size_t)h * 64 + hd) * 128 + ct * 64 + j0;
        *(u16x8*)(gVc0 + dst)     = *(u16x8*)&hb[0];
        *(u16x8*)(gVc0 + dst + 8) = *(u16x8*)&hb[8];
        *(u16x8*)(gVc1 + dst)     = *(u16x8*)&lb[0];
        *(u16x8*)(gVc1 + dst + 8) = *(u16x8*)&lb[8];
    }
}

// ---------------- kernel 4: fused hyperbolic attention (MFMA, LDS-staged K/V) ----------------
// j-tiles 0..8 = token K/V (per-bh buffers); tiles 9..10 = centroid K/V
// (per-head buffers, shared across batch -> L2 hits). No online max-shift
// (logits <= 0, centroid rows bound max-logit; den clamp provably inert).
__global__ __launch_bounds__(256) void attn_kernel(
    const u16* __restrict__ Qb0, const u16* __restrict__ Qb1, const u16* __restrict__ Qb2,
    const u16* __restrict__ Kb0, const u16* __restrict__ Kb1, const u16* __restrict__ Kb2,
    const u16* __restrict__ Kc0, const u16* __restrict__ Kc1, const u16* __restrict__ Kc2,
    const u16* __restrict__ gV0, const u16* __restrict__ gV1,
    const u16* __restrict__ gVc0, const u16* __restrict__ gVc1,
    const float* __restrict__ x2q, const float* __restrict__ y2g, const float* __restrict__ gm1,
    const float* __restrict__ y2c, const float* __restrict__ gm1c,
    const float* __restrict__ sigma_raw, const float* __restrict__ curv_raw,
    u16* __restrict__ Oh, u16* __restrict__ Ol)
{
    __shared__ __align__(16) u16 Kst[2][3][4096];  // [buf][plane][row*64 + swizzled col]
    __shared__ __align__(16) u16 Vst[2][4096];     // [plane][row*64 + swizzled col]
    __shared__ __align__(16) u16 wb_hi[4][1024];
    __shared__ __align__(16) u16 wb_lo[4][1024];

    const int blk = blockIdx.x;
    // XCD swizzle (8 XCDs, 1728 = 8 * 216 blocks, 216 = 24 bh-groups * 9 qt)
    const int xcd = blk & 7;
    const int serial = blk >> 3;
    const int bhg = serial / 9;
    const int qt = serial - bhg * 9;
    const int bh = bhg * 8 + xcd;
    const int b = bh / 12, h = bh % 12;
    const float c  = softplus_f(curv_raw[0]);
    const float sc = sqrtf(c);
    const float sig = softplus_f(sigma_raw[h]) + 1e-6f;
    const float coef = -2.f / (c * sig * sig);   // logit = coef * artanh(arg)^2
    const float c2h  = coef * 0.25f * 0.6931471805599453f;  // exp2 basis
    const float m2c  = -2.f * c;
    const float CLIP = 1.f - 1e-7f;

    const int tid = threadIdx.x;
    const int w = tid >> 6, lane = tid & 63;
    const int lr = lane & 15, lg = lane >> 4, lo8 = lg * 8;
    const int swl = (lr & 7) << 3;

    const size_t qbase = (size_t)bh * 576 + qt * 64;

    // staging geometry: chunk cc = (rr*4 + w)*64 + lane covers LDS row cc>>3, col (cc&7)*8;
    // source col is inverse-swizzled: 8*((cc&7) ^ (row&7))
    int srow[2], scol[2];
#pragma unroll
    for (int rr = 0; rr < 2; ++rr) {
        int cch = (rr * 4 + w) * 64 + lane;
        srow[rr] = cch >> 3;
        scol[rr] = ((cch & 7) ^ (srow[rr] & 7)) << 3;
    }
    const size_t kb_base = (size_t)bh * 576 * 64;
    const size_t kc_base = (size_t)h * 128 * 64;
    const size_t vb_base = (size_t)bh * 64 * 576;
    const size_t vc_base = (size_t)h * 64 * 128;

    auto stageK = [&](int t, int buf) {
        if (t < 9) {
            const size_t rb = kb_base + (size_t)t * 64 * 64;
#pragma unroll
            for (int rr = 0; rr < 2; ++rr) {
                const size_t so = rb + (size_t)srow[rr] * 64 + scol[rr];
                gload_lds16(Kb0 + so, &Kst[buf][0][(rr * 4 + w) * 512]);
                gload_lds16(Kb1 + so, &Kst[buf][1][(rr * 4 + w) * 512]);
                gload_lds16(Kb2 + so, &Kst[buf][2][(rr * 4 + w) * 512]);
            }
        } else {
            const size_t rb = kc_base + (size_t)(t - 9) * 64 * 64;
#pragma unroll
            for (int rr = 0; rr < 2; ++rr) {
                const size_t so = rb + (size_t)srow[rr] * 64 + scol[rr];
                gload_lds16(Kc0 + so, &Kst[buf][0][(rr * 4 + w) * 512]);
                gload_lds16(Kc1 + so, &Kst[buf][1][(rr * 4 + w) * 512]);
                gload_lds16(Kc2 + so, &Kst[buf][2][(rr * 4 + w) * 512]);
            }
        }
    };
    auto stageV = [&](int t) {
        if (t < 9) {
            const size_t rb = vb_base + (size_t)t * 64;
#pragma unroll
            for (int rr = 0; rr < 2; ++rr) {
                const size_t so = rb + (size_t)srow[rr] * 576 + scol[rr];
                gload_lds16(gV0 + so, &Vst[0][(rr * 4 + w) * 512]);
                gload_lds16(gV1 + so, &Vst[1][(rr * 4 + w) * 512]);
            }
        } else {
            const size_t rb = vc_base + (size_t)(t - 9) * 64;
#pragma unroll
            for (int rr = 0; rr < 2; ++rr) {
                const size_t so = rb + (size_t)srow[rr] * 128 + scol[rr];
                gload_lds16(gVc0 + so, &Vst[0][(rr * 4 + w) * 512]);
                gload_lds16(gVc1 + so, &Vst[1][(rr * 4 + w) * 512]);
            }
        }
    };

    // Q A-frags (3 components x 2 k-halves)
    bf16x8 aQh[2], aQm[2], aQl[2];
    {
        const size_t qrow = (qbase + w * 16 + lr) * 64;
#pragma unroll
        for (int kt = 0; kt < 2; ++kt) {
            const size_t o = qrow + kt * 32 + lo8;
            aQh[kt] = *(const bf16x8*)(Qb0 + o);
            aQm[kt] = *(const bf16x8*)(Qb1 + o);
            aQl[kt] = *(const bf16x8*)(Qb2 + o);
        }
    }
    float x2r[4], m2Bc[4], Bc2[4], ccx2[4];
#pragma unroll
    for (int r = 0; r < 4; ++r) {
        float x2 = x2q[qbase + w * 16 + lg * 4 + r];
        float Bc = fmaf(-c, x2, 1.f);
        x2r[r] = x2; m2Bc[r] = -2.f * Bc; Bc2[r] = Bc * Bc; ccx2[r] = c * c * x2;
    }

    f32x4 pv[4];
#pragma unroll
    for (int i = 0; i < 4; ++i) pv[i] = (f32x4){0.f, 0.f, 0.f, 0.f};
    float den[4] = {0.f, 0.f, 0.f, 0.f};

    u16* wbh = &wb_hi[w][0];
    u16* wbl = &wb_lo[w][0];

    // prologue: stage K(0) into Kst[0]
    stageK(0, 0);
    __syncthreads();

    int cur = 0;
    for (int jt = 0; jt < 11; ++jt) {
        const int jb = jt * 64;

        // prefetch next K tile into Kst[cur^1] (drains at mid-iter barrier)
        if (jt < 10) stageK(jt + 1, cur ^ 1);
        // stage gammaV for this tile (consumed after mid-iter barrier)
        stageV(jt);

        // per-tile scalar sources
        const float* y2p;
        const float* gm1p;
        if (jt < 9) { y2p = y2g + (size_t)bh * 576 + jb;  gm1p = gm1 + (size_t)bh * 576 + jb; }
        else        { y2p = y2c + (size_t)h * 128 + (jb - 576); gm1p = gm1c + (size_t)h * 128 + (jb - 576); }

        // ---- S-phase: QK^T from Kst[cur]
        const u16* kp0 = &Kst[cur][0][0];
        const u16* kp1 = &Kst[cur][1][0];
        const u16* kp2 = &Kst[cur][2][0];
        f32x4 sf[4];
        float y2v[4], gm1v[4];
#pragma unroll
        for (int jf = 0; jf < 4; ++jf) {
            y2v[jf] = y2p[jf * 16 + lr];
            gm1v[jf] = gm1p[jf * 16 + lr];
            const int rb = (jf * 16 + lr) * 64;
            f32x4 s = (f32x4){0.f, 0.f, 0.f, 0.f};
#pragma unroll
            for (int kt = 0; kt < 2; ++kt) {
                const int o = rb + ((kt * 32 + lo8) ^ swl);
                bf16x8 kh = *(const bf16x8*)(kp0 + o);
                bf16x8 km = *(const bf16x8*)(kp1 + o);
                bf16x8 kl = *(const bf16x8*)(kp2 + o);
                s = __builtin_amdgcn_mfma_f32_16x16x32_bf16(aQh[kt], kh, s, 0, 0, 0);
                s = __builtin_amdgcn_mfma_f32_16x16x32_bf16(aQh[kt], km, s, 0, 0, 0);
                s = __builtin_amdgcn_mfma_f32_16x16x32_bf16(aQm[kt], kh, s, 0, 0, 0);
                s = __builtin_amdgcn_mfma_f32_16x16x32_bf16(aQm[kt], km, s, 0, 0, 0);
                s = __builtin_amdgcn_mfma_f32_16x16x32_bf16(aQh[kt], kl, s, 0, 0, 0);
                s = __builtin_amdgcn_mfma_f32_16x16x32_bf16(aQl[kt], kh, s, 0, 0, 0);
            }
            sf[jf] = s;
        }

        // ---- xy -> W = exp2(c2h * (log2(dn+s)-log2(dn-s))^2), division-free
#pragma unroll
        for (int jf = 0; jf < 4; ++jf) {
            const float y2 = y2v[jf];
            const float cy2 = c * y2;
#pragma unroll
            for (int r = 0; r < 4; ++r) {
                float xy = sf[jf][r];
                float one = fmaf(m2c, xy, 1.f);          // 1 - 2c*xy
                float A   = one + cy2;
                float dn  = fmaf(ccx2[r], y2, one);      // 1 - 2c*xy + c^2*x2*y2
                float u   = A * x2r[r];
                u = fmaf(m2Bc[r], xy, u);
                float num2 = fmaf(A, u, Bc2[r] * y2);
                num2 = fmaxf(num2, 0.f);
                float s = sqrtf(num2) * sc;
                float dnc = fmaxf(dn, 1e-15f);
                s = fminf(s, dnc * CLIP);                // folds the artanh arg clip
                float td = __builtin_amdgcn_logf(dnc + s) - __builtin_amdgcn_logf(dnc - s);
                float wv_ = __builtin_amdgcn_exp2f(c2h * td * td);
                sf[jf][r] = wv_;
                den[r] = fmaf(wv_, gm1v[jf], den[r]);
            }
        }

        // ---- W -> wave-private LDS (hi/lo, XOR-swizzled)
#pragma unroll
        for (int r = 0; r < 4; ++r) {
            const int row = lg * 4 + r;
            const int sw = (row & 7) << 3;
#pragma unroll
            for (int jf = 0; jf < 4; ++jf) {
                const int colu = (jf * 16 + lr) ^ sw;
                float wv_ = sf[jf][r];
                u16 hb = bf16_rne(wv_);
                wbh[row * 64 + colu] = hb;
                wbl[row * 64 + colu] = bf16_rne(wv_ - bf16_tof(hb));
            }
        }

        __syncthreads();   // V staged (vmcnt drained); K prefetch also landed

        // ---- read W back as A-frags
        bf16x8 aWh[2], aWl[2];
#pragma unroll
        for (int kt = 0; kt < 2; ++kt) {
            const int colu = (kt * 32 + lo8) ^ swl;
            aWh[kt] = *(const bf16x8*)(wbh + lr * 64 + colu);
            aWl[kt] = *(const bf16x8*)(wbl + lr * 64 + colu);
        }

        // ---- PV: pv += W x (gamma*V) from Vst
#pragma unroll
        for (int hf = 0; hf < 4; ++hf) {
            const int rb = (hf * 16 + lr) * 64;
#pragma unroll
            for (int kt = 0; kt < 2; ++kt) {
                const int o = rb + ((kt * 32 + lo8) ^ swl);
                bf16x8 vh = *(const bf16x8*)(&Vst[0][o]);
                bf16x8 vl = *(const bf16x8*)(&Vst[1][o]);
                pv[hf] = __builtin_amdgcn_mfma_f32_16x16x32_bf16(aWh[kt], vh, pv[hf], 0, 0, 0);
                pv[hf] = __builtin_amdgcn_mfma_f32_16x16x32_bf16(aWh[kt], vl, pv[hf], 0, 0, 0);
                pv[hf] = __builtin_amdgcn_mfma_f32_16x16x32_bf16(aWl[kt], vh, pv[hf], 0, 0, 0);
            }
        }

        __syncthreads();   // all waves done with Vst & Kst[cur] before restage
        cur ^= 1;
    }

    // ---- epilogue: reduce den across the 16 j-lanes, then
    //      two_mean = pv/den ; O = 0.5*artanh(sc*n)/(sc*n) * two_mean
#pragma unroll
    for (int r = 0; r < 4; ++r) {
        float d = den[r];
#pragma unroll
        for (int msk = 1; msk < 16; msk <<= 1) d += __shfl_xor(d, msk, 64);
        float rd = 1.f / d;                      // den > 0 always (gamma-1 >= 1)
        float o_[4];
        float n2 = 0.f;
#pragma unroll
        for (int hf = 0; hf < 4; ++hf) { o_[hf] = pv[hf][r] * rd; n2 = fmaf(o_[hf], o_[hf], n2); }
#pragma unroll
        for (int msk = 1; msk < 16; msk <<= 1) n2 += __shfl_xor(n2, msk, 64);
        float nrm = sqrtf(fmaxf(n2, 1e-15f));
        float arg = fminf(sc * nrm, 1.f - 1e-7f);
        float t = artanh_fast(arg);
        float f = 0.5f * t / (sc * nrm);
        const int nrow = qt * 64 + w * 16 + lg * 4 + r;
        const size_t dst = ((size_t)(b * 576 + nrow)) * 768 + h * 64;
#pragma unroll
        for (int hf = 0; hf < 4; ++hf) {
            float val = o_[hf] * f;
            u16 hb = bf16_rne(val);
            Oh[dst + hf * 16 + lr] = hb;
            Ol[dst + hf * 16 + lr] = bf16_rne(val - bf16_tof(hb));
        }
    }
}

// ---------------- launcher ----------------
extern "C" void kernel_launch(void* const* d_in, const int* in_sizes, int n_in,
                              void* d_out, int out_size, void* d_ws, size_t ws_size,
                              hipStream_t stream) {
    (void)in_sizes; (void)n_in; (void)out_size; (void)ws_size;
    const float* x    = (const float*)d_in[0];
    const float* Wq   = (const float*)d_in[1];
    const float* bq   = (const float*)d_in[2];
    const float* Wk   = (const float*)d_in[3];
    const float* bk   = (const float*)d_in[4];
    const float* Wv   = (const float*)d_in[5];
    const float* bv   = (const float*)d_in[6];
    const float* Wo   = (const float*)d_in[7];
    const float* bo   = (const float*)d_in[8];
    const float* cent = (const float*)d_in[9];
    const float* curv = (const float*)d_in[10];
    const float* sigr = (const float*)d_in[11];
    float* out = (float*)d_out;

    const size_t QH  = (size_t)B_ * H_ * N_ * 64;   // 7,077,888 (also K/V token size)
    const size_t CK  = (size_t)H_ * M_ * 64;        // 98,304 centroid-plane size
    const size_t WSZ = (size_t)D_ * D_;             // 589,824

    float* fp = (float*)d_ws;
    float* qh   = fp;            fp += QH;
    float* Khf  = fp;            fp += QH;
    float* Vhf  = fp;            fp += QH;
    float* x2q  = fp;            fp += (size_t)B_ * H_ * N_;
    float* y2g  = fp;            fp += (size_t)B_ * H_ * N_;
    float* gm1  = fp;            fp += (size_t)B_ * H_ * N_;
    float* y2c  = fp;            fp += (size_t)H_ * M_;
    float* gm1c = fp;            fp += (size_t)H_ * M_;
    u16* up = (u16*)fp;
    u16* xh  = up;  up += QH;     // aliased with Oh (xh dead before attn writes Oh)
    u16* xl  = up;  up += QH;     // aliased with Ol
    u16* Oh  = xh;
    u16* Ol  = xl;
    u16* Wqh = up;  up += WSZ;
    u16* Wql = up;  up += WSZ;
    u16* Wkh = up;  up += WSZ;
    u16* Wkl = up;  up += WSZ;
    u16* Wvh = up;  up += WSZ;
    u16* Wvl = up;  up += WSZ;
    u16* Woh = up;  up += WSZ;
    u16* Wol = up;  up += WSZ;
    u16* Qb  = up;  up += 3 * QH;
    u16* Kb  = up;  up += 3 * QH;
    u16* gV  = up;  up += 2 * QH;
    u16* Kc  = up;  up += 3 * CK;
    u16* gVc = up;  up += 2 * CK;

    u16* Qb0 = Qb;           u16* Qb1 = Qb + QH;   u16* Qb2 = Qb + 2 * QH;
    u16* Kb0 = Kb;           u16* Kb1 = Kb + QH;   u16* Kb2 = Kb + 2 * QH;
    u16* gV0 = gV;           u16* gV1 = gV + QH;
    u16* Kc0 = Kc;           u16* Kc1 = Kc + CK;   u16* Kc2 = Kc + 2 * CK;
    u16* gVc0 = gVc;         u16* gVc1 = gVc + CK;

    // 0: hi/lo splits (x + all 4 weights in 2 launches)
    split_bf16_kernel<<<(int)(QH / 4 / 256), 256, 0, stream>>>(x, xh, xl, (int)(QH / 4));
    split_w4_kernel<<<dim3((int)(WSZ / 4 / 256), 4), 256, 0, stream>>>(
        Wq, Wk, Wv, Wo, Wqh, Wql, Wkh, Wkl, Wvh, Wvl, Woh, Wol);

    // 1: QKV projections (MFMA, XCD-banded)
    gemm_qkv_mfma<<<1296, 256, 0, stream>>>(xh, xl, Wqh, Wql, Wkh, Wkl, Wvh, Wvl,
                                            bq, bk, bv, qh, Khf, Vhf);
    // 2: fused hyperbolic maps (q + K/V tokens + per-head centroids)
    maps_kernel<<<3480, 256, 0, stream>>>(qh, Khf, Vhf, cent,
                                          Qb0, Qb1, Qb2, Kb0, Kb1, Kb2, Kc0, Kc1, Kc2,
                                          gV0, gV1, gVc0, gVc1,
                                          x2q, y2g, gm1, y2c, gm1c, curv);
    // 4: fused attention (MFMA, LDS-staged, XCD-affine, shared centroid tiles)
    attn_kernel<<<1728, 256, 0, stream>>>(Qb0, Qb1, Qb2, Kb0, Kb1, Kb2, Kc0, Kc1, Kc2,
                                          gV0, gV1, gVc0, gVc1,
                                          x2q, y2g, gm1, y2c, gm1c, sigr, curv, Oh, Ol);
    // 5: output projection (MFMA, XCD-banded)
    gemm_o_mfma<<<432, 256, 0, stream>>>(Oh, Ol, Woh, Wol, bo, out);
}

// Round 9
// 430.303 us; speedup vs baseline: 3.1036x; 1.0660x over previous
//
#include <hip/hip_runtime.h>
#include <cstdint>
#include <cstddef>

#define B_  16
#define N_  576
#define D_  768
#define H_  12
#define HD_ 64
#define M_  128
#define J_  704   // N_ + M_

typedef unsigned short u16;
typedef __attribute__((ext_vector_type(8))) short bf16x8;
typedef __attribute__((ext_vector_type(4))) float f32x4;
typedef __attribute__((ext_vector_type(4))) unsigned short u16x4;
typedef __attribute__((ext_vector_type(8))) unsigned short u16x8;

// ---------------- helpers ----------------

__device__ __forceinline__ float softplus_f(float x) {
    return (x > 20.f) ? x : log1pf(expf(x));
}

__device__ __forceinline__ float wred_sum64(float v) {
#pragma unroll
    for (int m = 1; m < 64; m <<= 1) v += __shfl_xor(v, m, 64);
    return v;
}

__device__ __forceinline__ u16 bf16_rne(float f) {
    unsigned int u = __float_as_uint(f);
    unsigned int r = u + 0x7FFFu + ((u >> 16) & 1u);
    return (u16)(r >> 16);
}
__device__ __forceinline__ float bf16_tof(u16 h) {
    return __uint_as_float(((unsigned int)h) << 16);
}

// expmap0 total multiplier for a row with raw sumsq n2; also returns final ||out||^2
__device__ __forceinline__ float expmap0_factor(float n2, float sc, float* n2out) {
    const float ATANH_1M1E5 = 6.1030335f;     // artanh(1 - 1e-5)
    float n0 = sqrtf(fmaxf(n2, 1e-15f));
    float maxtan = ATANH_1M1E5 / sc;
    float f1 = fminf(1.f, maxtan / n0);       // pre-clip
    float n1 = n0 * f1;
    float a  = sc * n1;
    float th = tanhf(a);
    float yfac  = th / a;                     // y = u * f1 * yfac
    float ynorm = th / sc;
    float lim   = (1.f - 1e-5f) / sc;
    float f2 = fminf(1.f, lim / ynorm);       // post-clip
    float fn = ynorm * f2;
    *n2out = fn * fn;
    return f1 * yfac * f2;
}

__device__ __forceinline__ float artanh_fast(float z) {  // z in [0, 1-1e-7]
    return 0.5f * __logf((1.f + z) / (1.f - z));
}

// global -> LDS direct copy, 16B per lane (wave-uniform LDS base + lane*16)
typedef const __attribute__((address_space(1))) unsigned int* gas_u32;
typedef __attribute__((address_space(3))) unsigned int* las_u32;
__device__ __forceinline__ void gload_lds16(const u16* g, u16* l) {
    __builtin_amdgcn_global_load_lds((gas_u32)(const void*)g, (las_u32)(void*)l, 16, 0, 0);
}

// ---------------- kernel 0a: f32 -> bf16 hi/lo split (x) ----------------
__global__ __launch_bounds__(256) void split_bf16_kernel(
    const float* __restrict__ src, u16* __restrict__ hi, u16* __restrict__ lo, int n4)
{
    int i = blockIdx.x * 256 + threadIdx.x;
    if (i >= n4) return;
    float4 v = ((const float4*)src)[i];
    u16x4 h, l;
    h[0] = bf16_rne(v.x); l[0] = bf16_rne(v.x - bf16_tof(h[0]));
    h[1] = bf16_rne(v.y); l[1] = bf16_rne(v.y - bf16_tof(h[1]));
    h[2] = bf16_rne(v.z); l[2] = bf16_rne(v.z - bf16_tof(h[2]));
    h[3] = bf16_rne(v.w); l[3] = bf16_rne(v.w - bf16_tof(h[3]));
    ((u16x4*)hi)[i] = h;
    ((u16x4*)lo)[i] = l;
}

// ---------------- kernel 0b: split all 4 weight matrices in one launch ----------------
__global__ __launch_bounds__(256) void split_w4_kernel(
    const float* __restrict__ W0, const float* __restrict__ W1,
    const float* __restrict__ W2, const float* __restrict__ W3,
    u16* __restrict__ H0, u16* __restrict__ L0, u16* __restrict__ H1, u16* __restrict__ L1,
    u16* __restrict__ H2, u16* __restrict__ L2, u16* __restrict__ H3, u16* __restrict__ L3)
{
    int i = blockIdx.x * 256 + threadIdx.x;   // < WSZ/4 = 147456
    const int wsel = blockIdx.y;
    const float* src = wsel == 0 ? W0 : (wsel == 1 ? W1 : (wsel == 2 ? W2 : W3));
    u16* hi = wsel == 0 ? H0 : (wsel == 1 ? H1 : (wsel == 2 ? H2 : H3));
    u16* lo = wsel == 0 ? L0 : (wsel == 1 ? L1 : (wsel == 2 ? L2 : L3));
    float4 v = ((const float4*)src)[i];
    u16x4 h, l;
    h[0] = bf16_rne(v.x); l[0] = bf16_rne(v.x - bf16_tof(h[0]));
    h[1] = bf16_rne(v.y); l[1] = bf16_rne(v.y - bf16_tof(h[1]));
    h[2] = bf16_rne(v.z); l[2] = bf16_rne(v.z - bf16_tof(h[2]));
    h[3] = bf16_rne(v.w); l[3] = bf16_rne(v.w - bf16_tof(h[3]));
    ((u16x4*)hi)[i] = h;
    ((u16x4*)lo)[i] = l;
}

// ---------------- kernel 1: QKV projection + FUSED hyperbolic maps ----------------
// Epilogue computes expmap0 (per-row norm via a reduction tree that is bitwise
// identical to wred_sum64: per-ni lrow-butterfly masks 1,2,4,8 then (p0+p1)+(p2+p3)),
// emitting 3-plane bf16 q/K, transposed 2-plane gamma*V, and x2/y2/gm1 scalars
// directly from registers -- no f32 intermediate round trip.
__global__ __launch_bounds__(256) void gemm_qkv_mfma(
    const u16* __restrict__ xh, const u16* __restrict__ xl,
    const u16* __restrict__ Wh0, const u16* __restrict__ Wl0,
    const u16* __restrict__ Wh1, const u16* __restrict__ Wl1,
    const u16* __restrict__ Wh2, const u16* __restrict__ Wl2,
    const float* __restrict__ bq, const float* __restrict__ bk, const float* __restrict__ bv,
    u16* __restrict__ Qb0, u16* __restrict__ Qb1, u16* __restrict__ Qb2,
    u16* __restrict__ Kb0, u16* __restrict__ Kb1, u16* __restrict__ Kb2,
    u16* __restrict__ gV0, u16* __restrict__ gV1,
    float* __restrict__ x2q, float* __restrict__ y2g, float* __restrict__ gm1,
    const float* __restrict__ curv_raw)
{
    __shared__ u16 Ah[4096], Al[4096], Bh[4096], Bl[4096];   // 8 frags x 512 each
    const int tid = threadIdx.x;
    const int w = tid >> 6, lane = tid & 63;
    const int wr = w >> 1, wc = w & 1;
    const int lrow = lane & 15, lk8 = (lane >> 4) << 3;
    // XCD-band swizzle: 1296 blocks = 8 XCDs x (9 mt x 18 yb)
    const int bid = blockIdx.x;
    const int xcd = bid & 7, ser = bid >> 3;       // ser < 162
    const int mt = xcd * 9 + (ser % 9);
    const int yb = ser / 9;                        // < 18
    const int which = yb / 6, ct = yb - which * 6;
    const u16* Bp_h = which == 0 ? Wh0 : (which == 1 ? Wh1 : Wh2);
    const u16* Bp_l = which == 0 ? Wl0 : (which == 1 ? Wl1 : Wl2);
    const int row0 = mt * 128, col0 = ct * 128;

    const size_t a0 = (size_t)(row0 + (2 * w + 0) * 16 + lrow) * 768 + lk8;
    const size_t a1 = a0 + 16 * 768;
    const size_t b0 = (size_t)(col0 + (2 * w + 0) * 16 + lrow) * 768 + lk8;
    const size_t b1 = b0 + 16 * 768;
    u16* lAh0 = Ah + (2 * w) * 512; u16* lAh1 = lAh0 + 512;
    u16* lAl0 = Al + (2 * w) * 512; u16* lAl1 = lAl0 + 512;
    u16* lBh0 = Bh + (2 * w) * 512; u16* lBh1 = lBh0 + 512;
    u16* lBl0 = Bl + (2 * w) * 512; u16* lBl1 = lBl0 + 512;

    f32x4 acc[4][4];
#pragma unroll
    for (int i = 0; i < 4; ++i)
#pragma unroll
        for (int j = 0; j < 4; ++j) acc[i][j] = (f32x4){0.f, 0.f, 0.f, 0.f};

    for (int k0 = 0; k0 < 768; k0 += 32) {
        gload_lds16(xh + a0 + k0, lAh0);
        gload_lds16(xh + a1 + k0, lAh1);
        gload_lds16(xl + a0 + k0, lAl0);
        gload_lds16(xl + a1 + k0, lAl1);
        gload_lds16(Bp_h + b0 + k0, lBh0);
        gload_lds16(Bp_h + b1 + k0, lBh1);
        gload_lds16(Bp_l + b0 + k0, lBl0);
        gload_lds16(Bp_l + b1 + k0, lBl1);
        __syncthreads();
        bf16x8 aH[4], aL[4], bH[4], bL[4];
        const int lo8 = lane * 8;
#pragma unroll
        for (int i = 0; i < 4; ++i) {
            aH[i] = *(const bf16x8*)(Ah + (wr * 4 + i) * 512 + lo8);
            aL[i] = *(const bf16x8*)(Al + (wr * 4 + i) * 512 + lo8);
            bH[i] = *(const bf16x8*)(Bh + (wc * 4 + i) * 512 + lo8);
            bL[i] = *(const bf16x8*)(Bl + (wc * 4 + i) * 512 + lo8);
        }
#pragma unroll
        for (int mi = 0; mi < 4; ++mi)
#pragma unroll
            for (int ni = 0; ni < 4; ++ni) {
                acc[mi][ni] = __builtin_amdgcn_mfma_f32_16x16x32_bf16(aH[mi], bH[ni], acc[mi][ni], 0, 0, 0);
                acc[mi][ni] = __builtin_amdgcn_mfma_f32_16x16x32_bf16(aH[mi], bL[ni], acc[mi][ni], 0, 0, 0);
                acc[mi][ni] = __builtin_amdgcn_mfma_f32_16x16x32_bf16(aL[mi], bH[ni], acc[mi][ni], 0, 0, 0);
            }
        __syncthreads();
    }

    // ---------------- fused epilogue ----------------
    const float* bias = which == 0 ? bq : (which == 1 ? bk : bv);
    const int h = ct * 2 + wc;
    const int rbase = row0 + wr * 64 + ((lane >> 4) << 2);
    const float c  = softplus_f(curv_raw[0]);
    const float sc = sqrtf(c);
    float bvv[4];
#pragma unroll
    for (int ni = 0; ni < 4; ++ni) bvv[ni] = bias[h * 64 + ni * 16 + lrow];

#pragma unroll
    for (int mi = 0; mi < 4; ++mi) {
        float v4[4][4];   // [ni][r]
#pragma unroll
        for (int ni = 0; ni < 4; ++ni) {
            f32x4 a = acc[mi][ni];
#pragma unroll
            for (int r = 0; r < 4; ++r) v4[ni][r] = a[r] + bvv[ni];
        }
        // per-row sumsq: bitwise == wred_sum64 (bits 0-3 via lrow butterfly per ni,
        // bit4 via p0+p1/p2+p3, bit5 via the outer add)
        float f_[4], n2o_[4];
#pragma unroll
        for (int r = 0; r < 4; ++r) {
            float p[4];
#pragma unroll
            for (int ni = 0; ni < 4; ++ni) {
                float s = v4[ni][r] * v4[ni][r];
#pragma unroll
                for (int m = 1; m < 16; m <<= 1) s += __shfl_xor(s, m, 64);
                p[ni] = s;
            }
            float n2 = (p[0] + p[1]) + (p[2] + p[3]);
            f_[r] = expmap0_factor(n2, sc, &n2o_[r]);
        }
        const int row0g = rbase + mi * 16;          // 4 consecutive rows, same batch
        const int bb = row0g / 576;
        const int nn0 = row0g - bb * 576;
        const size_t gbase = ((size_t)(bb * 12 + h)) * 576 + nn0;
        if (which == 2) {
            float gmm[4];
#pragma unroll
            for (int r = 0; r < 4; ++r) gmm[r] = 2.f / fmaxf(1.f - c * n2o_[r], 1e-15f);
            if (lrow == 0) {
#pragma unroll
                for (int r = 0; r < 4; ++r) gm1[gbase + r] = gmm[r] - 1.f;
            }
#pragma unroll
            for (int ni = 0; ni < 4; ++ni) {
                const int hd = ni * 16 + lrow;
                u16x4 hs, ls;
#pragma unroll
                for (int r = 0; r < 4; ++r) {
                    float gv = v4[ni][r] * f_[r] * gmm[r];
                    u16 hb = bf16_rne(gv);
                    hs[r] = hb;
                    ls[r] = bf16_rne(gv - bf16_tof(hb));
                }
                const size_t dst = (((size_t)(bb * 12 + h)) * 64 + hd) * 576 + nn0;
                *(u16x4*)(gV0 + dst) = hs;
                *(u16x4*)(gV1 + dst) = ls;
            }
        } else {
            float* scal = which == 0 ? x2q : y2g;
            if (lrow == 0) {
#pragma unroll
                for (int r = 0; r < 4; ++r) scal[gbase + r] = n2o_[r];
            }
            u16* P0 = which == 0 ? Qb0 : Kb0;
            u16* P1 = which == 0 ? Qb1 : Kb1;
            u16* P2 = which == 0 ? Qb2 : Kb2;
#pragma unroll
            for (int ni = 0; ni < 4; ++ni) {
                const int hd = ni * 16 + lrow;
#pragma unroll
                for (int r = 0; r < 4; ++r) {
                    float y = v4[ni][r] * f_[r];
                    u16 hb = bf16_rne(y);
                    float r1 = y - bf16_tof(hb);
                    u16 mb = bf16_rne(r1);
                    u16 lb = bf16_rne(r1 - bf16_tof(mb));
                    const size_t off = (gbase + r) * 64 + hd;
                    P0[off] = hb; P1[off] = mb; P2[off] = lb;
                }
            }
        }
    }
}

// ---------------- kernel 5: output projection (split-bf16 MFMA, XCD-banded) ----------------
__global__ __launch_bounds__(256) void gemm_o_mfma(
    const u16* __restrict__ Oh, const u16* __restrict__ Ol,
    const u16* __restrict__ Wh, const u16* __restrict__ Wl,
    const float* __restrict__ bo, float* __restrict__ out)
{
    __shared__ u16 Ah[4096], Al[4096], Bh[4096], Bl[4096];
    const int tid = threadIdx.x;
    const int w = tid >> 6, lane = tid & 63;
    const int wr = w >> 1, wc = w & 1;
    const int lrow = lane & 15, lk8 = (lane >> 4) << 3;
    // 432 blocks = 8 XCDs x (9 mt x 6 ct)
    const int bid = blockIdx.x;
    const int xcd = bid & 7, ser = bid >> 3;       // ser < 54
    const int mt = xcd * 9 + (ser % 9);
    const int ct = ser / 9;                        // < 6
    const int row0 = mt * 128, col0 = ct * 128;

    const size_t a0 = (size_t)(row0 + (2 * w + 0) * 16 + lrow) * 768 + lk8;
    const size_t a1 = a0 + 16 * 768;
    const size_t b0 = (size_t)(col0 + (2 * w + 0) * 16 + lrow) * 768 + lk8;
    const size_t b1 = b0 + 16 * 768;
    u16* lAh0 = Ah + (2 * w) * 512; u16* lAh1 = lAh0 + 512;
    u16* lAl0 = Al + (2 * w) * 512; u16* lAl1 = lAl0 + 512;
    u16* lBh0 = Bh + (2 * w) * 512; u16* lBh1 = lBh0 + 512;
    u16* lBl0 = Bl + (2 * w) * 512; u16* lBl1 = lBl0 + 512;

    f32x4 acc[4][4];
#pragma unroll
    for (int i = 0; i < 4; ++i)
#pragma unroll
        for (int j = 0; j < 4; ++j) acc[i][j] = (f32x4){0.f, 0.f, 0.f, 0.f};

    for (int k0 = 0; k0 < 768; k0 += 32) {
        gload_lds16(Oh + a0 + k0, lAh0);
        gload_lds16(Oh + a1 + k0, lAh1);
        gload_lds16(Ol + a0 + k0, lAl0);
        gload_lds16(Ol + a1 + k0, lAl1);
        gload_lds16(Wh + b0 + k0, lBh0);
        gload_lds16(Wh + b1 + k0, lBh1);
        gload_lds16(Wl + b0 + k0, lBl0);
        gload_lds16(Wl + b1 + k0, lBl1);
        __syncthreads();
        bf16x8 aH[4], aL[4], bH[4], bL[4];
        const int lo8 = lane * 8;
#pragma unroll
        for (int i = 0; i < 4; ++i) {
            aH[i] = *(const bf16x8*)(Ah + (wr * 4 + i) * 512 + lo8);
            aL[i] = *(const bf16x8*)(Al + (wr * 4 + i) * 512 + lo8);
            bH[i] = *(const bf16x8*)(Bh + (wc * 4 + i) * 512 + lo8);
            bL[i] = *(const bf16x8*)(Bl + (wc * 4 + i) * 512 + lo8);
        }
#pragma unroll
        for (int mi = 0; mi < 4; ++mi)
#pragma unroll
            for (int ni = 0; ni < 4; ++ni) {
                acc[mi][ni] = __builtin_amdgcn_mfma_f32_16x16x32_bf16(aH[mi], bH[ni], acc[mi][ni], 0, 0, 0);
                acc[mi][ni] = __builtin_amdgcn_mfma_f32_16x16x32_bf16(aH[mi], bL[ni], acc[mi][ni], 0, 0, 0);
                acc[mi][ni] = __builtin_amdgcn_mfma_f32_16x16x32_bf16(aL[mi], bH[ni], acc[mi][ni], 0, 0, 0);
            }
        __syncthreads();
    }

    const int rbase = row0 + wr * 64 + ((lane >> 4) << 2);
#pragma unroll
    for (int ni = 0; ni < 4; ++ni) {
        const int colg = col0 + wc * 64 + ni * 16 + lrow;
        const float bv_ = bo[colg];
#pragma unroll
        for (int mi = 0; mi < 4; ++mi) {
            f32x4 a = acc[mi][ni];
#pragma unroll
            for (int r = 0; r < 4; ++r) {
                int row = rbase + mi * 16 + r;
                out[(size_t)row * 768 + colg] = a[r] + bv_;
            }
        }
    }
}

// ---------------- kernel 2: per-head centroid maps (once, shared across batch) ----------------
__global__ __launch_bounds__(256) void cent_kernel(
    const float* __restrict__ cent,
    u16* __restrict__ Kc0, u16* __restrict__ Kc1, u16* __restrict__ Kc2,
    u16* __restrict__ gVc0, u16* __restrict__ gVc1,
    float* __restrict__ y2c, float* __restrict__ gm1c,
    const float* __restrict__ curv_raw)
{
    __shared__ float gvt_s[64][65];
    const float c  = softplus_f(curv_raw[0]);
    const float sc = sqrtf(c);
    const int t = blockIdx.x;         // < 24
    const int h = t >> 1, ct = t & 1;
    const int w = threadIdx.x >> 6, lane = threadIdx.x & 63;
#pragma unroll 4
    for (int i = 0; i < 16; ++i) {
        const int m = ct * 64 + w * 16 + i;
        const size_t g = (size_t)h * 128 + m;
        float cv = cent[g * 64 + lane];
        float n2 = wred_sum64(cv * cv);
        float n2o;
        float f = expmap0_factor(n2, sc, &n2o);
        float ky = cv * f;
        u16 kh = bf16_rne(ky);
        float r1 = ky - bf16_tof(kh);
        u16 km = bf16_rne(r1);
        u16 kl = bf16_rne(r1 - bf16_tof(km));
        Kc0[g * 64 + lane] = kh; Kc1[g * 64 + lane] = km; Kc2[g * 64 + lane] = kl;
        float gmm = 2.f / fmaxf(1.f - c * n2o, 1e-15f);
        gvt_s[lane][w * 16 + i] = ky * gmm;
        if (lane == 0) { y2c[g] = n2o; gm1c[g] = gmm - 1.f; }
    }
    __syncthreads();
    const int hd = threadIdx.x >> 2, j0 = (threadIdx.x & 3) * 16;
    u16 hb[16], lb[16];
#pragma unroll
    for (int e = 0; e < 16; ++e) {
        float v = gvt_s[hd][j0 + e];
        hb[e] = bf16_rne(v);
        lb[e] = bf16_rne(v - bf16_tof(hb[e]));
    }
    const size_t dst = ((size_t)h * 64 + hd) * 128 + ct * 64 + j0;
    *(u16x8*)(gVc0 + dst)     = *(u16x8*)&hb[0];
    *(u16x8*)(gVc0 + dst + 8) = *(u16x8*)&hb[8];
    *(u16x8*)(gVc1 + dst)     = *(u16x8*)&lb[0];
    *(u16x8*)(gVc1 + dst + 8) = *(u16x8*)&lb[8];
}

// ---------------- kernel 4: fused hyperbolic attention (MFMA, LDS-staged K/V) ----------------
__global__ __launch_bounds__(256) void attn_kernel(
    const u16* __restrict__ Qb0, const u16* __restrict__ Qb1, const u16* __restrict__ Qb2,
    const u16* __restrict__ Kb0, const u16* __restrict__ Kb1, const u16* __restrict__ Kb2,
    const u16* __restrict__ Kc0, const u16* __restrict__ Kc1, const u16* __restrict__ Kc2,
    const u16* __restrict__ gV0, const u16* __restrict__ gV1,
    const u16* __restrict__ gVc0, const u16* __restrict__ gVc1,
    const float* __restrict__ x2q, const float* __restrict__ y2g, const float* __restrict__ gm1,
    const float* __restrict__ y2c, const float* __restrict__ gm1c,
    const float* __restrict__ sigma_raw, const float* __restrict__ curv_raw,
    u16* __restrict__ Oh, u16* __restrict__ Ol)
{
    __shared__ __align__(16) u16 Kst[2][3][4096];  // [buf][plane][row*64 + swizzled col]
    __shared__ __align__(16) u16 Vst[2][4096];     // [plane][row*64 + swizzled col]
    __shared__ __align__(16) u16 wb_hi[4][1024];
    __shared__ __align__(16) u16 wb_lo[4][1024];

    const int blk = blockIdx.x;
    const int xcd = blk & 7;
    const int serial = blk >> 3;
    const int bhg = serial / 9;
    const int qt = serial - bhg * 9;
    const int bh = bhg * 8 + xcd;
    const int b = bh / 12, h = bh % 12;
    const float c  = softplus_f(curv_raw[0]);
    const float sc = sqrtf(c);
    const float sig = softplus_f(sigma_raw[h]) + 1e-6f;
    const float coef = -2.f / (c * sig * sig);   // logit = coef * artanh(arg)^2
    const float c2h  = coef * 0.25f * 0.6931471805599453f;  // exp2 basis
    const float m2c  = -2.f * c;
    const float CLIP = 1.f - 1e-7f;

    const int tid = threadIdx.x;
    const int w = tid >> 6, lane = tid & 63;
    const int lr = lane & 15, lg = lane >> 4, lo8 = lg * 8;
    const int swl = (lr & 7) << 3;

    const size_t qbase = (size_t)bh * 576 + qt * 64;

    int srow[2], scol[2];
#pragma unroll
    for (int rr = 0; rr < 2; ++rr) {
        int cch = (rr * 4 + w) * 64 + lane;
        srow[rr] = cch >> 3;
        scol[rr] = ((cch & 7) ^ (srow[rr] & 7)) << 3;
    }
    const size_t kb_base = (size_t)bh * 576 * 64;
    const size_t kc_base = (size_t)h * 128 * 64;
    const size_t vb_base = (size_t)bh * 64 * 576;
    const size_t vc_base = (size_t)h * 64 * 128;

    auto stageK = [&](int t, int buf) {
        if (t < 9) {
            const size_t rb = kb_base + (size_t)t * 64 * 64;
#pragma unroll
            for (int rr = 0; rr < 2; ++rr) {
                const size_t so = rb + (size_t)srow[rr] * 64 + scol[rr];
                gload_lds16(Kb0 + so, &Kst[buf][0][(rr * 4 + w) * 512]);
                gload_lds16(Kb1 + so, &Kst[buf][1][(rr * 4 + w) * 512]);
                gload_lds16(Kb2 + so, &Kst[buf][2][(rr * 4 + w) * 512]);
            }
        } else {
            const size_t rb = kc_base + (size_t)(t - 9) * 64 * 64;
#pragma unroll
            for (int rr = 0; rr < 2; ++rr) {
                const size_t so = rb + (size_t)srow[rr] * 64 + scol[rr];
                gload_lds16(Kc0 + so, &Kst[buf][0][(rr * 4 + w) * 512]);
                gload_lds16(Kc1 + so, &Kst[buf][1][(rr * 4 + w) * 512]);
                gload_lds16(Kc2 + so, &Kst[buf][2][(rr * 4 + w) * 512]);
            }
        }
    };
    auto stageV = [&](int t) {
        if (t < 9) {
            const size_t rb = vb_base + (size_t)t * 64;
#pragma unroll
            for (int rr = 0; rr < 2; ++rr) {
                const size_t so = rb + (size_t)srow[rr] * 576 + scol[rr];
                gload_lds16(gV0 + so, &Vst[0][(rr * 4 + w) * 512]);
                gload_lds16(gV1 + so, &Vst[1][(rr * 4 + w) * 512]);
            }
        } else {
            const size_t rb = vc_base + (size_t)(t - 9) * 64;
#pragma unroll
            for (int rr = 0; rr < 2; ++rr) {
                const size_t so = rb + (size_t)srow[rr] * 128 + scol[rr];
                gload_lds16(gVc0 + so, &Vst[0][(rr * 4 + w) * 512]);
                gload_lds16(gVc1 + so, &Vst[1][(rr * 4 + w) * 512]);
            }
        }
    };

    bf16x8 aQh[2], aQm[2], aQl[2];
    {
        const size_t qrow = (qbase + w * 16 + lr) * 64;
#pragma unroll
        for (int kt = 0; kt < 2; ++kt) {
            const size_t o = qrow + kt * 32 + lo8;
            aQh[kt] = *(const bf16x8*)(Qb0 + o);
            aQm[kt] = *(const bf16x8*)(Qb1 + o);
            aQl[kt] = *(const bf16x8*)(Qb2 + o);
        }
    }
    float x2r[4], m2Bc[4], Bc2[4], ccx2[4];
#pragma unroll
    for (int r = 0; r < 4; ++r) {
        float x2 = x2q[qbase + w * 16 + lg * 4 + r];
        float Bc = fmaf(-c, x2, 1.f);
        x2r[r] = x2; m2Bc[r] = -2.f * Bc; Bc2[r] = Bc * Bc; ccx2[r] = c * c * x2;
    }

    f32x4 pv[4];
#pragma unroll
    for (int i = 0; i < 4; ++i) pv[i] = (f32x4){0.f, 0.f, 0.f, 0.f};
    float den[4] = {0.f, 0.f, 0.f, 0.f};

    u16* wbh = &wb_hi[w][0];
    u16* wbl = &wb_lo[w][0];

    stageK(0, 0);
    __syncthreads();

    int cur = 0;
    for (int jt = 0; jt < 11; ++jt) {
        const int jb = jt * 64;

        if (jt < 10) stageK(jt + 1, cur ^ 1);
        stageV(jt);

        const float* y2p;
        const float* gm1p;
        if (jt < 9) { y2p = y2g + (size_t)bh * 576 + jb;  gm1p = gm1 + (size_t)bh * 576 + jb; }
        else        { y2p = y2c + (size_t)h * 128 + (jb - 576); gm1p = gm1c + (size_t)h * 128 + (jb - 576); }

        const u16* kp0 = &Kst[cur][0][0];
        const u16* kp1 = &Kst[cur][1][0];
        const u16* kp2 = &Kst[cur][2][0];
        f32x4 sf[4];
        float y2v[4], gm1v[4];
#pragma unroll
        for (int jf = 0; jf < 4; ++jf) {
            y2v[jf] = y2p[jf * 16 + lr];
            gm1v[jf] = gm1p[jf * 16 + lr];
            const int rb = (jf * 16 + lr) * 64;
            f32x4 s = (f32x4){0.f, 0.f, 0.f, 0.f};
#pragma unroll
            for (int kt = 0; kt < 2; ++kt) {
                const int o = rb + ((kt * 32 + lo8) ^ swl);
                bf16x8 kh = *(const bf16x8*)(kp0 + o);
                bf16x8 km = *(const bf16x8*)(kp1 + o);
                bf16x8 kl = *(const bf16x8*)(kp2 + o);
                s = __builtin_amdgcn_mfma_f32_16x16x32_bf16(aQh[kt], kh, s, 0, 0, 0);
                s = __builtin_amdgcn_mfma_f32_16x16x32_bf16(aQh[kt], km, s, 0, 0, 0);
                s = __builtin_amdgcn_mfma_f32_16x16x32_bf16(aQm[kt], kh, s, 0, 0, 0);
                s = __builtin_amdgcn_mfma_f32_16x16x32_bf16(aQm[kt], km, s, 0, 0, 0);
                s = __builtin_amdgcn_mfma_f32_16x16x32_bf16(aQh[kt], kl, s, 0, 0, 0);
                s = __builtin_amdgcn_mfma_f32_16x16x32_bf16(aQl[kt], kh, s, 0, 0, 0);
            }
            sf[jf] = s;
        }

#pragma unroll
        for (int jf = 0; jf < 4; ++jf) {
            const float y2 = y2v[jf];
            const float cy2 = c * y2;
#pragma unroll
            for (int r = 0; r < 4; ++r) {
                float xy = sf[jf][r];
                float one = fmaf(m2c, xy, 1.f);          // 1 - 2c*xy
                float A   = one + cy2;
                float dn  = fmaf(ccx2[r], y2, one);      // 1 - 2c*xy + c^2*x2*y2
                float u   = A * x2r[r];
                u = fmaf(m2Bc[r], xy, u);
                float num2 = fmaf(A, u, Bc2[r] * y2);
                num2 = fmaxf(num2, 0.f);
                float s = sqrtf(num2) * sc;
                float dnc = fmaxf(dn, 1e-15f);
                s = fminf(s, dnc * CLIP);                // folds the artanh arg clip
                float td = __builtin_amdgcn_logf(dnc + s) - __builtin_amdgcn_logf(dnc - s);
                float wv_ = __builtin_amdgcn_exp2f(c2h * td * td);
                sf[jf][r] = wv_;
                den[r] = fmaf(wv_, gm1v[jf], den[r]);
            }
        }

#pragma unroll
        for (int r = 0; r < 4; ++r) {
            const int row = lg * 4 + r;
            const int sw = (row & 7) << 3;
#pragma unroll
            for (int jf = 0; jf < 4; ++jf) {
                const int colu = (jf * 16 + lr) ^ sw;
                float wv_ = sf[jf][r];
                u16 hb = bf16_rne(wv_);
                wbh[row * 64 + colu] = hb;
                wbl[row * 64 + colu] = bf16_rne(wv_ - bf16_tof(hb));
            }
        }

        __syncthreads();   // V staged (vmcnt drained); K prefetch also landed

        bf16x8 aWh[2], aWl[2];
#pragma unroll
        for (int kt = 0; kt < 2; ++kt) {
            const int colu = (kt * 32 + lo8) ^ swl;
            aWh[kt] = *(const bf16x8*)(wbh + lr * 64 + colu);
            aWl[kt] = *(const bf16x8*)(wbl + lr * 64 + colu);
        }

#pragma unroll
        for (int hf = 0; hf < 4; ++hf) {
            const int rb = (hf * 16 + lr) * 64;
#pragma unroll
            for (int kt = 0; kt < 2; ++kt) {
                const int o = rb + ((kt * 32 + lo8) ^ swl);
                bf16x8 vh = *(const bf16x8*)(&Vst[0][o]);
                bf16x8 vl = *(const bf16x8*)(&Vst[1][o]);
                pv[hf] = __builtin_amdgcn_mfma_f32_16x16x32_bf16(aWh[kt], vh, pv[hf], 0, 0, 0);
                pv[hf] = __builtin_amdgcn_mfma_f32_16x16x32_bf16(aWh[kt], vl, pv[hf], 0, 0, 0);
                pv[hf] = __builtin_amdgcn_mfma_f32_16x16x32_bf16(aWl[kt], vh, pv[hf], 0, 0, 0);
            }
        }

        __syncthreads();
        cur ^= 1;
    }

#pragma unroll
    for (int r = 0; r < 4; ++r) {
        float d = den[r];
#pragma unroll
        for (int msk = 1; msk < 16; msk <<= 1) d += __shfl_xor(d, msk, 64);
        float rd = 1.f / d;                      // den > 0 always (gamma-1 >= 1)
        float o_[4];
        float n2 = 0.f;
#pragma unroll
        for (int hf = 0; hf < 4; ++hf) { o_[hf] = pv[hf][r] * rd; n2 = fmaf(o_[hf], o_[hf], n2); }
#pragma unroll
        for (int msk = 1; msk < 16; msk <<= 1) n2 += __shfl_xor(n2, msk, 64);
        float nrm = sqrtf(fmaxf(n2, 1e-15f));
        float arg = fminf(sc * nrm, 1.f - 1e-7f);
        float t = artanh_fast(arg);
        float f = 0.5f * t / (sc * nrm);
        const int nrow = qt * 64 + w * 16 + lg * 4 + r;
        const size_t dst = ((size_t)(b * 576 + nrow)) * 768 + h * 64;
#pragma unroll
        for (int hf = 0; hf < 4; ++hf) {
            float val = o_[hf] * f;
            u16 hb = bf16_rne(val);
            Oh[dst + hf * 16 + lr] = hb;
            Ol[dst + hf * 16 + lr] = bf16_rne(val - bf16_tof(hb));
        }
    }
}

// ---------------- launcher ----------------
extern "C" void kernel_launch(void* const* d_in, const int* in_sizes, int n_in,
                              void* d_out, int out_size, void* d_ws, size_t ws_size,
                              hipStream_t stream) {
    (void)in_sizes; (void)n_in; (void)out_size; (void)ws_size;
    const float* x    = (const float*)d_in[0];
    const float* Wq   = (const float*)d_in[1];
    const float* bq   = (const float*)d_in[2];
    const float* Wk   = (const float*)d_in[3];
    const float* bk   = (const float*)d_in[4];
    const float* Wv   = (const float*)d_in[5];
    const float* bv   = (const float*)d_in[6];
    const float* Wo   = (const float*)d_in[7];
    const float* bo   = (const float*)d_in[8];
    const float* cent = (const float*)d_in[9];
    const float* curv = (const float*)d_in[10];
    const float* sigr = (const float*)d_in[11];
    float* out = (float*)d_out;

    const size_t QH  = (size_t)B_ * H_ * N_ * 64;   // 7,077,888 (also K/V token size)
    const size_t CK  = (size_t)H_ * M_ * 64;        // 98,304 centroid-plane size
    const size_t WSZ = (size_t)D_ * D_;             // 589,824

    float* fp = (float*)d_ws;
    float* x2q  = fp;            fp += (size_t)B_ * H_ * N_;
    float* y2g  = fp;            fp += (size_t)B_ * H_ * N_;
    float* gm1  = fp;            fp += (size_t)B_ * H_ * N_;
    float* y2c  = fp;            fp += (size_t)H_ * M_;
    float* gm1c = fp;            fp += (size_t)H_ * M_;
    u16* up = (u16*)fp;
    u16* xh  = up;  up += QH;     // aliased with Oh (xh dead before attn writes Oh)
    u16* xl  = up;  up += QH;     // aliased with Ol
    u16* Oh  = xh;
    u16* Ol  = xl;
    u16* Wqh = up;  up += WSZ;
    u16* Wql = up;  up += WSZ;
    u16* Wkh = up;  up += WSZ;
    u16* Wkl = up;  up += WSZ;
    u16* Wvh = up;  up += WSZ;
    u16* Wvl = up;  up += WSZ;
    u16* Woh = up;  up += WSZ;
    u16* Wol = up;  up += WSZ;
    u16* Qb  = up;  up += 3 * QH;
    u16* Kb  = up;  up += 3 * QH;
    u16* gV  = up;  up += 2 * QH;
    u16* Kc  = up;  up += 3 * CK;
    u16* gVc = up;  up += 2 * CK;

    u16* Qb0 = Qb;           u16* Qb1 = Qb + QH;   u16* Qb2 = Qb + 2 * QH;
    u16* Kb0 = Kb;           u16* Kb1 = Kb + QH;   u16* Kb2 = Kb + 2 * QH;
    u16* gV0 = gV;           u16* gV1 = gV + QH;
    u16* Kc0 = Kc;           u16* Kc1 = Kc + CK;   u16* Kc2 = Kc + 2 * CK;
    u16* gVc0 = gVc;         u16* gVc1 = gVc + CK;

    // 0: hi/lo splits (x + all 4 weights)
    split_bf16_kernel<<<(int)(QH / 4 / 256), 256, 0, stream>>>(x, xh, xl, (int)(QH / 4));
    split_w4_kernel<<<dim3((int)(WSZ / 4 / 256), 4), 256, 0, stream>>>(
        Wq, Wk, Wv, Wo, Wqh, Wql, Wkh, Wkl, Wvh, Wvl, Woh, Wol);

    // 2: per-head centroid maps (independent of GEMM)
    cent_kernel<<<24, 256, 0, stream>>>(cent, Kc0, Kc1, Kc2, gVc0, gVc1, y2c, gm1c, curv);

    // 1: QKV projections + fused hyperbolic maps (MFMA, XCD-banded)
    gemm_qkv_mfma<<<1296, 256, 0, stream>>>(xh, xl, Wqh, Wql, Wkh, Wkl, Wvh, Wvl,
                                            bq, bk, bv,
                                            Qb0, Qb1, Qb2, Kb0, Kb1, Kb2, gV0, gV1,
                                            x2q, y2g, gm1, curv);
    // 4: fused attention (MFMA, LDS-staged, XCD-affine, shared centroid tiles)
    attn_kernel<<<1728, 256, 0, stream>>>(Qb0, Qb1, Qb2, Kb0, Kb1, Kb2, Kc0, Kc1, Kc2,
                                          gV0, gV1, gVc0, gVc1,
                                          x2q, y2g, gm1, y2c, gm1c, sigr, curv, Oh, Ol);
    // 5: output projection (MFMA, XCD-banded)
    gemm_o_mfma<<<432, 256, 0, stream>>>(Oh, Ol, Woh, Wol, bo, out);
}

// Round 10
// 392.104 us; speedup vs baseline: 3.4060x; 1.0974x over previous
//
#include <hip/hip_runtime.h>
#include <cstdint>
#include <cstddef>

#define B_  16
#define N_  576
#define D_  768
#define H_  12
#define HD_ 64
#define M_  128
#define J_  704   // N_ + M_

typedef unsigned short u16;
typedef __attribute__((ext_vector_type(8))) short bf16x8;
typedef __attribute__((ext_vector_type(4))) float f32x4;
typedef __attribute__((ext_vector_type(4))) unsigned short u16x4;
typedef __attribute__((ext_vector_type(8))) unsigned short u16x8;

// ---------------- helpers ----------------

__device__ __forceinline__ float softplus_f(float x) {
    return (x > 20.f) ? x : log1pf(expf(x));
}

__device__ __forceinline__ float wred_sum64(float v) {
#pragma unroll
    for (int m = 1; m < 64; m <<= 1) v += __shfl_xor(v, m, 64);
    return v;
}

__device__ __forceinline__ u16 bf16_rne(float f) {
    unsigned int u = __float_as_uint(f);
    unsigned int r = u + 0x7FFFu + ((u >> 16) & 1u);
    return (u16)(r >> 16);
}
__device__ __forceinline__ float bf16_tof(u16 h) {
    return __uint_as_float(((unsigned int)h) << 16);
}

// expmap0 total multiplier for a row with raw sumsq n2; also returns final ||out||^2
__device__ __forceinline__ float expmap0_factor(float n2, float sc, float* n2out) {
    const float ATANH_1M1E5 = 6.1030335f;     // artanh(1 - 1e-5)
    float n0 = sqrtf(fmaxf(n2, 1e-15f));
    float maxtan = ATANH_1M1E5 / sc;
    float f1 = fminf(1.f, maxtan / n0);       // pre-clip
    float n1 = n0 * f1;
    float a  = sc * n1;
    float th = tanhf(a);
    float yfac  = th / a;                     // y = u * f1 * yfac
    float ynorm = th / sc;
    float lim   = (1.f - 1e-5f) / sc;
    float f2 = fminf(1.f, lim / ynorm);       // post-clip
    float fn = ynorm * f2;
    *n2out = fn * fn;
    return f1 * yfac * f2;
}

__device__ __forceinline__ float artanh_fast(float z) {  // z in [0, 1-1e-7]
    return 0.5f * __logf((1.f + z) / (1.f - z));
}

// global -> LDS direct copy, 16B per lane (wave-uniform LDS base + lane*16)
typedef const __attribute__((address_space(1))) unsigned int* gas_u32;
typedef __attribute__((address_space(3))) unsigned int* las_u32;
__device__ __forceinline__ void gload_lds16(const u16* g, u16* l) {
    __builtin_amdgcn_global_load_lds((gas_u32)(const void*)g, (las_u32)(void*)l, 16, 0, 0);
}

// ---------------- kernel 0a: f32 -> bf16 hi/lo split (x) ----------------
__global__ __launch_bounds__(256) void split_bf16_kernel(
    const float* __restrict__ src, u16* __restrict__ hi, u16* __restrict__ lo, int n4)
{
    int i = blockIdx.x * 256 + threadIdx.x;
    if (i >= n4) return;
    float4 v = ((const float4*)src)[i];
    u16x4 h, l;
    h[0] = bf16_rne(v.x); l[0] = bf16_rne(v.x - bf16_tof(h[0]));
    h[1] = bf16_rne(v.y); l[1] = bf16_rne(v.y - bf16_tof(h[1]));
    h[2] = bf16_rne(v.z); l[2] = bf16_rne(v.z - bf16_tof(h[2]));
    h[3] = bf16_rne(v.w); l[3] = bf16_rne(v.w - bf16_tof(h[3]));
    ((u16x4*)hi)[i] = h;
    ((u16x4*)lo)[i] = l;
}

// ---------------- kernel 0b: split all 4 weight matrices in one launch ----------------
__global__ __launch_bounds__(256) void split_w4_kernel(
    const float* __restrict__ W0, const float* __restrict__ W1,
    const float* __restrict__ W2, const float* __restrict__ W3,
    u16* __restrict__ H0, u16* __restrict__ L0, u16* __restrict__ H1, u16* __restrict__ L1,
    u16* __restrict__ H2, u16* __restrict__ L2, u16* __restrict__ H3, u16* __restrict__ L3)
{
    int i = blockIdx.x * 256 + threadIdx.x;   // < WSZ/4 = 147456
    const int wsel = blockIdx.y;
    const float* src = wsel == 0 ? W0 : (wsel == 1 ? W1 : (wsel == 2 ? W2 : W3));
    u16* hi = wsel == 0 ? H0 : (wsel == 1 ? H1 : (wsel == 2 ? H2 : H3));
    u16* lo = wsel == 0 ? L0 : (wsel == 1 ? L1 : (wsel == 2 ? L2 : L3));
    float4 v = ((const float4*)src)[i];
    u16x4 h, l;
    h[0] = bf16_rne(v.x); l[0] = bf16_rne(v.x - bf16_tof(h[0]));
    h[1] = bf16_rne(v.y); l[1] = bf16_rne(v.y - bf16_tof(h[1]));
    h[2] = bf16_rne(v.z); l[2] = bf16_rne(v.z - bf16_tof(h[2]));
    h[3] = bf16_rne(v.w); l[3] = bf16_rne(v.w - bf16_tof(h[3]));
    ((u16x4*)hi)[i] = h;
    ((u16x4*)lo)[i] = l;
}

// ---------------- kernel 1: QKV projection + FUSED hyperbolic maps ----------------
__global__ __launch_bounds__(256) void gemm_qkv_mfma(
    const u16* __restrict__ xh, const u16* __restrict__ xl,
    const u16* __restrict__ Wh0, const u16* __restrict__ Wl0,
    const u16* __restrict__ Wh1, const u16* __restrict__ Wl1,
    const u16* __restrict__ Wh2, const u16* __restrict__ Wl2,
    const float* __restrict__ bq, const float* __restrict__ bk, const float* __restrict__ bv,
    u16* __restrict__ Qb0, u16* __restrict__ Qb1, u16* __restrict__ Qb2,
    u16* __restrict__ Kb0, u16* __restrict__ Kb1, u16* __restrict__ Kb2,
    u16* __restrict__ gV0, u16* __restrict__ gV1,
    float* __restrict__ x2q, float* __restrict__ y2g, float* __restrict__ gm1,
    float* __restrict__ rbj,
    const float* __restrict__ curv_raw)
{
    __shared__ u16 Ah[4096], Al[4096], Bh[4096], Bl[4096];   // 8 frags x 512 each
    const int tid = threadIdx.x;
    const int w = tid >> 6, lane = tid & 63;
    const int wr = w >> 1, wc = w & 1;
    const int lrow = lane & 15, lk8 = (lane >> 4) << 3;
    // XCD-band swizzle: 1296 blocks = 8 XCDs x (9 mt x 18 yb)
    const int bid = blockIdx.x;
    const int xcd = bid & 7, ser = bid >> 3;       // ser < 162
    const int mt = xcd * 9 + (ser % 9);
    const int yb = ser / 9;                        // < 18
    const int which = yb / 6, ct = yb - which * 6;
    const u16* Bp_h = which == 0 ? Wh0 : (which == 1 ? Wh1 : Wh2);
    const u16* Bp_l = which == 0 ? Wl0 : (which == 1 ? Wl1 : Wl2);
    const int row0 = mt * 128, col0 = ct * 128;

    const size_t a0 = (size_t)(row0 + (2 * w + 0) * 16 + lrow) * 768 + lk8;
    const size_t a1 = a0 + 16 * 768;
    const size_t b0 = (size_t)(col0 + (2 * w + 0) * 16 + lrow) * 768 + lk8;
    const size_t b1 = b0 + 16 * 768;
    u16* lAh0 = Ah + (2 * w) * 512; u16* lAh1 = lAh0 + 512;
    u16* lAl0 = Al + (2 * w) * 512; u16* lAl1 = lAl0 + 512;
    u16* lBh0 = Bh + (2 * w) * 512; u16* lBh1 = lBh0 + 512;
    u16* lBl0 = Bl + (2 * w) * 512; u16* lBl1 = lBl0 + 512;

    f32x4 acc[4][4];
#pragma unroll
    for (int i = 0; i < 4; ++i)
#pragma unroll
        for (int j = 0; j < 4; ++j) acc[i][j] = (f32x4){0.f, 0.f, 0.f, 0.f};

    for (int k0 = 0; k0 < 768; k0 += 32) {
        gload_lds16(xh + a0 + k0, lAh0);
        gload_lds16(xh + a1 + k0, lAh1);
        gload_lds16(xl + a0 + k0, lAl0);
        gload_lds16(xl + a1 + k0, lAl1);
        gload_lds16(Bp_h + b0 + k0, lBh0);
        gload_lds16(Bp_h + b1 + k0, lBh1);
        gload_lds16(Bp_l + b0 + k0, lBl0);
        gload_lds16(Bp_l + b1 + k0, lBl1);
        __syncthreads();
        bf16x8 aH[4], aL[4], bH[4], bL[4];
        const int lo8 = lane * 8;
#pragma unroll
        for (int i = 0; i < 4; ++i) {
            aH[i] = *(const bf16x8*)(Ah + (wr * 4 + i) * 512 + lo8);
            aL[i] = *(const bf16x8*)(Al + (wr * 4 + i) * 512 + lo8);
            bH[i] = *(const bf16x8*)(Bh + (wc * 4 + i) * 512 + lo8);
            bL[i] = *(const bf16x8*)(Bl + (wc * 4 + i) * 512 + lo8);
        }
#pragma unroll
        for (int mi = 0; mi < 4; ++mi)
#pragma unroll
            for (int ni = 0; ni < 4; ++ni) {
                acc[mi][ni] = __builtin_amdgcn_mfma_f32_16x16x32_bf16(aH[mi], bH[ni], acc[mi][ni], 0, 0, 0);
                acc[mi][ni] = __builtin_amdgcn_mfma_f32_16x16x32_bf16(aH[mi], bL[ni], acc[mi][ni], 0, 0, 0);
                acc[mi][ni] = __builtin_amdgcn_mfma_f32_16x16x32_bf16(aL[mi], bH[ni], acc[mi][ni], 0, 0, 0);
            }
        __syncthreads();
    }

    // ---------------- fused epilogue ----------------
    const float* bias = which == 0 ? bq : (which == 1 ? bk : bv);
    const int h = ct * 2 + wc;
    const int rbase = row0 + wr * 64 + ((lane >> 4) << 2);
    const float c  = softplus_f(curv_raw[0]);
    const float sc = sqrtf(c);
    float bvv[4];
#pragma unroll
    for (int ni = 0; ni < 4; ++ni) bvv[ni] = bias[h * 64 + ni * 16 + lrow];

#pragma unroll
    for (int mi = 0; mi < 4; ++mi) {
        float v4[4][4];   // [ni][r]
#pragma unroll
        for (int ni = 0; ni < 4; ++ni) {
            f32x4 a = acc[mi][ni];
#pragma unroll
            for (int r = 0; r < 4; ++r) v4[ni][r] = a[r] + bvv[ni];
        }
        // per-row sumsq: bitwise == wred_sum64
        float f_[4], n2o_[4];
#pragma unroll
        for (int r = 0; r < 4; ++r) {
            float p[4];
#pragma unroll
            for (int ni = 0; ni < 4; ++ni) {
                float s = v4[ni][r] * v4[ni][r];
#pragma unroll
                for (int m = 1; m < 16; m <<= 1) s += __shfl_xor(s, m, 64);
                p[ni] = s;
            }
            float n2 = (p[0] + p[1]) + (p[2] + p[3]);
            f_[r] = expmap0_factor(n2, sc, &n2o_[r]);
        }
        const int row0g = rbase + mi * 16;          // 4 consecutive rows, same batch
        const int bb = row0g / 576;
        const int nn0 = row0g - bb * 576;
        const size_t gbase = ((size_t)(bb * 12 + h)) * 576 + nn0;
        if (which == 2) {
            float gmm[4];
#pragma unroll
            for (int r = 0; r < 4; ++r) gmm[r] = 2.f / fmaxf(1.f - c * n2o_[r], 1e-15f);
            if (lrow == 0) {
#pragma unroll
                for (int r = 0; r < 4; ++r) gm1[gbase + r] = gmm[r] - 1.f;
            }
#pragma unroll
            for (int ni = 0; ni < 4; ++ni) {
                const int hd = ni * 16 + lrow;
                u16x4 hs, ls;
#pragma unroll
                for (int r = 0; r < 4; ++r) {
                    float gv = v4[ni][r] * f_[r] * gmm[r];
                    u16 hb = bf16_rne(gv);
                    hs[r] = hb;
                    ls[r] = bf16_rne(gv - bf16_tof(hb));
                }
                const size_t dst = (((size_t)(bb * 12 + h)) * 64 + hd) * 576 + nn0;
                *(u16x4*)(gV0 + dst) = hs;
                *(u16x4*)(gV1 + dst) = ls;
            }
        } else {
            float* scal = which == 0 ? x2q : y2g;
            if (lrow == 0) {
#pragma unroll
                for (int r = 0; r < 4; ++r) scal[gbase + r] = n2o_[r];
                if (which == 1) {
#pragma unroll
                    for (int r = 0; r < 4; ++r)
                        rbj[gbase + r] = 1.f / fmaf(-c, n2o_[r], 1.f);
                }
            }
            u16* P0 = which == 0 ? Qb0 : Kb0;
            u16* P1 = which == 0 ? Qb1 : Kb1;
            u16* P2 = which == 0 ? Qb2 : Kb2;
#pragma unroll
            for (int ni = 0; ni < 4; ++ni) {
                const int hd = ni * 16 + lrow;
#pragma unroll
                for (int r = 0; r < 4; ++r) {
                    float y = v4[ni][r] * f_[r];
                    u16 hb = bf16_rne(y);
                    float r1 = y - bf16_tof(hb);
                    u16 mb = bf16_rne(r1);
                    u16 lb = bf16_rne(r1 - bf16_tof(mb));
                    const size_t off = (gbase + r) * 64 + hd;
                    P0[off] = hb; P1[off] = mb; P2[off] = lb;
                }
            }
        }
    }
}

// ---------------- kernel 5: output projection (split-bf16 MFMA, XCD-banded) ----------------
__global__ __launch_bounds__(256) void gemm_o_mfma(
    const u16* __restrict__ Oh, const u16* __restrict__ Ol,
    const u16* __restrict__ Wh, const u16* __restrict__ Wl,
    const float* __restrict__ bo, float* __restrict__ out)
{
    __shared__ u16 Ah[4096], Al[4096], Bh[4096], Bl[4096];
    const int tid = threadIdx.x;
    const int w = tid >> 6, lane = tid & 63;
    const int wr = w >> 1, wc = w & 1;
    const int lrow = lane & 15, lk8 = (lane >> 4) << 3;
    // 432 blocks = 8 XCDs x (9 mt x 6 ct)
    const int bid = blockIdx.x;
    const int xcd = bid & 7, ser = bid >> 3;       // ser < 54
    const int mt = xcd * 9 + (ser % 9);
    const int ct = ser / 9;                        // < 6
    const int row0 = mt * 128, col0 = ct * 128;

    const size_t a0 = (size_t)(row0 + (2 * w + 0) * 16 + lrow) * 768 + lk8;
    const size_t a1 = a0 + 16 * 768;
    const size_t b0 = (size_t)(col0 + (2 * w + 0) * 16 + lrow) * 768 + lk8;
    const size_t b1 = b0 + 16 * 768;
    u16* lAh0 = Ah + (2 * w) * 512; u16* lAh1 = lAh0 + 512;
    u16* lAl0 = Al + (2 * w) * 512; u16* lAl1 = lAl0 + 512;
    u16* lBh0 = Bh + (2 * w) * 512; u16* lBh1 = lBh0 + 512;
    u16* lBl0 = Bl + (2 * w) * 512; u16* lBl1 = lBl0 + 512;

    f32x4 acc[4][4];
#pragma unroll
    for (int i = 0; i < 4; ++i)
#pragma unroll
        for (int j = 0; j < 4; ++j) acc[i][j] = (f32x4){0.f, 0.f, 0.f, 0.f};

    for (int k0 = 0; k0 < 768; k0 += 32) {
        gload_lds16(Oh + a0 + k0, lAh0);
        gload_lds16(Oh + a1 + k0, lAh1);
        gload_lds16(Ol + a0 + k0, lAl0);
        gload_lds16(Ol + a1 + k0, lAl1);
        gload_lds16(Wh + b0 + k0, lBh0);
        gload_lds16(Wh + b1 + k0, lBh1);
        gload_lds16(Wl + b0 + k0, lBl0);
        gload_lds16(Wl + b1 + k0, lBl1);
        __syncthreads();
        bf16x8 aH[4], aL[4], bH[4], bL[4];
        const int lo8 = lane * 8;
#pragma unroll
        for (int i = 0; i < 4; ++i) {
            aH[i] = *(const bf16x8*)(Ah + (wr * 4 + i) * 512 + lo8);
            aL[i] = *(const bf16x8*)(Al + (wr * 4 + i) * 512 + lo8);
            bH[i] = *(const bf16x8*)(Bh + (wc * 4 + i) * 512 + lo8);
            bL[i] = *(const bf16x8*)(Bl + (wc * 4 + i) * 512 + lo8);
        }
#pragma unroll
        for (int mi = 0; mi < 4; ++mi)
#pragma unroll
            for (int ni = 0; ni < 4; ++ni) {
                acc[mi][ni] = __builtin_amdgcn_mfma_f32_16x16x32_bf16(aH[mi], bH[ni], acc[mi][ni], 0, 0, 0);
                acc[mi][ni] = __builtin_amdgcn_mfma_f32_16x16x32_bf16(aH[mi], bL[ni], acc[mi][ni], 0, 0, 0);
                acc[mi][ni] = __builtin_amdgcn_mfma_f32_16x16x32_bf16(aL[mi], bH[ni], acc[mi][ni], 0, 0, 0);
            }
        __syncthreads();
    }

    const int rbase = row0 + wr * 64 + ((lane >> 4) << 2);
#pragma unroll
    for (int ni = 0; ni < 4; ++ni) {
        const int colg = col0 + wc * 64 + ni * 16 + lrow;
        const float bv_ = bo[colg];
#pragma unroll
        for (int mi = 0; mi < 4; ++mi) {
            f32x4 a = acc[mi][ni];
#pragma unroll
            for (int r = 0; r < 4; ++r) {
                int row = rbase + mi * 16 + r;
                out[(size_t)row * 768 + colg] = a[r] + bv_;
            }
        }
    }
}

// ---------------- kernel 2: per-head centroid maps (once, shared across batch) ----------------
__global__ __launch_bounds__(256) void cent_kernel(
    const float* __restrict__ cent,
    u16* __restrict__ Kc0, u16* __restrict__ Kc1, u16* __restrict__ Kc2,
    u16* __restrict__ gVc0, u16* __restrict__ gVc1,
    float* __restrict__ y2c, float* __restrict__ gm1c, float* __restrict__ rbc,
    const float* __restrict__ curv_raw)
{
    __shared__ float gvt_s[64][65];
    const float c  = softplus_f(curv_raw[0]);
    const float sc = sqrtf(c);
    const int t = blockIdx.x;         // < 24
    const int h = t >> 1, ct = t & 1;
    const int w = threadIdx.x >> 6, lane = threadIdx.x & 63;
#pragma unroll 4
    for (int i = 0; i < 16; ++i) {
        const int m = ct * 64 + w * 16 + i;
        const size_t g = (size_t)h * 128 + m;
        float cv = cent[g * 64 + lane];
        float n2 = wred_sum64(cv * cv);
        float n2o;
        float f = expmap0_factor(n2, sc, &n2o);
        float ky = cv * f;
        u16 kh = bf16_rne(ky);
        float r1 = ky - bf16_tof(kh);
        u16 km = bf16_rne(r1);
        u16 kl = bf16_rne(r1 - bf16_tof(km));
        Kc0[g * 64 + lane] = kh; Kc1[g * 64 + lane] = km; Kc2[g * 64 + lane] = kl;
        float gmm = 2.f / fmaxf(1.f - c * n2o, 1e-15f);
        gvt_s[lane][w * 16 + i] = ky * gmm;
        if (lane == 0) {
            y2c[g] = n2o; gm1c[g] = gmm - 1.f;
            rbc[g] = 1.f / fmaf(-c, n2o, 1.f);
        }
    }
    __syncthreads();
    const int hd = threadIdx.x >> 2, j0 = (threadIdx.x & 3) * 16;
    u16 hb[16], lb[16];
#pragma unroll
    for (int e = 0; e < 16; ++e) {
        float v = gvt_s[hd][j0 + e];
        hb[e] = bf16_rne(v);
        lb[e] = bf16_rne(v - bf16_tof(hb[e]));
    }
    const size_t dst = ((size_t)h * 64 + hd) * 128 + ct * 64 + j0;
    *(u16x8*)(gVc0 + dst)     = *(u16x8*)&hb[0];
    *(u16x8*)(gVc0 + dst + 8) = *(u16x8*)&hb[8];
    *(u16x8*)(gVc1 + dst)     = *(u16x8*)&lb[0];
    *(u16x8*)(gVc1 + dst + 8) = *(u16x8*)&lb[8];
}

// ---------------- kernel 4: fused hyperbolic attention (MFMA, LDS-staged K/V) ----------------
// Logit via the arcosh form of the Poincare distance (exactly 2*artanh(arg)):
// z = 1 + 2c*||x-y||^2 * ra * rb, t = arcosh(z)/2; W = exp2(c2h*lg^2),
// lg = log2(z + sqrt(z^2-1)). ra/rb precomputed; 3 transcendentals per logit.
__global__ __launch_bounds__(256) void attn_kernel(
    const u16* __restrict__ Qb0, const u16* __restrict__ Qb1, const u16* __restrict__ Qb2,
    const u16* __restrict__ Kb0, const u16* __restrict__ Kb1, const u16* __restrict__ Kb2,
    const u16* __restrict__ Kc0, const u16* __restrict__ Kc1, const u16* __restrict__ Kc2,
    const u16* __restrict__ gV0, const u16* __restrict__ gV1,
    const u16* __restrict__ gVc0, const u16* __restrict__ gVc1,
    const float* __restrict__ x2q, const float* __restrict__ y2g, const float* __restrict__ gm1,
    const float* __restrict__ y2c, const float* __restrict__ gm1c,
    const float* __restrict__ rbj, const float* __restrict__ rbc,
    const float* __restrict__ sigma_raw, const float* __restrict__ curv_raw,
    u16* __restrict__ Oh, u16* __restrict__ Ol)
{
    __shared__ __align__(16) u16 Kst[2][3][4096];  // [buf][plane][row*64 + swizzled col]
    __shared__ __align__(16) u16 Vst[2][4096];     // [plane][row*64 + swizzled col]
    __shared__ __align__(16) u16 wb_hi[4][1024];
    __shared__ __align__(16) u16 wb_lo[4][1024];

    const int blk = blockIdx.x;
    const int xcd = blk & 7;
    const int serial = blk >> 3;
    const int bhg = serial / 9;
    const int qt = serial - bhg * 9;
    const int bh = bhg * 8 + xcd;
    const int b = bh / 12, h = bh % 12;
    const float c  = softplus_f(curv_raw[0]);
    const float sc = sqrtf(c);
    const float sig = softplus_f(sigma_raw[h]) + 1e-6f;
    const float coef = -2.f / (c * sig * sig);   // logit = coef * artanh(arg)^2
    const float c2h  = coef * 0.25f * 0.6931471805599453f;  // exp2 basis

    const int tid = threadIdx.x;
    const int w = tid >> 6, lane = tid & 63;
    const int lr = lane & 15, lg = lane >> 4, lo8 = lg * 8;
    const int swl = (lr & 7) << 3;

    const size_t qbase = (size_t)bh * 576 + qt * 64;

    int srow[2], scol[2];
#pragma unroll
    for (int rr = 0; rr < 2; ++rr) {
        int cch = (rr * 4 + w) * 64 + lane;
        srow[rr] = cch >> 3;
        scol[rr] = ((cch & 7) ^ (srow[rr] & 7)) << 3;
    }
    const size_t kb_base = (size_t)bh * 576 * 64;
    const size_t kc_base = (size_t)h * 128 * 64;
    const size_t vb_base = (size_t)bh * 64 * 576;
    const size_t vc_base = (size_t)h * 64 * 128;

    auto stageK = [&](int t, int buf) {
        if (t < 9) {
            const size_t rb = kb_base + (size_t)t * 64 * 64;
#pragma unroll
            for (int rr = 0; rr < 2; ++rr) {
                const size_t so = rb + (size_t)srow[rr] * 64 + scol[rr];
                gload_lds16(Kb0 + so, &Kst[buf][0][(rr * 4 + w) * 512]);
                gload_lds16(Kb1 + so, &Kst[buf][1][(rr * 4 + w) * 512]);
                gload_lds16(Kb2 + so, &Kst[buf][2][(rr * 4 + w) * 512]);
            }
        } else {
            const size_t rb = kc_base + (size_t)(t - 9) * 64 * 64;
#pragma unroll
            for (int rr = 0; rr < 2; ++rr) {
                const size_t so = rb + (size_t)srow[rr] * 64 + scol[rr];
                gload_lds16(Kc0 + so, &Kst[buf][0][(rr * 4 + w) * 512]);
                gload_lds16(Kc1 + so, &Kst[buf][1][(rr * 4 + w) * 512]);
                gload_lds16(Kc2 + so, &Kst[buf][2][(rr * 4 + w) * 512]);
            }
        }
    };
    auto stageV = [&](int t) {
        if (t < 9) {
            const size_t rb = vb_base + (size_t)t * 64;
#pragma unroll
            for (int rr = 0; rr < 2; ++rr) {
                const size_t so = rb + (size_t)srow[rr] * 576 + scol[rr];
                gload_lds16(gV0 + so, &Vst[0][(rr * 4 + w) * 512]);
                gload_lds16(gV1 + so, &Vst[1][(rr * 4 + w) * 512]);
            }
        } else {
            const size_t rb = vc_base + (size_t)(t - 9) * 64;
#pragma unroll
            for (int rr = 0; rr < 2; ++rr) {
                const size_t so = rb + (size_t)srow[rr] * 128 + scol[rr];
                gload_lds16(gVc0 + so, &Vst[0][(rr * 4 + w) * 512]);
                gload_lds16(gVc1 + so, &Vst[1][(rr * 4 + w) * 512]);
            }
        }
    };

    bf16x8 aQh[2], aQm[2], aQl[2];
    {
        const size_t qrow = (qbase + w * 16 + lr) * 64;
#pragma unroll
        for (int kt = 0; kt < 2; ++kt) {
            const size_t o = qrow + kt * 32 + lo8;
            aQh[kt] = *(const bf16x8*)(Qb0 + o);
            aQm[kt] = *(const bf16x8*)(Qb1 + o);
            aQl[kt] = *(const bf16x8*)(Qb2 + o);
        }
    }
    float x2r[4], Pr[4];
#pragma unroll
    for (int r = 0; r < 4; ++r) {
        float x2 = x2q[qbase + w * 16 + lg * 4 + r];
        x2r[r] = x2;
        Pr[r] = (c + c) / fmaf(-c, x2, 1.f);    // 2c * ra, ra = 1/(1-c*x2)
    }

    f32x4 pv[4];
#pragma unroll
    for (int i = 0; i < 4; ++i) pv[i] = (f32x4){0.f, 0.f, 0.f, 0.f};
    float den[4] = {0.f, 0.f, 0.f, 0.f};

    u16* wbh = &wb_hi[w][0];
    u16* wbl = &wb_lo[w][0];

    stageK(0, 0);
    __syncthreads();

    int cur = 0;
    for (int jt = 0; jt < 11; ++jt) {
        const int jb = jt * 64;

        if (jt < 10) stageK(jt + 1, cur ^ 1);
        stageV(jt);

        const float* y2p;
        const float* gm1p;
        const float* rbp;
        if (jt < 9) {
            y2p = y2g + (size_t)bh * 576 + jb;  gm1p = gm1 + (size_t)bh * 576 + jb;
            rbp = rbj + (size_t)bh * 576 + jb;
        } else {
            y2p = y2c + (size_t)h * 128 + (jb - 576); gm1p = gm1c + (size_t)h * 128 + (jb - 576);
            rbp = rbc + (size_t)h * 128 + (jb - 576);
        }

        const u16* kp0 = &Kst[cur][0][0];
        const u16* kp1 = &Kst[cur][1][0];
        const u16* kp2 = &Kst[cur][2][0];
        f32x4 sf[4];
        float y2v[4], gm1v[4], rbv[4];
#pragma unroll
        for (int jf = 0; jf < 4; ++jf) {
            y2v[jf] = y2p[jf * 16 + lr];
            gm1v[jf] = gm1p[jf * 16 + lr];
            rbv[jf] = rbp[jf * 16 + lr];
            const int rb = (jf * 16 + lr) * 64;
            f32x4 s = (f32x4){0.f, 0.f, 0.f, 0.f};
#pragma unroll
            for (int kt = 0; kt < 2; ++kt) {
                const int o = rb + ((kt * 32 + lo8) ^ swl);
                bf16x8 kh = *(const bf16x8*)(kp0 + o);
                bf16x8 km = *(const bf16x8*)(kp1 + o);
                bf16x8 kl = *(const bf16x8*)(kp2 + o);
                s = __builtin_amdgcn_mfma_f32_16x16x32_bf16(aQh[kt], kh, s, 0, 0, 0);
                s = __builtin_amdgcn_mfma_f32_16x16x32_bf16(aQh[kt], km, s, 0, 0, 0);
                s = __builtin_amdgcn_mfma_f32_16x16x32_bf16(aQm[kt], kh, s, 0, 0, 0);
                s = __builtin_amdgcn_mfma_f32_16x16x32_bf16(aQm[kt], km, s, 0, 0, 0);
                s = __builtin_amdgcn_mfma_f32_16x16x32_bf16(aQh[kt], kl, s, 0, 0, 0);
                s = __builtin_amdgcn_mfma_f32_16x16x32_bf16(aQl[kt], kh, s, 0, 0, 0);
            }
            sf[jf] = s;
        }

        // ---- xy -> W via arcosh form (division-free, 3 transcendentals)
#pragma unroll
        for (int jf = 0; jf < 4; ++jf) {
            const float y2 = y2v[jf];
            const float rb_ = rbv[jf];
#pragma unroll
            for (int r = 0; r < 4; ++r) {
                float xy = sf[jf][r];
                float sxy = x2r[r] + y2;
                float u = fmaf(-2.f, xy, sxy);           // ||x-y||^2
                float krr = Pr[r] * rb_;                 // 2c*ra*rb
                float z = fmaxf(fmaf(krr, u, 1.f), 1.f);
                float zm = fmaxf(fmaf(z, z, -1.f), 0.f);
                float lg = __builtin_amdgcn_logf(z + __builtin_amdgcn_sqrtf(zm));
                float wv_ = __builtin_amdgcn_exp2f(c2h * (lg * lg));
                sf[jf][r] = wv_;
                den[r] = fmaf(wv_, gm1v[jf], den[r]);
            }
        }

#pragma unroll
        for (int r = 0; r < 4; ++r) {
            const int row = lg * 4 + r;
            const int sw = (row & 7) << 3;
#pragma unroll
            for (int jf = 0; jf < 4; ++jf) {
                const int colu = (jf * 16 + lr) ^ sw;
                float wv_ = sf[jf][r];
                u16 hb = bf16_rne(wv_);
                wbh[row * 64 + colu] = hb;
                wbl[row * 64 + colu] = bf16_rne(wv_ - bf16_tof(hb));
            }
        }

        __syncthreads();   // V staged (vmcnt drained); K prefetch also landed

        bf16x8 aWh[2], aWl[2];
#pragma unroll
        for (int kt = 0; kt < 2; ++kt) {
            const int colu = (kt * 32 + lo8) ^ swl;
            aWh[kt] = *(const bf16x8*)(wbh + lr * 64 + colu);
            aWl[kt] = *(const bf16x8*)(wbl + lr * 64 + colu);
        }

#pragma unroll
        for (int hf = 0; hf < 4; ++hf) {
            const int rb = (hf * 16 + lr) * 64;
#pragma unroll
            for (int kt = 0; kt < 2; ++kt) {
                const int o = rb + ((kt * 32 + lo8) ^ swl);
                bf16x8 vh = *(const bf16x8*)(&Vst[0][o]);
                bf16x8 vl = *(const bf16x8*)(&Vst[1][o]);
                pv[hf] = __builtin_amdgcn_mfma_f32_16x16x32_bf16(aWh[kt], vh, pv[hf], 0, 0, 0);
                pv[hf] = __builtin_amdgcn_mfma_f32_16x16x32_bf16(aWh[kt], vl, pv[hf], 0, 0, 0);
                pv[hf] = __builtin_amdgcn_mfma_f32_16x16x32_bf16(aWl[kt], vh, pv[hf], 0, 0, 0);
            }
        }

        __syncthreads();
        cur ^= 1;
    }

#pragma unroll
    for (int r = 0; r < 4; ++r) {
        float d = den[r];
#pragma unroll
        for (int msk = 1; msk < 16; msk <<= 1) d += __shfl_xor(d, msk, 64);
        float rd = 1.f / d;                      // den > 0 always (gamma-1 >= 1)
        float o_[4];
        float n2 = 0.f;
#pragma unroll
        for (int hf = 0; hf < 4; ++hf) { o_[hf] = pv[hf][r] * rd; n2 = fmaf(o_[hf], o_[hf], n2); }
#pragma unroll
        for (int msk = 1; msk < 16; msk <<= 1) n2 += __shfl_xor(n2, msk, 64);
        float nrm = sqrtf(fmaxf(n2, 1e-15f));
        float arg = fminf(sc * nrm, 1.f - 1e-7f);
        float t = artanh_fast(arg);
        float f = 0.5f * t / (sc * nrm);
        const int nrow = qt * 64 + w * 16 + lg * 4 + r;
        const size_t dst = ((size_t)(b * 576 + nrow)) * 768 + h * 64;
#pragma unroll
        for (int hf = 0; hf < 4; ++hf) {
            float val = o_[hf] * f;
            u16 hb = bf16_rne(val);
            Oh[dst + hf * 16 + lr] = hb;
            Ol[dst + hf * 16 + lr] = bf16_rne(val - bf16_tof(hb));
        }
    }
}

// ---------------- launcher ----------------
extern "C" void kernel_launch(void* const* d_in, const int* in_sizes, int n_in,
                              void* d_out, int out_size, void* d_ws, size_t ws_size,
                              hipStream_t stream) {
    (void)in_sizes; (void)n_in; (void)out_size; (void)ws_size;
    const float* x    = (const float*)d_in[0];
    const float* Wq   = (const float*)d_in[1];
    const float* bq   = (const float*)d_in[2];
    const float* Wk   = (const float*)d_in[3];
    const float* bk   = (const float*)d_in[4];
    const float* Wv   = (const float*)d_in[5];
    const float* bv   = (const float*)d_in[6];
    const float* Wo   = (const float*)d_in[7];
    const float* bo   = (const float*)d_in[8];
    const float* cent = (const float*)d_in[9];
    const float* curv = (const float*)d_in[10];
    const float* sigr = (const float*)d_in[11];
    float* out = (float*)d_out;

    const size_t QH  = (size_t)B_ * H_ * N_ * 64;   // 7,077,888 (also K/V token size)
    const size_t CK  = (size_t)H_ * M_ * 64;        // 98,304 centroid-plane size
    const size_t WSZ = (size_t)D_ * D_;             // 589,824

    float* fp = (float*)d_ws;
    float* x2q  = fp;            fp += (size_t)B_ * H_ * N_;
    float* y2g  = fp;            fp += (size_t)B_ * H_ * N_;
    float* gm1  = fp;            fp += (size_t)B_ * H_ * N_;
    float* rbjv = fp;            fp += (size_t)B_ * H_ * N_;
    float* y2c  = fp;            fp += (size_t)H_ * M_;
    float* gm1c = fp;            fp += (size_t)H_ * M_;
    float* rbcv = fp;            fp += (size_t)H_ * M_;
    u16* up = (u16*)fp;
    u16* xh  = up;  up += QH;     // aliased with Oh (xh dead before attn writes Oh)
    u16* xl  = up;  up += QH;     // aliased with Ol
    u16* Oh  = xh;
    u16* Ol  = xl;
    u16* Wqh = up;  up += WSZ;
    u16* Wql = up;  up += WSZ;
    u16* Wkh = up;  up += WSZ;
    u16* Wkl = up;  up += WSZ;
    u16* Wvh = up;  up += WSZ;
    u16* Wvl = up;  up += WSZ;
    u16* Woh = up;  up += WSZ;
    u16* Wol = up;  up += WSZ;
    u16* Qb  = up;  up += 3 * QH;
    u16* Kb  = up;  up += 3 * QH;
    u16* gV  = up;  up += 2 * QH;
    u16* Kc  = up;  up += 3 * CK;
    u16* gVc = up;  up += 2 * CK;

    u16* Qb0 = Qb;           u16* Qb1 = Qb + QH;   u16* Qb2 = Qb + 2 * QH;
    u16* Kb0 = Kb;           u16* Kb1 = Kb + QH;   u16* Kb2 = Kb + 2 * QH;
    u16* gV0 = gV;           u16* gV1 = gV + QH;
    u16* Kc0 = Kc;           u16* Kc1 = Kc + CK;   u16* Kc2 = Kc + 2 * CK;
    u16* gVc0 = gVc;         u16* gVc1 = gVc + CK;

    // 0: hi/lo splits (x + all 4 weights)
    split_bf16_kernel<<<(int)(QH / 4 / 256), 256, 0, stream>>>(x, xh, xl, (int)(QH / 4));
    split_w4_kernel<<<dim3((int)(WSZ / 4 / 256), 4), 256, 0, stream>>>(
        Wq, Wk, Wv, Wo, Wqh, Wql, Wkh, Wkl, Wvh, Wvl, Woh, Wol);

    // 2: per-head centroid maps (independent of GEMM)
    cent_kernel<<<24, 256, 0, stream>>>(cent, Kc0, Kc1, Kc2, gVc0, gVc1, y2c, gm1c, rbcv, curv);

    // 1: QKV projections + fused hyperbolic maps (MFMA, XCD-banded)
    gemm_qkv_mfma<<<1296, 256, 0, stream>>>(xh, xl, Wqh, Wql, Wkh, Wkl, Wvh, Wvl,
                                            bq, bk, bv,
                                            Qb0, Qb1, Qb2, Kb0, Kb1, Kb2, gV0, gV1,
                                            x2q, y2g, gm1, rbjv, curv);
    // 4: fused attention (MFMA, LDS-staged, XCD-affine, arcosh logit)
    attn_kernel<<<1728, 256, 0, stream>>>(Qb0, Qb1, Qb2, Kb0, Kb1, Kb2, Kc0, Kc1, Kc2,
                                          gV0, gV1, gVc0, gVc1,
                                          x2q, y2g, gm1, y2c, gm1c, rbjv, rbcv,
                                          sigr, curv, Oh, Ol);
    // 5: output projection (MFMA, XCD-banded)
    gemm_o_mfma<<<432, 256, 0, stream>>>(Oh, Ol, Woh, Wol, bo, out);
}

// Round 11
// 370.509 us; speedup vs baseline: 3.6045x; 1.0583x over previous
//
#include <hip/hip_runtime.h>
#include <cstdint>
#include <cstddef>

#define B_  16
#define N_  576
#define D_  768
#define H_  12
#define HD_ 64
#define M_  128
#define J_  704   // N_ + M_

typedef unsigned short u16;
typedef __attribute__((ext_vector_type(8))) short bf16x8;
typedef __attribute__((ext_vector_type(4))) float f32x4;
typedef __attribute__((ext_vector_type(4))) unsigned short u16x4;
typedef __attribute__((ext_vector_type(8))) unsigned short u16x8;

// ---------------- helpers ----------------

__device__ __forceinline__ float softplus_f(float x) {
    return (x > 20.f) ? x : log1pf(expf(x));
}

__device__ __forceinline__ float wred_sum64(float v) {
#pragma unroll
    for (int m = 1; m < 64; m <<= 1) v += __shfl_xor(v, m, 64);
    return v;
}

__device__ __forceinline__ u16 bf16_rne(float f) {
    unsigned int u = __float_as_uint(f);
    unsigned int r = u + 0x7FFFu + ((u >> 16) & 1u);
    return (u16)(r >> 16);
}
__device__ __forceinline__ float bf16_tof(u16 h) {
    return __uint_as_float(((unsigned int)h) << 16);
}

// expmap0 total multiplier (division- and tanhf-free: v_rcp/v_exp).
// Valid for a = sc*n1 in (0, 6.11]; real row norms here are in [~0.1, 6.1].
__device__ __forceinline__ float expmap0_factor(float n2, float sc, float* n2out) {
    const float ATANH_1M1E5 = 6.1030335f;     // artanh(1 - 1e-5)
    const float LOG2E2 = 2.8853900817779268f; // 2*log2(e)
    float rsc = __builtin_amdgcn_rcpf(sc);
    float n0 = __builtin_amdgcn_sqrtf(fmaxf(n2, 1e-15f));
    float f1 = fminf(1.f, (ATANH_1M1E5 * rsc) * __builtin_amdgcn_rcpf(n0));  // pre-clip
    float n1 = n0 * f1;
    float a  = sc * n1;
    float e2a = __builtin_amdgcn_exp2f(a * LOG2E2);
    float th  = 1.f - 2.f * __builtin_amdgcn_rcpf(e2a + 1.f);   // tanh(a), a not tiny
    float yfac  = th * __builtin_amdgcn_rcpf(a);
    float f2 = fminf(1.f, 0.99999f * __builtin_amdgcn_rcpf(th)); // post-clip
    float fn = (th * rsc) * f2;
    *n2out = fn * fn;
    return f1 * yfac * f2;
}

__device__ __forceinline__ float artanh_fast(float z) {  // z in [0, 1-1e-7]
    return 0.5f * __logf((1.f + z) / (1.f - z));
}

// global -> LDS direct copy, 16B per lane (wave-uniform LDS base + lane*16)
typedef const __attribute__((address_space(1))) unsigned int* gas_u32;
typedef __attribute__((address_space(3))) unsigned int* las_u32;
__device__ __forceinline__ void gload_lds16(const u16* g, u16* l) {
    __builtin_amdgcn_global_load_lds((gas_u32)(const void*)g, (las_u32)(void*)l, 16, 0, 0);
}

// ---------------- kernel 0a: f32 -> bf16 hi/lo split (x) ----------------
__global__ __launch_bounds__(256) void split_bf16_kernel(
    const float* __restrict__ src, u16* __restrict__ hi, u16* __restrict__ lo, int n4)
{
    int i = blockIdx.x * 256 + threadIdx.x;
    if (i >= n4) return;
    float4 v = ((const float4*)src)[i];
    u16x4 h, l;
    h[0] = bf16_rne(v.x); l[0] = bf16_rne(v.x - bf16_tof(h[0]));
    h[1] = bf16_rne(v.y); l[1] = bf16_rne(v.y - bf16_tof(h[1]));
    h[2] = bf16_rne(v.z); l[2] = bf16_rne(v.z - bf16_tof(h[2]));
    h[3] = bf16_rne(v.w); l[3] = bf16_rne(v.w - bf16_tof(h[3]));
    ((u16x4*)hi)[i] = h;
    ((u16x4*)lo)[i] = l;
}

// ---------------- kernel 0b: split all 4 weight matrices in one launch ----------------
__global__ __launch_bounds__(256) void split_w4_kernel(
    const float* __restrict__ W0, const float* __restrict__ W1,
    const float* __restrict__ W2, const float* __restrict__ W3,
    u16* __restrict__ H0, u16* __restrict__ L0, u16* __restrict__ H1, u16* __restrict__ L1,
    u16* __restrict__ H2, u16* __restrict__ L2, u16* __restrict__ H3, u16* __restrict__ L3)
{
    int i = blockIdx.x * 256 + threadIdx.x;   // < WSZ/4 = 147456
    const int wsel = blockIdx.y;
    const float* src = wsel == 0 ? W0 : (wsel == 1 ? W1 : (wsel == 2 ? W2 : W3));
    u16* hi = wsel == 0 ? H0 : (wsel == 1 ? H1 : (wsel == 2 ? H2 : H3));
    u16* lo = wsel == 0 ? L0 : (wsel == 1 ? L1 : (wsel == 2 ? L2 : L3));
    float4 v = ((const float4*)src)[i];
    u16x4 h, l;
    h[0] = bf16_rne(v.x); l[0] = bf16_rne(v.x - bf16_tof(h[0]));
    h[1] = bf16_rne(v.y); l[1] = bf16_rne(v.y - bf16_tof(h[1]));
    h[2] = bf16_rne(v.z); l[2] = bf16_rne(v.z - bf16_tof(h[2]));
    h[3] = bf16_rne(v.w); l[3] = bf16_rne(v.w - bf16_tof(h[3]));
    ((u16x4*)hi)[i] = h;
    ((u16x4*)lo)[i] = l;
}

// ---------------- kernel 1: QKV projection + FUSED hyperbolic maps ----------------
// K-loop is single-buffer software-pipelined (T3-minimum): ds_read frags ->
// barrier -> STAGE(next) -> MFMA (staging latency hides under MFMA) -> barrier.
__global__ __launch_bounds__(256) void gemm_qkv_mfma(
    const u16* __restrict__ xh, const u16* __restrict__ xl,
    const u16* __restrict__ Wh0, const u16* __restrict__ Wl0,
    const u16* __restrict__ Wh1, const u16* __restrict__ Wl1,
    const u16* __restrict__ Wh2, const u16* __restrict__ Wl2,
    const float* __restrict__ bq, const float* __restrict__ bk, const float* __restrict__ bv,
    u16* __restrict__ Qb0, u16* __restrict__ Qb1, u16* __restrict__ Qb2,
    u16* __restrict__ Kb0, u16* __restrict__ Kb1, u16* __restrict__ Kb2,
    u16* __restrict__ gV0, u16* __restrict__ gV1,
    float* __restrict__ x2q, float* __restrict__ y2g, float* __restrict__ gm1,
    float* __restrict__ rbj,
    const float* __restrict__ curv_raw)
{
    __shared__ u16 Ah[4096], Al[4096], Bh[4096], Bl[4096];   // 8 frags x 512 each
    const int tid = threadIdx.x;
    const int w = tid >> 6, lane = tid & 63;
    const int wr = w >> 1, wc = w & 1;
    const int lrow = lane & 15, lk8 = (lane >> 4) << 3;
    // XCD-band swizzle: 1296 blocks = 8 XCDs x (9 mt x 18 yb)
    const int bid = blockIdx.x;
    const int xcd = bid & 7, ser = bid >> 3;       // ser < 162
    const int mt = xcd * 9 + (ser % 9);
    const int yb = ser / 9;                        // < 18
    const int which = yb / 6, ct = yb - which * 6;
    const u16* Bp_h = which == 0 ? Wh0 : (which == 1 ? Wh1 : Wh2);
    const u16* Bp_l = which == 0 ? Wl0 : (which == 1 ? Wl1 : Wl2);
    const int row0 = mt * 128, col0 = ct * 128;

    const size_t a0 = (size_t)(row0 + (2 * w + 0) * 16 + lrow) * 768 + lk8;
    const size_t a1 = a0 + 16 * 768;
    const size_t b0 = (size_t)(col0 + (2 * w + 0) * 16 + lrow) * 768 + lk8;
    const size_t b1 = b0 + 16 * 768;
    u16* lAh0 = Ah + (2 * w) * 512; u16* lAh1 = lAh0 + 512;
    u16* lAl0 = Al + (2 * w) * 512; u16* lAl1 = lAl0 + 512;
    u16* lBh0 = Bh + (2 * w) * 512; u16* lBh1 = lBh0 + 512;
    u16* lBl0 = Bl + (2 * w) * 512; u16* lBl1 = lBl0 + 512;

    auto STAGE = [&](int k0) {
        gload_lds16(xh + a0 + k0, lAh0);
        gload_lds16(xh + a1 + k0, lAh1);
        gload_lds16(xl + a0 + k0, lAl0);
        gload_lds16(xl + a1 + k0, lAl1);
        gload_lds16(Bp_h + b0 + k0, lBh0);
        gload_lds16(Bp_h + b1 + k0, lBh1);
        gload_lds16(Bp_l + b0 + k0, lBl0);
        gload_lds16(Bp_l + b1 + k0, lBl1);
    };

    f32x4 acc[4][4];
#pragma unroll
    for (int i = 0; i < 4; ++i)
#pragma unroll
        for (int j = 0; j < 4; ++j) acc[i][j] = (f32x4){0.f, 0.f, 0.f, 0.f};

    STAGE(0);
    __syncthreads();

    const int lo8 = lane * 8;
    for (int k0 = 0; k0 < 768; k0 += 32) {
        bf16x8 aH[4], aL[4], bH[4], bL[4];
#pragma unroll
        for (int i = 0; i < 4; ++i) {
            aH[i] = *(const bf16x8*)(Ah + (wr * 4 + i) * 512 + lo8);
            aL[i] = *(const bf16x8*)(Al + (wr * 4 + i) * 512 + lo8);
            bH[i] = *(const bf16x8*)(Bh + (wc * 4 + i) * 512 + lo8);
            bL[i] = *(const bf16x8*)(Bl + (wc * 4 + i) * 512 + lo8);
        }
        __syncthreads();                 // all waves done reading LDS
        if (k0 < 736) STAGE(k0 + 32);    // overwrite same buffer; hides under MFMA
#pragma unroll
        for (int mi = 0; mi < 4; ++mi)
#pragma unroll
            for (int ni = 0; ni < 4; ++ni) {
                acc[mi][ni] = __builtin_amdgcn_mfma_f32_16x16x32_bf16(aH[mi], bH[ni], acc[mi][ni], 0, 0, 0);
                acc[mi][ni] = __builtin_amdgcn_mfma_f32_16x16x32_bf16(aH[mi], bL[ni], acc[mi][ni], 0, 0, 0);
                acc[mi][ni] = __builtin_amdgcn_mfma_f32_16x16x32_bf16(aL[mi], bH[ni], acc[mi][ni], 0, 0, 0);
            }
        __syncthreads();                 // staging drained (vmcnt 0) before next reads
    }

    // ---------------- fused epilogue ----------------
    const float* bias = which == 0 ? bq : (which == 1 ? bk : bv);
    const int h = ct * 2 + wc;
    const int rbase = row0 + wr * 64 + ((lane >> 4) << 2);
    const float c  = softplus_f(curv_raw[0]);
    const float sc = sqrtf(c);
    float bvv[4];
#pragma unroll
    for (int ni = 0; ni < 4; ++ni) bvv[ni] = bias[h * 64 + ni * 16 + lrow];

#pragma unroll
    for (int mi = 0; mi < 4; ++mi) {
        float v4[4][4];   // [ni][r]
#pragma unroll
        for (int ni = 0; ni < 4; ++ni) {
            f32x4 a = acc[mi][ni];
#pragma unroll
            for (int r = 0; r < 4; ++r) v4[ni][r] = a[r] + bvv[ni];
        }
        // per-row sumsq: in-lane ni-sum first, then 4-step lrow butterfly
        float f_[4], n2o_[4];
#pragma unroll
        for (int r = 0; r < 4; ++r) {
            float s = v4[0][r] * v4[0][r];
#pragma unroll
            for (int ni = 1; ni < 4; ++ni) s = fmaf(v4[ni][r], v4[ni][r], s);
#pragma unroll
            for (int m = 1; m < 16; m <<= 1) s += __shfl_xor(s, m, 64);
            f_[r] = expmap0_factor(s, sc, &n2o_[r]);
        }
        const int row0g = rbase + mi * 16;          // 4 consecutive rows, same batch
        const int bb = row0g / 576;
        const int nn0 = row0g - bb * 576;
        const size_t gbase = ((size_t)(bb * 12 + h)) * 576 + nn0;
        if (which == 2) {
            float gmm[4];
#pragma unroll
            for (int r = 0; r < 4; ++r)
                gmm[r] = 2.f * __builtin_amdgcn_rcpf(fmaxf(1.f - c * n2o_[r], 1e-15f));
            if (lrow == 0) {
#pragma unroll
                for (int r = 0; r < 4; ++r) gm1[gbase + r] = gmm[r] - 1.f;
            }
#pragma unroll
            for (int ni = 0; ni < 4; ++ni) {
                const int hd = ni * 16 + lrow;
                u16x4 hs, ls;
#pragma unroll
                for (int r = 0; r < 4; ++r) {
                    float gv = v4[ni][r] * f_[r] * gmm[r];
                    u16 hb = bf16_rne(gv);
                    hs[r] = hb;
                    ls[r] = bf16_rne(gv - bf16_tof(hb));
                }
                const size_t dst = (((size_t)(bb * 12 + h)) * 64 + hd) * 576 + nn0;
                *(u16x4*)(gV0 + dst) = hs;
                *(u16x4*)(gV1 + dst) = ls;
            }
        } else {
            float* scal = which == 0 ? x2q : y2g;
            if (lrow == 0) {
#pragma unroll
                for (int r = 0; r < 4; ++r) scal[gbase + r] = n2o_[r];
                if (which == 1) {
#pragma unroll
                    for (int r = 0; r < 4; ++r)
                        rbj[gbase + r] = __builtin_amdgcn_rcpf(fmaf(-c, n2o_[r], 1.f));
                }
            }
            u16* P0 = which == 0 ? Qb0 : Kb0;
            u16* P1 = which == 0 ? Qb1 : Kb1;
            u16* P2 = which == 0 ? Qb2 : Kb2;
#pragma unroll
            for (int ni = 0; ni < 4; ++ni) {
                const int hd = ni * 16 + lrow;
#pragma unroll
                for (int r = 0; r < 4; ++r) {
                    float y = v4[ni][r] * f_[r];
                    u16 hb = bf16_rne(y);
                    float r1 = y - bf16_tof(hb);
                    u16 mb = bf16_rne(r1);
                    u16 lb = bf16_rne(r1 - bf16_tof(mb));
                    const size_t off = (gbase + r) * 64 + hd;
                    P0[off] = hb; P1[off] = mb; P2[off] = lb;
                }
            }
        }
    }
}

// ---------------- kernel 5: output projection (split-bf16 MFMA, pipelined) ----------------
__global__ __launch_bounds__(256) void gemm_o_mfma(
    const u16* __restrict__ Oh, const u16* __restrict__ Ol,
    const u16* __restrict__ Wh, const u16* __restrict__ Wl,
    const float* __restrict__ bo, float* __restrict__ out)
{
    __shared__ u16 Ah[4096], Al[4096], Bh[4096], Bl[4096];
    const int tid = threadIdx.x;
    const int w = tid >> 6, lane = tid & 63;
    const int wr = w >> 1, wc = w & 1;
    const int lrow = lane & 15, lk8 = (lane >> 4) << 3;
    // 432 blocks = 8 XCDs x (9 mt x 6 ct)
    const int bid = blockIdx.x;
    const int xcd = bid & 7, ser = bid >> 3;       // ser < 54
    const int mt = xcd * 9 + (ser % 9);
    const int ct = ser / 9;                        // < 6
    const int row0 = mt * 128, col0 = ct * 128;

    const size_t a0 = (size_t)(row0 + (2 * w + 0) * 16 + lrow) * 768 + lk8;
    const size_t a1 = a0 + 16 * 768;
    const size_t b0 = (size_t)(col0 + (2 * w + 0) * 16 + lrow) * 768 + lk8;
    const size_t b1 = b0 + 16 * 768;
    u16* lAh0 = Ah + (2 * w) * 512; u16* lAh1 = lAh0 + 512;
    u16* lAl0 = Al + (2 * w) * 512; u16* lAl1 = lAl0 + 512;
    u16* lBh0 = Bh + (2 * w) * 512; u16* lBh1 = lBh0 + 512;
    u16* lBl0 = Bl + (2 * w) * 512; u16* lBl1 = lBl0 + 512;

    auto STAGE = [&](int k0) {
        gload_lds16(Oh + a0 + k0, lAh0);
        gload_lds16(Oh + a1 + k0, lAh1);
        gload_lds16(Ol + a0 + k0, lAl0);
        gload_lds16(Ol + a1 + k0, lAl1);
        gload_lds16(Wh + b0 + k0, lBh0);
        gload_lds16(Wh + b1 + k0, lBh1);
        gload_lds16(Wl + b0 + k0, lBl0);
        gload_lds16(Wl + b1 + k0, lBl1);
    };

    f32x4 acc[4][4];
#pragma unroll
    for (int i = 0; i < 4; ++i)
#pragma unroll
        for (int j = 0; j < 4; ++j) acc[i][j] = (f32x4){0.f, 0.f, 0.f, 0.f};

    STAGE(0);
    __syncthreads();

    const int lo8 = lane * 8;
    for (int k0 = 0; k0 < 768; k0 += 32) {
        bf16x8 aH[4], aL[4], bH[4], bL[4];
#pragma unroll
        for (int i = 0; i < 4; ++i) {
            aH[i] = *(const bf16x8*)(Ah + (wr * 4 + i) * 512 + lo8);
            aL[i] = *(const bf16x8*)(Al + (wr * 4 + i) * 512 + lo8);
            bH[i] = *(const bf16x8*)(Bh + (wc * 4 + i) * 512 + lo8);
            bL[i] = *(const bf16x8*)(Bl + (wc * 4 + i) * 512 + lo8);
        }
        __syncthreads();
        if (k0 < 736) STAGE(k0 + 32);
#pragma unroll
        for (int mi = 0; mi < 4; ++mi)
#pragma unroll
            for (int ni = 0; ni < 4; ++ni) {
                acc[mi][ni] = __builtin_amdgcn_mfma_f32_16x16x32_bf16(aH[mi], bH[ni], acc[mi][ni], 0, 0, 0);
                acc[mi][ni] = __builtin_amdgcn_mfma_f32_16x16x32_bf16(aH[mi], bL[ni], acc[mi][ni], 0, 0, 0);
                acc[mi][ni] = __builtin_amdgcn_mfma_f32_16x16x32_bf16(aL[mi], bH[ni], acc[mi][ni], 0, 0, 0);
            }
        __syncthreads();
    }

    const int rbase = row0 + wr * 64 + ((lane >> 4) << 2);
#pragma unroll
    for (int ni = 0; ni < 4; ++ni) {
        const int colg = col0 + wc * 64 + ni * 16 + lrow;
        const float bv_ = bo[colg];
#pragma unroll
        for (int mi = 0; mi < 4; ++mi) {
            f32x4 a = acc[mi][ni];
#pragma unroll
            for (int r = 0; r < 4; ++r) {
                int row = rbase + mi * 16 + r;
                out[(size_t)row * 768 + colg] = a[r] + bv_;
            }
        }
    }
}

// ---------------- kernel 2: per-head centroid maps (once, shared across batch) ----------------
__global__ __launch_bounds__(256) void cent_kernel(
    const float* __restrict__ cent,
    u16* __restrict__ Kc0, u16* __restrict__ Kc1, u16* __restrict__ Kc2,
    u16* __restrict__ gVc0, u16* __restrict__ gVc1,
    float* __restrict__ y2c, float* __restrict__ gm1c, float* __restrict__ rbc,
    const float* __restrict__ curv_raw)
{
    __shared__ float gvt_s[64][65];
    const float c  = softplus_f(curv_raw[0]);
    const float sc = sqrtf(c);
    const int t = blockIdx.x;         // < 24
    const int h = t >> 1, ct = t & 1;
    const int w = threadIdx.x >> 6, lane = threadIdx.x & 63;
#pragma unroll 4
    for (int i = 0; i < 16; ++i) {
        const int m = ct * 64 + w * 16 + i;
        const size_t g = (size_t)h * 128 + m;
        float cv = cent[g * 64 + lane];
        float n2 = wred_sum64(cv * cv);
        float n2o;
        float f = expmap0_factor(n2, sc, &n2o);
        float ky = cv * f;
        u16 kh = bf16_rne(ky);
        float r1 = ky - bf16_tof(kh);
        u16 km = bf16_rne(r1);
        u16 kl = bf16_rne(r1 - bf16_tof(km));
        Kc0[g * 64 + lane] = kh; Kc1[g * 64 + lane] = km; Kc2[g * 64 + lane] = kl;
        float gmm = 2.f * __builtin_amdgcn_rcpf(fmaxf(1.f - c * n2o, 1e-15f));
        gvt_s[lane][w * 16 + i] = ky * gmm;
        if (lane == 0) {
            y2c[g] = n2o; gm1c[g] = gmm - 1.f;
            rbc[g] = __builtin_amdgcn_rcpf(fmaf(-c, n2o, 1.f));
        }
    }
    __syncthreads();
    const int hd = threadIdx.x >> 2, j0 = (threadIdx.x & 3) * 16;
    u16 hb[16], lb[16];
#pragma unroll
    for (int e = 0; e < 16; ++e) {
        float v = gvt_s[hd][j0 + e];
        hb[e] = bf16_rne(v);
        lb[e] = bf16_rne(v - bf16_tof(hb[e]));
    }
    const size_t dst = ((size_t)h * 64 + hd) * 128 + ct * 64 + j0;
    *(u16x8*)(gVc0 + dst)     = *(u16x8*)&hb[0];
    *(u16x8*)(gVc0 + dst + 8) = *(u16x8*)&hb[8];
    *(u16x8*)(gVc1 + dst)     = *(u16x8*)&lb[0];
    *(u16x8*)(gVc1 + dst + 8) = *(u16x8*)&lb[8];
}

// ---------------- kernel 4: fused hyperbolic attention (MFMA, LDS-staged K/V) ----------------
// Logit via the arcosh form of the Poincare distance (exactly 2*artanh(arg)):
// z = 1 + 2c*||x-y||^2 * ra * rb; W = exp2(c2h*lg^2), lg = log2(z + sqrt(z^2-1)).
__global__ __launch_bounds__(256) void attn_kernel(
    const u16* __restrict__ Qb0, const u16* __restrict__ Qb1, const u16* __restrict__ Qb2,
    const u16* __restrict__ Kb0, const u16* __restrict__ Kb1, const u16* __restrict__ Kb2,
    const u16* __restrict__ Kc0, const u16* __restrict__ Kc1, const u16* __restrict__ Kc2,
    const u16* __restrict__ gV0, const u16* __restrict__ gV1,
    const u16* __restrict__ gVc0, const u16* __restrict__ gVc1,
    const float* __restrict__ x2q, const float* __restrict__ y2g, const float* __restrict__ gm1,
    const float* __restrict__ y2c, const float* __restrict__ gm1c,
    const float* __restrict__ rbj, const float* __restrict__ rbc,
    const float* __restrict__ sigma_raw, const float* __restrict__ curv_raw,
    u16* __restrict__ Oh, u16* __restrict__ Ol)
{
    __shared__ __align__(16) u16 Kst[2][3][4096];  // [buf][plane][row*64 + swizzled col]
    __shared__ __align__(16) u16 Vst[2][4096];     // [plane][row*64 + swizzled col]
    __shared__ __align__(16) u16 wb_hi[4][1024];
    __shared__ __align__(16) u16 wb_lo[4][1024];

    const int blk = blockIdx.x;
    const int xcd = blk & 7;
    const int serial = blk >> 3;
    const int bhg = serial / 9;
    const int qt = serial - bhg * 9;
    const int bh = bhg * 8 + xcd;
    const int b = bh / 12, h = bh % 12;
    const float c  = softplus_f(curv_raw[0]);
    const float sc = sqrtf(c);
    const float sig = softplus_f(sigma_raw[h]) + 1e-6f;
    const float coef = -2.f / (c * sig * sig);   // logit = coef * artanh(arg)^2
    const float c2h  = coef * 0.25f * 0.6931471805599453f;  // exp2 basis

    const int tid = threadIdx.x;
    const int w = tid >> 6, lane = tid & 63;
    const int lr = lane & 15, lg = lane >> 4, lo8 = lg * 8;
    const int swl = (lr & 7) << 3;

    const size_t qbase = (size_t)bh * 576 + qt * 64;

    int srow[2], scol[2];
#pragma unroll
    for (int rr = 0; rr < 2; ++rr) {
        int cch = (rr * 4 + w) * 64 + lane;
        srow[rr] = cch >> 3;
        scol[rr] = ((cch & 7) ^ (srow[rr] & 7)) << 3;
    }
    const size_t kb_base = (size_t)bh * 576 * 64;
    const size_t kc_base = (size_t)h * 128 * 64;
    const size_t vb_base = (size_t)bh * 64 * 576;
    const size_t vc_base = (size_t)h * 64 * 128;

    auto stageK = [&](int t, int buf) {
        if (t < 9) {
            const size_t rb = kb_base + (size_t)t * 64 * 64;
#pragma unroll
            for (int rr = 0; rr < 2; ++rr) {
                const size_t so = rb + (size_t)srow[rr] * 64 + scol[rr];
                gload_lds16(Kb0 + so, &Kst[buf][0][(rr * 4 + w) * 512]);
                gload_lds16(Kb1 + so, &Kst[buf][1][(rr * 4 + w) * 512]);
                gload_lds16(Kb2 + so, &Kst[buf][2][(rr * 4 + w) * 512]);
            }
        } else {
            const size_t rb = kc_base + (size_t)(t - 9) * 64 * 64;
#pragma unroll
            for (int rr = 0; rr < 2; ++rr) {
                const size_t so = rb + (size_t)srow[rr] * 64 + scol[rr];
                gload_lds16(Kc0 + so, &Kst[buf][0][(rr * 4 + w) * 512]);
                gload_lds16(Kc1 + so, &Kst[buf][1][(rr * 4 + w) * 512]);
                gload_lds16(Kc2 + so, &Kst[buf][2][(rr * 4 + w) * 512]);
            }
        }
    };
    auto stageV = [&](int t) {
        if (t < 9) {
            const size_t rb = vb_base + (size_t)t * 64;
#pragma unroll
            for (int rr = 0; rr < 2; ++rr) {
                const size_t so = rb + (size_t)srow[rr] * 576 + scol[rr];
                gload_lds16(gV0 + so, &Vst[0][(rr * 4 + w) * 512]);
                gload_lds16(gV1 + so, &Vst[1][(rr * 4 + w) * 512]);
            }
        } else {
            const size_t rb = vc_base + (size_t)(t - 9) * 64;
#pragma unroll
            for (int rr = 0; rr < 2; ++rr) {
                const size_t so = rb + (size_t)srow[rr] * 128 + scol[rr];
                gload_lds16(gVc0 + so, &Vst[0][(rr * 4 + w) * 512]);
                gload_lds16(gVc1 + so, &Vst[1][(rr * 4 + w) * 512]);
            }
        }
    };

    bf16x8 aQh[2], aQm[2], aQl[2];
    {
        const size_t qrow = (qbase + w * 16 + lr) * 64;
#pragma unroll
        for (int kt = 0; kt < 2; ++kt) {
            const size_t o = qrow + kt * 32 + lo8;
            aQh[kt] = *(const bf16x8*)(Qb0 + o);
            aQm[kt] = *(const bf16x8*)(Qb1 + o);
            aQl[kt] = *(const bf16x8*)(Qb2 + o);
        }
    }
    float x2r[4], Pr[4];
#pragma unroll
    for (int r = 0; r < 4; ++r) {
        float x2 = x2q[qbase + w * 16 + lg * 4 + r];
        x2r[r] = x2;
        Pr[r] = (c + c) / fmaf(-c, x2, 1.f);    // 2c * ra, ra = 1/(1-c*x2)
    }

    f32x4 pv[4];
#pragma unroll
    for (int i = 0; i < 4; ++i) pv[i] = (f32x4){0.f, 0.f, 0.f, 0.f};
    float den[4] = {0.f, 0.f, 0.f, 0.f};

    u16* wbh = &wb_hi[w][0];
    u16* wbl = &wb_lo[w][0];

    stageK(0, 0);
    __syncthreads();

    int cur = 0;
    for (int jt = 0; jt < 11; ++jt) {
        const int jb = jt * 64;

        if (jt < 10) stageK(jt + 1, cur ^ 1);
        stageV(jt);

        const float* y2p;
        const float* gm1p;
        const float* rbp;
        if (jt < 9) {
            y2p = y2g + (size_t)bh * 576 + jb;  gm1p = gm1 + (size_t)bh * 576 + jb;
            rbp = rbj + (size_t)bh * 576 + jb;
        } else {
            y2p = y2c + (size_t)h * 128 + (jb - 576); gm1p = gm1c + (size_t)h * 128 + (jb - 576);
            rbp = rbc + (size_t)h * 128 + (jb - 576);
        }

        const u16* kp0 = &Kst[cur][0][0];
        const u16* kp1 = &Kst[cur][1][0];
        const u16* kp2 = &Kst[cur][2][0];
        f32x4 sf[4];
        float y2v[4], gm1v[4], rbv[4];
#pragma unroll
        for (int jf = 0; jf < 4; ++jf) {
            y2v[jf] = y2p[jf * 16 + lr];
            gm1v[jf] = gm1p[jf * 16 + lr];
            rbv[jf] = rbp[jf * 16 + lr];
            const int rb = (jf * 16 + lr) * 64;
            f32x4 s = (f32x4){0.f, 0.f, 0.f, 0.f};
#pragma unroll
            for (int kt = 0; kt < 2; ++kt) {
                const int o = rb + ((kt * 32 + lo8) ^ swl);
                bf16x8 kh = *(const bf16x8*)(kp0 + o);
                bf16x8 km = *(const bf16x8*)(kp1 + o);
                bf16x8 kl = *(const bf16x8*)(kp2 + o);
                s = __builtin_amdgcn_mfma_f32_16x16x32_bf16(aQh[kt], kh, s, 0, 0, 0);
                s = __builtin_amdgcn_mfma_f32_16x16x32_bf16(aQh[kt], km, s, 0, 0, 0);
                s = __builtin_amdgcn_mfma_f32_16x16x32_bf16(aQm[kt], kh, s, 0, 0, 0);
                s = __builtin_amdgcn_mfma_f32_16x16x32_bf16(aQm[kt], km, s, 0, 0, 0);
                s = __builtin_amdgcn_mfma_f32_16x16x32_bf16(aQh[kt], kl, s, 0, 0, 0);
                s = __builtin_amdgcn_mfma_f32_16x16x32_bf16(aQl[kt], kh, s, 0, 0, 0);
            }
            sf[jf] = s;
        }

        // ---- xy -> W via arcosh form (division-free, 3 transcendentals)
#pragma unroll
        for (int jf = 0; jf < 4; ++jf) {
            const float y2 = y2v[jf];
            const float rb_ = rbv[jf];
#pragma unroll
            for (int r = 0; r < 4; ++r) {
                float xy = sf[jf][r];
                float sxy = x2r[r] + y2;
                float u = fmaf(-2.f, xy, sxy);           // ||x-y||^2
                float krr = Pr[r] * rb_;                 // 2c*ra*rb
                float z = fmaxf(fmaf(krr, u, 1.f), 1.f);
                float zm = fmaxf(fmaf(z, z, -1.f), 0.f);
                float lg = __builtin_amdgcn_logf(z + __builtin_amdgcn_sqrtf(zm));
                float wv_ = __builtin_amdgcn_exp2f(c2h * (lg * lg));
                sf[jf][r] = wv_;
                den[r] = fmaf(wv_, gm1v[jf], den[r]);
            }
        }

#pragma unroll
        for (int r = 0; r < 4; ++r) {
            const int row = lg * 4 + r;
            const int sw = (row & 7) << 3;
#pragma unroll
            for (int jf = 0; jf < 4; ++jf) {
                const int colu = (jf * 16 + lr) ^ sw;
                float wv_ = sf[jf][r];
                u16 hb = bf16_rne(wv_);
                wbh[row * 64 + colu] = hb;
                wbl[row * 64 + colu] = bf16_rne(wv_ - bf16_tof(hb));
            }
        }

        __syncthreads();   // V staged (vmcnt drained); K prefetch also landed

        bf16x8 aWh[2], aWl[2];
#pragma unroll
        for (int kt = 0; kt < 2; ++kt) {
            const int colu = (kt * 32 + lo8) ^ swl;
            aWh[kt] = *(const bf16x8*)(wbh + lr * 64 + colu);
            aWl[kt] = *(const bf16x8*)(wbl + lr * 64 + colu);
        }

#pragma unroll
        for (int hf = 0; hf < 4; ++hf) {
            const int rb = (hf * 16 + lr) * 64;
#pragma unroll
            for (int kt = 0; kt < 2; ++kt) {
                const int o = rb + ((kt * 32 + lo8) ^ swl);
                bf16x8 vh = *(const bf16x8*)(&Vst[0][o]);
                bf16x8 vl = *(const bf16x8*)(&Vst[1][o]);
                pv[hf] = __builtin_amdgcn_mfma_f32_16x16x32_bf16(aWh[kt], vh, pv[hf], 0, 0, 0);
                pv[hf] = __builtin_amdgcn_mfma_f32_16x16x32_bf16(aWh[kt], vl, pv[hf], 0, 0, 0);
                pv[hf] = __builtin_amdgcn_mfma_f32_16x16x32_bf16(aWl[kt], vh, pv[hf], 0, 0, 0);
            }
        }

        __syncthreads();
        cur ^= 1;
    }

#pragma unroll
    for (int r = 0; r < 4; ++r) {
        float d = den[r];
#pragma unroll
        for (int msk = 1; msk < 16; msk <<= 1) d += __shfl_xor(d, msk, 64);
        float rd = 1.f / d;                      // den > 0 always (gamma-1 >= 1)
        float o_[4];
        float n2 = 0.f;
#pragma unroll
        for (int hf = 0; hf < 4; ++hf) { o_[hf] = pv[hf][r] * rd; n2 = fmaf(o_[hf], o_[hf], n2); }
#pragma unroll
        for (int msk = 1; msk < 16; msk <<= 1) n2 += __shfl_xor(n2, msk, 64);
        float nrm = sqrtf(fmaxf(n2, 1e-15f));
        float arg = fminf(sc * nrm, 1.f - 1e-7f);
        float t = artanh_fast(arg);
        float f = 0.5f * t / (sc * nrm);
        const int nrow = qt * 64 + w * 16 + lg * 4 + r;
        const size_t dst = ((size_t)(b * 576 + nrow)) * 768 + h * 64;
#pragma unroll
        for (int hf = 0; hf < 4; ++hf) {
            float val = o_[hf] * f;
            u16 hb = bf16_rne(val);
            Oh[dst + hf * 16 + lr] = hb;
            Ol[dst + hf * 16 + lr] = bf16_rne(val - bf16_tof(hb));
        }
    }
}

// ---------------- launcher ----------------
extern "C" void kernel_launch(void* const* d_in, const int* in_sizes, int n_in,
                              void* d_out, int out_size, void* d_ws, size_t ws_size,
                              hipStream_t stream) {
    (void)in_sizes; (void)n_in; (void)out_size; (void)ws_size;
    const float* x    = (const float*)d_in[0];
    const float* Wq   = (const float*)d_in[1];
    const float* bq   = (const float*)d_in[2];
    const float* Wk   = (const float*)d_in[3];
    const float* bk   = (const float*)d_in[4];
    const float* Wv   = (const float*)d_in[5];
    const float* bv   = (const float*)d_in[6];
    const float* Wo   = (const float*)d_in[7];
    const float* bo   = (const float*)d_in[8];
    const float* cent = (const float*)d_in[9];
    const float* curv = (const float*)d_in[10];
    const float* sigr = (const float*)d_in[11];
    float* out = (float*)d_out;

    const size_t QH  = (size_t)B_ * H_ * N_ * 64;   // 7,077,888 (also K/V token size)
    const size_t CK  = (size_t)H_ * M_ * 64;        // 98,304 centroid-plane size
    const size_t WSZ = (size_t)D_ * D_;             // 589,824

    float* fp = (float*)d_ws;
    float* x2q  = fp;            fp += (size_t)B_ * H_ * N_;
    float* y2g  = fp;            fp += (size_t)B_ * H_ * N_;
    float* gm1  = fp;            fp += (size_t)B_ * H_ * N_;
    float* rbjv = fp;            fp += (size_t)B_ * H_ * N_;
    float* y2c  = fp;            fp += (size_t)H_ * M_;
    float* gm1c = fp;            fp += (size_t)H_ * M_;
    float* rbcv = fp;            fp += (size_t)H_ * M_;
    u16* up = (u16*)fp;
    u16* xh  = up;  up += QH;     // aliased with Oh (xh dead before attn writes Oh)
    u16* xl  = up;  up += QH;     // aliased with Ol
    u16* Oh  = xh;
    u16* Ol  = xl;
    u16* Wqh = up;  up += WSZ;
    u16* Wql = up;  up += WSZ;
    u16* Wkh = up;  up += WSZ;
    u16* Wkl = up;  up += WSZ;
    u16* Wvh = up;  up += WSZ;
    u16* Wvl = up;  up += WSZ;
    u16* Woh = up;  up += WSZ;
    u16* Wol = up;  up += WSZ;
    u16* Qb  = up;  up += 3 * QH;
    u16* Kb  = up;  up += 3 * QH;
    u16* gV  = up;  up += 2 * QH;
    u16* Kc  = up;  up += 3 * CK;
    u16* gVc = up;  up += 2 * CK;

    u16* Qb0 = Qb;           u16* Qb1 = Qb + QH;   u16* Qb2 = Qb + 2 * QH;
    u16* Kb0 = Kb;           u16* Kb1 = Kb + QH;   u16* Kb2 = Kb + 2 * QH;
    u16* gV0 = gV;           u16* gV1 = gV + QH;
    u16* Kc0 = Kc;           u16* Kc1 = Kc + CK;   u16* Kc2 = Kc + 2 * CK;
    u16* gVc0 = gVc;         u16* gVc1 = gVc + CK;

    // 0: hi/lo splits (x + all 4 weights)
    split_bf16_kernel<<<(int)(QH / 4 / 256), 256, 0, stream>>>(x, xh, xl, (int)(QH / 4));
    split_w4_kernel<<<dim3((int)(WSZ / 4 / 256), 4), 256, 0, stream>>>(
        Wq, Wk, Wv, Wo, Wqh, Wql, Wkh, Wkl, Wvh, Wvl, Woh, Wol);

    // 2: per-head centroid maps (independent of GEMM)
    cent_kernel<<<24, 256, 0, stream>>>(cent, Kc0, Kc1, Kc2, gVc0, gVc1, y2c, gm1c, rbcv, curv);

    // 1: QKV projections + fused hyperbolic maps (MFMA, XCD-banded, pipelined)
    gemm_qkv_mfma<<<1296, 256, 0, stream>>>(xh, xl, Wqh, Wql, Wkh, Wkl, Wvh, Wvl,
                                            bq, bk, bv,
                                            Qb0, Qb1, Qb2, Kb0, Kb1, Kb2, gV0, gV1,
                                            x2q, y2g, gm1, rbjv, curv);
    // 4: fused attention (MFMA, LDS-staged, XCD-affine, arcosh logit)
    attn_kernel<<<1728, 256, 0, stream>>>(Qb0, Qb1, Qb2, Kb0, Kb1, Kb2, Kc0, Kc1, Kc2,
                                          gV0, gV1, gVc0, gVc1,
                                          x2q, y2g, gm1, y2c, gm1c, rbjv, rbcv,
                                          sigr, curv, Oh, Ol);
    // 5: output projection (MFMA, XCD-banded, pipelined)
    gemm_o_mfma<<<432, 256, 0, stream>>>(Oh, Ol, Woh, Wol, bo, out);
}